// Round 3
// baseline (374.879 us; speedup 1.0000x reference)
//
#include <hip/hip_runtime.h>
#include <cstdint>
#include <cstddef>

#define NB   8
#define NPTS 4096
#define KNN  20
#define P    4   // points per fused-MLP block (M = P*KNN = 80 rows = 5 m-tiles)
#define QPW  4   // query points per wave in topk
#define WPB  16  // waves per topk block (1024 threads)

typedef __attribute__((ext_vector_type(8))) short    short8;
typedef __attribute__((ext_vector_type(4))) float    floatx4;
typedef __attribute__((ext_vector_type(4))) unsigned short ushort4v;

__device__ __forceinline__ uint16_t f2bf(float f) {
    uint32_t u = __float_as_uint(f);
    uint32_t r = (u + 0x7FFFu + ((u >> 16) & 1u)) >> 16;   // RNE
    return (uint16_t)r;
}
__device__ __forceinline__ float bf2f(uint16_t h) {
    return __uint_as_float(((uint32_t)h) << 16);
}

#define NEGINF __int_as_float((int)0xFF800000)

// pin a wave-uniform float to an SGPR (value identical; frees VGPRs)
__device__ __forceinline__ float rfl_f32(float v) {
    return __uint_as_float((uint32_t)__builtin_amdgcn_readfirstlane(__float_as_uint(v)));
}

// DPP f32 max step: invalid source lanes fall back to own value (idempotent)
template <int CTRL>
__device__ __forceinline__ float dpp_maxf(float v) {
    int o = __builtin_amdgcn_update_dpp(__float_as_int(v), __float_as_int(v),
                                        CTRL, 0xF, 0xF, false);
    return fmaxf(v, __int_as_float(o));
}
// wave64 f32 max-reduce, result broadcast via readlane 63
__device__ __forceinline__ float wave_max_f32(float v) {
    v = dpp_maxf<0x111>(v);   // row_shr:1
    v = dpp_maxf<0x112>(v);   // row_shr:2
    v = dpp_maxf<0x114>(v);   // row_shr:4
    v = dpp_maxf<0x118>(v);   // row_shr:8
    v = dpp_maxf<0x142>(v);   // row_bcast:15
    v = dpp_maxf<0x143>(v);   // row_bcast:31 -> lane 63 has max
    return __int_as_float(__builtin_amdgcn_readlane(__float_as_int(v), 63));
}

// ---------------------------------------------------------------------------
// Prep: pack (x,y,z,||x||^2); sq uses the SAME fma order as rounds 1-5 so
// pair values are bitwise-identical to the passing kernels.
__global__ __launch_bounds__(256) void prep_xyzs(
    const float* __restrict__ x,      // (B,3,N)
    float4* __restrict__ xyzs)        // (B,N)
{
    const int i = blockIdx.x * 256 + threadIdx.x;
    if (i >= NB * NPTS) return;
    const int b = i / NPTS, n = i - b * NPTS;
    const float* xb = x + (size_t)b * 3 * NPTS;
    const float x0 = xb[n], x1 = xb[NPTS + n], x2 = xb[2 * NPTS + n];
    float4 v;
    v.x = x0; v.y = x1; v.z = x2;
    v.w = fmaf(x2, x2, fmaf(x1, x1, x0 * x0));
    xyzs[i] = v;
}

// ---------------------------------------------------------------------------
// Top-20. 1024-thread blocks; whole 64KB point cloud staged in LDS (2 blocks/
// CU -> 8 waves/SIMD). One wave per QPW=4 points, lane l owns columns m%64==l
// (m = j*64+l). Full-precision f32 pair values (bitwise == rounds 1-5).
// Query scalars pinned to SGPRs (readfirstlane). Lane-local sorted top-3
// (med3 insert) + index regs. Selection is k-outer / p-inner so the 4 DPP
// max-reduce chains overlap. Rare refill (>3 pops on a lane) reconstructs the
// consumed-bitmap from prior winners via readlane (no persistent bitmap).
__global__ __launch_bounds__(1024, 8) void topk_kernel(
    const float4* __restrict__ xyzs,  // (B,N) packed (x,y,z,sq)
    int*   __restrict__ idx_out,      // (B,N,K)
    float* __restrict__ dist_out)     // (B,N,K)
{
    const int t = threadIdx.x;
    const int wave = t >> 6, l = t & 63;
    const int b = blockIdx.y;
    const float4* xq = xyzs + (size_t)b * NPTS;

    __shared__ float4 pts[NPTS];      // 64 KB
    for (int i = t; i < NPTS; i += WPB * 64) pts[i] = xq[i];
    __syncthreads();

    const int nbase = (blockIdx.x * WPB + wave) * QPW;

    float xn0[QPW], xn1[QPW], xn2[QPW], sqn[QPW];
    float V0[QPW], V1[QPW], V2[QPW];
    int   J0[QPW], J1[QPW], J2[QPW];
    int   my_m[QPW];

    #pragma unroll
    for (int p = 0; p < QPW; ++p) {
        const float4 pn = pts[nbase + p];
        xn0[p] = rfl_f32(pn.x); xn1[p] = rfl_f32(pn.y);
        xn2[p] = rfl_f32(pn.z); sqn[p] = rfl_f32(pn.w);
        V0[p] = NEGINF; V1[p] = NEGINF; V2[p] = NEGINF;
        J0[p] = 0; J1[p] = 0; J2[p] = 0;
        my_m[p] = 0;
    }

    #pragma unroll 2
    for (int j = 0; j < 64; ++j) {
        const float4 pm = pts[j * 64 + l];
        #pragma unroll
        for (int p = 0; p < QPW; ++p) {
            const float dot = fmaf(xn2[p], pm.z, fmaf(xn1[p], pm.y, xn0[p] * pm.x));
            const float s = 2.0f * dot - sqn[p] - pm.w;  // == rounds 1-5 bitwise
            const bool c0 = s > V0[p], c1 = s > V1[p], c2 = s > V2[p];
            const float nV2 = __builtin_amdgcn_fmed3f(V1[p], V2[p], s);
            const float nV1 = __builtin_amdgcn_fmed3f(V0[p], V1[p], s);
            V0[p] = fmaxf(V0[p], s);
            V1[p] = nV1; V2[p] = nV2;
            const int tA = c1 ? J1[p] : j;
            J2[p] = c2 ? tA : J2[p];
            const int tB = c0 ? J0[p] : j;
            J1[p] = c1 ? tB : J1[p];
            J0[p] = c0 ? j : J0[p];
        }
    }

    for (int k = 0; k < KNN; ++k) {
        // rare refill: rebuild top-3 of unconsumed cols (consumed set derived
        // from the k prior winners, which live in my_m[p] of lanes 0..k-1)
        #pragma unroll
        for (int p = 0; p < QPW; ++p) {
            if (V0[p] == NEGINF) {
                unsigned long long cons = 0ull;
                for (int i = 0; i < k; ++i) {
                    const int mw = __builtin_amdgcn_readlane(my_m[p], i);
                    if ((mw & 63) == l) cons |= 1ull << (mw >> 6);
                }
                V1[p] = NEGINF; V2[p] = NEGINF;
                for (int j = 0; j < 64; ++j) {
                    const float4 pm = pts[j * 64 + l];
                    const float dot = fmaf(xn2[p], pm.z, fmaf(xn1[p], pm.y, xn0[p] * pm.x));
                    float s = 2.0f * dot - sqn[p] - pm.w;
                    if ((cons >> j) & 1ull) s = NEGINF;
                    const bool c0 = s > V0[p], c1 = s > V1[p], c2 = s > V2[p];
                    const float nV2 = __builtin_amdgcn_fmed3f(V1[p], V2[p], s);
                    const float nV1 = __builtin_amdgcn_fmed3f(V0[p], V1[p], s);
                    V0[p] = fmaxf(V0[p], s);
                    V1[p] = nV1; V2[p] = nV2;
                    const int tA = c1 ? J1[p] : j;
                    J2[p] = c2 ? tA : J2[p];
                    const int tB = c0 ? J0[p] : j;
                    J1[p] = c1 ? tB : J1[p];
                    J0[p] = c0 ? j : J0[p];
                }
            }
        }
        // 4 independent DPP reduce chains in flight
        float wv[QPW];
        #pragma unroll
        for (int p = 0; p < QPW; ++p) wv[p] = wave_max_f32(V0[p]);
        #pragma unroll
        for (int p = 0; p < QPW; ++p) {
            const unsigned long long own = __ballot(V0[p] == wv[p]);
            const int owner = (int)__builtin_ctzll(own);
            const int jwin  = __builtin_amdgcn_readlane(J0[p], owner);
            const int m     = jwin * 64 + owner;
            if (l == k) my_m[p] = m;
            if (l == owner) {                 // owner pops its head
                V0[p] = V1[p]; V1[p] = V2[p]; V2[p] = NEGINF;
                J0[p] = J1[p]; J1[p] = J2[p];
            }
        }
    }

    #pragma unroll
    for (int p = 0; p < QPW; ++p) {
        if (l < KNN) {
            const int n = nbase + p;
            const float4 pm = pts[my_m[p]];
            const float d0 = pm.x - xn0[p], d1 = pm.y - xn1[p], d2 = pm.z - xn2[p];
            const float dist = sqrtf(((d0 * d0 + d1 * d1) + d2 * d2) + 1e-12f);
            const size_t base = ((size_t)b * NPTS + n) * KNN + l;
            idx_out[base]  = my_m[p];
            dist_out[base] = dist;
        }
    }
}

// ---------------------------------------------------------------------------
// Weight prep: fragment-ordered bf16 B-operands for mfma_f32_16x16x32_bf16.
__global__ void prep_wfrag(const float* __restrict__ w, uint16_t* __restrict__ frag,
                           int C, int NT, int KT) {
    const int i = blockIdx.x * 256 + threadIdx.x;   // one (nt,kt,lane)
    if (i >= NT * KT * 64) return;
    const int lane = i & 63;
    const int kt   = (i >> 6) % KT;
    const int nt   = (i >> 6) / KT;
    const int n    = nt * 16 + (lane & 15);
    const int c0   = kt * 32 + (lane >> 4) * 8;
    uint16_t o[8];
    #pragma unroll
    for (int j = 0; j < 8; ++j) {
        const int c = c0 + j;
        o[j] = (c < C) ? f2bf(w[(size_t)n * C + c]) : (uint16_t)0;
    }
    uint16_t* dst = frag + (size_t)i * 8;
    #pragma unroll
    for (int j = 0; j < 8; ++j) dst[j] = o[j];
}

// w5 (512,512) fp32 -> bf16 row-major
__global__ __launch_bounds__(256) void prep_w5bf(const float* __restrict__ w5,
                                                 uint16_t* __restrict__ w5b) {
    const int i = blockIdx.x * 256 + threadIdx.x;
    if (i < 512 * 512) w5b[i] = f2bf(w5[i]);
}

// ---------------------------------------------------------------------------
// One MFMA conv layer: in (LDS bf16, [80][IN_STRIDE]) x wf -> out (LDS bf16,
// [80][OUT_STRIDE], relu'd). bfrag preloaded for all ni; af hoisted out of
// the ni loop (one A-read per (mt,kt), reused across NT_W n-tiles).
template <int NT_TOT, int KT, int IN_STRIDE, int OUT_STRIDE>
__device__ __forceinline__ void mfma_layer(const uint16_t* __restrict__ in,
                                           uint16_t* __restrict__ out,
                                           const uint16_t* __restrict__ wf,
                                           int wave, int lane) {
    constexpr int NT_W = NT_TOT / 4;
    const int col = lane & 15, quad = lane >> 4;
    short8 bfrag[NT_W][KT];
    #pragma unroll
    for (int ni = 0; ni < NT_W; ++ni)
        #pragma unroll
        for (int k = 0; k < KT; ++k)
            bfrag[ni][k] = *(const short8*)(wf +
                ((size_t)((wave * NT_W + ni) * KT + k) * 64 + lane) * 8);
    #pragma unroll
    for (int mt = 0; mt < 5; ++mt) {
        short8 af[KT];
        #pragma unroll
        for (int k = 0; k < KT; ++k)
            af[k] = *(const short8*)(in + (mt * 16 + col) * IN_STRIDE + k * 32 + quad * 8);
        #pragma unroll
        for (int ni = 0; ni < NT_W; ++ni) {
            floatx4 acc = {0.f, 0.f, 0.f, 0.f};
            #pragma unroll
            for (int k = 0; k < KT; ++k)
                acc = __builtin_amdgcn_mfma_f32_16x16x32_bf16(af[k], bfrag[ni][k], acc, 0, 0, 0);
            const int nt = wave * NT_W + ni;
            #pragma unroll
            for (int r = 0; r < 4; ++r) {
                const float v = acc[r] > 0.f ? acc[r] : 0.f;
                out[(mt * 16 + quad * 4 + r) * OUT_STRIDE + nt * 16 + col] = f2bf(v);
            }
        }
    }
}

// max over the 20 k-rows of each point -> bf16 into cat (non-negative values)
template <int O, int STRIDE>
__device__ __forceinline__ void maxk(const uint16_t* __restrict__ h,
                                     uint16_t* __restrict__ cat_ws, int catoff,
                                     int t, int b, int n0) {
    constexpr int G = O / 8;
    if (t < P * G) {
        const int p = t / G, g = t % G;
        uint16_t mx[8];
        #pragma unroll
        for (int j = 0; j < 8; ++j) mx[j] = 0;
        for (int k = 0; k < KNN; ++k) {
            const uint16_t* row = h + (p * KNN + k) * STRIDE + g * 8;
            #pragma unroll
            for (int j = 0; j < 8; ++j) mx[j] = row[j] > mx[j] ? row[j] : mx[j];
        }
        uint16_t* dst = cat_ws + ((size_t)b * NPTS + n0 + p) * 512 + catoff + g * 8;
        *(short8*)dst = *(const short8*)mx;
    }
}

// ---------------------------------------------------------------------------
// Fused MLP, MFMA edition. Block = 4 points, 256 threads (4 waves).
__global__ __launch_bounds__(256) void fused_mlp_mfma(
    const float* __restrict__ x,
    const int*   __restrict__ idx_ws,
    const float* __restrict__ dist_ws,
    const uint16_t* __restrict__ wf1,
    const uint16_t* __restrict__ wf2,
    const uint16_t* __restrict__ wf3,
    const uint16_t* __restrict__ wf4,
    uint16_t* __restrict__ cat_ws)      // (B*N, 512) bf16
{
    const int n0 = blockIdx.x * P, b = blockIdx.y, t = threadIdx.x;
    const int wave = t >> 6, lane = t & 63;

    __shared__ __align__(16) uint16_t bufA[12800];  // feat(3200) / h2(5760) / slabs(12800)
    __shared__ __align__(16) uint16_t bufB[10880];  // h1(5760) / h3(10880)

    // ---- stage feat: [80][40] bf16, cols 0-2 xc, 3-5 nbr, 6-25 dist, 26+ zero
    for (int i = t; i < 1600; i += 256) ((uint32_t*)bufA)[i] = 0;
    __syncthreads();
    {
        const float* xb = x + (size_t)b * 3 * NPTS;
        if (t < P * KNN) {
            const int p = t / KNN, k = t % KNN;
            const int n = n0 + p;
            const size_t base = ((size_t)b * NPTS + n) * KNN + k;
            const int   m = idx_ws[base];
            const float d = dist_ws[base];
            uint16_t* fr = bufA + t * 40;
            fr[0] = f2bf(xb[n]);        fr[1] = f2bf(xb[NPTS + n]);
            fr[2] = f2bf(xb[2 * NPTS + n]);
            fr[3] = f2bf(xb[m]);        fr[4] = f2bf(xb[NPTS + m]);
            fr[5] = f2bf(xb[2 * NPTS + m]);
            const uint16_t db = f2bf(d);
            #pragma unroll
            for (int j = 0; j < KNN; ++j) bufA[(p * KNN + j) * 40 + 6 + k] = db;
        }
    }
    __syncthreads();

    // ---- L1: feat(A) -> h1(B)
    mfma_layer<4, 1, 40, 72>(bufA, bufB, wf1, wave, lane);
    __syncthreads();

    // ---- L2: h1(B) -> h2(A); x1 = maxk(h1)
    maxk<64, 72>(bufB, cat_ws, 0, t, b, n0);
    mfma_layer<4, 2, 72, 72>(bufB, bufA, wf2, wave, lane);
    __syncthreads();

    // ---- L3: h2(A) -> h3(B); x2 = maxk(h2)
    maxk<64, 72>(bufA, cat_ws, 64, t, b, n0);
    mfma_layer<8, 2, 72, 136>(bufA, bufB, wf3, wave, lane);
    __syncthreads();

    // ---- L4: h3(B) -> per-wave slab (A) -> relu+max -> cat; x3 = maxk(h3)
    maxk<128, 136>(bufB, cat_ws, 128, t, b, n0);
    {
        float* slab = (float*)bufA + wave * 1600;   // [80][20] f32, wave-private
        const int col = lane & 15, quad = lane >> 4;
        #pragma unroll
        for (int ni = 0; ni < 4; ++ni) {
            const int nt = wave * 4 + ni;
            short8 bfrag[4];
            #pragma unroll
            for (int k = 0; k < 4; ++k)
                bfrag[k] = *(const short8*)(wf4 + ((size_t)(nt * 4 + k) * 64 + lane) * 8);
            #pragma unroll
            for (int mt = 0; mt < 5; ++mt) {
                floatx4 acc = {0.f, 0.f, 0.f, 0.f};
                #pragma unroll
                for (int k = 0; k < 4; ++k) {
                    const short8 af = *(const short8*)(bufB + (mt * 16 + col) * 136
                                                           + k * 32 + quad * 8);
                    acc = __builtin_amdgcn_mfma_f32_16x16x32_bf16(af, bfrag[k], acc, 0, 0, 0);
                }
                #pragma unroll
                for (int r = 0; r < 4; ++r)
                    slab[(mt * 16 + quad * 4 + r) * 20 + col] = fmaxf(acc[r], 0.f);
            }
            const int p = lane >> 4, grp = (lane >> 2) & 3, kq = lane & 3;
            floatx4 mx = {0.f, 0.f, 0.f, 0.f};
            #pragma unroll
            for (int i = 0; i < 5; ++i) {
                const floatx4 v = *(const floatx4*)&slab[(p * KNN + kq * 5 + i) * 20 + grp * 4];
                mx[0] = fmaxf(mx[0], v[0]); mx[1] = fmaxf(mx[1], v[1]);
                mx[2] = fmaxf(mx[2], v[2]); mx[3] = fmaxf(mx[3], v[3]);
            }
            #pragma unroll
            for (int r = 0; r < 4; ++r) {
                mx[r] = fmaxf(mx[r], __shfl_xor(mx[r], 1));
                mx[r] = fmaxf(mx[r], __shfl_xor(mx[r], 2));
            }
            if (kq == 0) {
                ushort4v q;
                q.x = f2bf(mx[0]); q.y = f2bf(mx[1]);
                q.z = f2bf(mx[2]); q.w = f2bf(mx[3]);
                uint16_t* dst = cat_ws + ((size_t)b * NPTS + n0 + p) * 512
                              + 256 + nt * 16 + grp * 4;
                *(ushort4v*)dst = q;
            }
        }
    }
}

// ---------------------------------------------------------------------------
// Final GEMM, MFMA: out[b,o,n] = relu( sum_c w5[o,c] * cat[b,n,c] ).
// 64(o) x 64(n) tile, 4 waves (wave = o-subtile), K-chunks of 64.
__global__ __launch_bounds__(256) void final_gemm_mfma(
    const uint16_t* __restrict__ w5b,  // (512,512) bf16 row-major (o,c)
    const uint16_t* __restrict__ cat,  // (B*N,512) bf16
    float* __restrict__ out)           // (B,512,N) f32
{
    const int b  = blockIdx.z;
    const int o0 = blockIdx.y * 64;
    const int n0 = blockIdx.x * 64;
    const int t  = threadIdx.x;
    const int wave = t >> 6, lane = t & 63;
    const int col = lane & 15, quad = lane >> 4;

    __shared__ __align__(16) uint16_t As[64 * 72];  // w5 tile [o][k], +8 pad
    __shared__ __align__(16) uint16_t Bs[64 * 72];  // cat tile [n][k], +8 pad

    floatx4 acc[4] = {{0.f,0.f,0.f,0.f},{0.f,0.f,0.f,0.f},
                      {0.f,0.f,0.f,0.f},{0.f,0.f,0.f,0.f}};

    const size_t arow_base = (size_t)o0 * 512;
    const size_t brow_base = ((size_t)b * NPTS + n0) * 512;

    for (int kc = 0; kc < 512; kc += 64) {
        #pragma unroll
        for (int i = 0; i < 2; ++i) {
            const int idx = t + i * 256;          // 0..511
            const int row = idx >> 3;             // 0..63
            const int k8  = (idx & 7) * 8;        // 0..56
            *(short8*)&As[row * 72 + k8] =
                *(const short8*)&w5b[arow_base + (size_t)row * 512 + kc + k8];
            *(short8*)&Bs[row * 72 + k8] =
                *(const short8*)&cat[brow_base + (size_t)row * 512 + kc + k8];
        }
        __syncthreads();
        #pragma unroll
        for (int kt = 0; kt < 2; ++kt) {
            const short8 af = *(const short8*)&As[(wave * 16 + col) * 72 + kt * 32 + quad * 8];
            #pragma unroll
            for (int ns = 0; ns < 4; ++ns) {
                const short8 bf = *(const short8*)&Bs[(ns * 16 + col) * 72 + kt * 32 + quad * 8];
                acc[ns] = __builtin_amdgcn_mfma_f32_16x16x32_bf16(af, bf, acc[ns], 0, 0, 0);
            }
        }
        __syncthreads();
    }

    #pragma unroll
    for (int ns = 0; ns < 4; ++ns) {
        #pragma unroll
        for (int r = 0; r < 4; ++r) {
            out[((size_t)b * 512 + o0 + wave * 16 + quad * 4 + r) * NPTS
                + n0 + ns * 16 + col] = fmaxf(acc[ns][r], 0.f);
        }
    }
}

// ---------------------------------------------------------------------------
extern "C" void kernel_launch(void* const* d_in, const int* in_sizes, int n_in,
                              void* d_out, int out_size, void* d_ws, size_t ws_size,
                              hipStream_t stream) {
    const float* x  = (const float*)d_in[0];  // (8,3,4096)
    const float* w1 = (const float*)d_in[1];  // (64,26)
    const float* w2 = (const float*)d_in[2];  // (64,64)
    const float* w3 = (const float*)d_in[3];  // (128,64)
    const float* w4 = (const float*)d_in[4];  // (256,128)
    const float* w5 = (const float*)d_in[5];  // (512,512)
    float* out = (float*)d_out;               // (8,512,4096) fp32

    // workspace layout (bytes):
    //   [0)         idx_ws   B*N*K int     = 2,621,440
    //   [2621440)   dist_ws  B*N*K f32     = 2,621,440
    //   [5242880)   cat_ws   B*N*512 bf16  = 33,554,432
    //               (xyzs aliases cat_ws[0:512KB]: consumed by topk BEFORE
    //                fused_mlp writes cat — stream-ordered, safe)
    //   [38797312)  w5b bf16 (512x512)     = 524,288
    //   [72351744)  wf1 4 KB; wf2 8 KB; wf3 16 KB; wf4 64 KB
    char* ws = (char*)d_ws;
    int*      idx_ws  = (int*)ws;
    float*    dist_ws = (float*)(ws + 2621440);
    uint16_t* cat_ws  = (uint16_t*)(ws + 5242880);
    float4*   xyzs    = (float4*)(ws + 5242880);   // alias, 512 KB
    uint16_t* w5b     = (uint16_t*)(ws + 38797312);
    uint16_t* wf1     = (uint16_t*)(ws + 72351744);
    uint16_t* wf2     = (uint16_t*)(ws + 72351744 + 4096);
    uint16_t* wf3     = (uint16_t*)(ws + 72351744 + 4096 + 8192);
    uint16_t* wf4     = (uint16_t*)(ws + 72351744 + 4096 + 8192 + 16384);

    prep_wfrag<<<dim3(1), 256, 0, stream>>>(w1, wf1, 26,  4, 1);
    prep_wfrag<<<dim3(2), 256, 0, stream>>>(w2, wf2, 64,  4, 2);
    prep_wfrag<<<dim3(4), 256, 0, stream>>>(w3, wf3, 64,  8, 2);
    prep_wfrag<<<dim3(16), 256, 0, stream>>>(w4, wf4, 128, 16, 4);
    prep_w5bf<<<dim3(1024), 256, 0, stream>>>(w5, w5b);
    prep_xyzs<<<dim3((NB * NPTS + 255) / 256), 256, 0, stream>>>(x, xyzs);

    topk_kernel<<<dim3(NPTS / (WPB * QPW), NB), 1024, 0, stream>>>(xyzs, idx_ws, dist_ws);
    fused_mlp_mfma<<<dim3(NPTS / P, NB), 256, 0, stream>>>(
        x, idx_ws, dist_ws, wf1, wf2, wf3, wf4, cat_ws);
    final_gemm_mfma<<<dim3(NPTS / 64, 512 / 64, NB), 256, 0, stream>>>(w5b, cat_ws, out);
}

// Round 4
// 367.292 us; speedup vs baseline: 1.0207x; 1.0207x over previous
//
#include <hip/hip_runtime.h>
#include <cstdint>
#include <cstddef>

#define NB   8
#define NPTS 4096
#define KNN  20
#define P    4   // points per fused-MLP block (M = P*KNN = 80 rows = 5 m-tiles)
#define QPW  4   // query points per wave in topk
#define WPB  8   // waves per topk block (512 threads)

typedef __attribute__((ext_vector_type(8))) short    short8;
typedef __attribute__((ext_vector_type(4))) float    floatx4;
typedef __attribute__((ext_vector_type(4))) unsigned short ushort4v;

__device__ __forceinline__ uint16_t f2bf(float f) {
    uint32_t u = __float_as_uint(f);
    uint32_t r = (u + 0x7FFFu + ((u >> 16) & 1u)) >> 16;   // RNE
    return (uint16_t)r;
}

// packed f32->bf16 RNE (same rounding as f2bf), 1 instr for 2 values
__device__ __forceinline__ uint32_t cvtpk_bf16(float lo, float hi) {
    uint32_t r;
    asm("v_cvt_pk_bf16_f32 %0, %1, %2" : "=v"(r) : "v"(lo), "v"(hi));
    return r;
}

#define NEGINF __int_as_float((int)0xFF800000)

// pin a wave-uniform float to an SGPR (value identical; frees VGPRs)
__device__ __forceinline__ float rfl_f32(float v) {
    return __uint_as_float((uint32_t)__builtin_amdgcn_readfirstlane(__float_as_uint(v)));
}

// DPP f32 max step: invalid source lanes fall back to own value (idempotent)
template <int CTRL>
__device__ __forceinline__ float dpp_maxf(float v) {
    int o = __builtin_amdgcn_update_dpp(__float_as_int(v), __float_as_int(v),
                                        CTRL, 0xF, 0xF, false);
    return fmaxf(v, __int_as_float(o));
}
// wave64 f32 max-reduce, result broadcast via readlane 63
__device__ __forceinline__ float wave_max_f32(float v) {
    v = dpp_maxf<0x111>(v);   // row_shr:1
    v = dpp_maxf<0x112>(v);   // row_shr:2
    v = dpp_maxf<0x114>(v);   // row_shr:4
    v = dpp_maxf<0x118>(v);   // row_shr:8
    v = dpp_maxf<0x142>(v);   // row_bcast:15
    v = dpp_maxf<0x143>(v);   // row_bcast:31 -> lane 63 has max
    return __int_as_float(__builtin_amdgcn_readlane(__float_as_int(v), 63));
}

// ---------------------------------------------------------------------------
// Top-20. 512-thread blocks (8 waves); point cloud staged planar in LDS
// (48 KB -> 3 blocks/CU). One wave per QPW=4 points, lane l owns columns
// m%64==l (m = j*64+l). ||xm||^2 recomputed per j with the SAME fma order as
// the old prep kernel, so s is bitwise-identical to all prior passing rounds.
// Query scalars pinned to SGPRs. Lane-local sorted top-3 (med3 insert) +
// index regs. Selection k-outer/p-inner (4 DPP chains overlap). Rare refill
// (>3 pops on a lane) reconstructs the consumed set from prior winners.
__global__ __launch_bounds__(512, 6) void topk_kernel(
    const float* __restrict__ x,      // (B,3,N)
    int*   __restrict__ idx_out,      // (B,N,K)
    float* __restrict__ dist_out)     // (B,N,K)
{
    const int t = threadIdx.x;
    const int wave = t >> 6, l = t & 63;
    const int b = blockIdx.y;

    __shared__ float xs[NPTS], ys[NPTS], zs[NPTS];   // 48 KB planar
    {
        const float* xb = x + (size_t)b * 3 * NPTS;
        for (int i = t; i < NPTS; i += WPB * 64) {
            xs[i] = xb[i];
            ys[i] = xb[NPTS + i];
            zs[i] = xb[2 * NPTS + i];
        }
    }
    __syncthreads();

    const int nbase = (blockIdx.x * WPB + wave) * QPW;

    float xn0[QPW], xn1[QPW], xn2[QPW], sqn[QPW];
    float V0[QPW], V1[QPW], V2[QPW];
    int   J0[QPW], J1[QPW], J2[QPW];
    int   my_m[QPW];

    #pragma unroll
    for (int p = 0; p < QPW; ++p) {
        const int n = nbase + p;
        const float qx = xs[n], qy = ys[n], qz = zs[n];
        xn0[p] = rfl_f32(qx); xn1[p] = rfl_f32(qy); xn2[p] = rfl_f32(qz);
        sqn[p] = rfl_f32(fmaf(qz, qz, fmaf(qy, qy, qx * qx)));
        V0[p] = NEGINF; V1[p] = NEGINF; V2[p] = NEGINF;
        J0[p] = 0; J1[p] = 0; J2[p] = 0;
        my_m[p] = 0;
    }

    #pragma unroll 2
    for (int j = 0; j < 64; ++j) {
        const float px = xs[j * 64 + l], py = ys[j * 64 + l], pz = zs[j * 64 + l];
        const float sqm = fmaf(pz, pz, fmaf(py, py, px * px));   // == old prep .w
        #pragma unroll
        for (int p = 0; p < QPW; ++p) {
            const float dot = fmaf(xn2[p], pz, fmaf(xn1[p], py, xn0[p] * px));
            const float s = 2.0f * dot - sqn[p] - sqm;   // bitwise == prior rounds
            const bool c0 = s > V0[p], c1 = s > V1[p], c2 = s > V2[p];
            const float nV2 = __builtin_amdgcn_fmed3f(V1[p], V2[p], s);
            const float nV1 = __builtin_amdgcn_fmed3f(V0[p], V1[p], s);
            V0[p] = fmaxf(V0[p], s);
            V1[p] = nV1; V2[p] = nV2;
            const int tA = c1 ? J1[p] : j;
            J2[p] = c2 ? tA : J2[p];
            const int tB = c0 ? J0[p] : j;
            J1[p] = c1 ? tB : J1[p];
            J0[p] = c0 ? j : J0[p];
        }
    }

    for (int k = 0; k < KNN; ++k) {
        // rare refill: rebuild top-3 of unconsumed cols (consumed set derived
        // from the k prior winners, which live in my_m[p] of lanes 0..k-1)
        #pragma unroll
        for (int p = 0; p < QPW; ++p) {
            if (V0[p] == NEGINF) {
                unsigned long long cons = 0ull;
                for (int i = 0; i < k; ++i) {
                    const int mw = __builtin_amdgcn_readlane(my_m[p], i);
                    if ((mw & 63) == l) cons |= 1ull << (mw >> 6);
                }
                V1[p] = NEGINF; V2[p] = NEGINF;
                for (int j = 0; j < 64; ++j) {
                    const float px = xs[j * 64 + l], py = ys[j * 64 + l], pz = zs[j * 64 + l];
                    const float sqm = fmaf(pz, pz, fmaf(py, py, px * px));
                    const float dot = fmaf(xn2[p], pz, fmaf(xn1[p], py, xn0[p] * px));
                    float s = 2.0f * dot - sqn[p] - sqm;
                    if ((cons >> j) & 1ull) s = NEGINF;
                    const bool c0 = s > V0[p], c1 = s > V1[p], c2 = s > V2[p];
                    const float nV2 = __builtin_amdgcn_fmed3f(V1[p], V2[p], s);
                    const float nV1 = __builtin_amdgcn_fmed3f(V0[p], V1[p], s);
                    V0[p] = fmaxf(V0[p], s);
                    V1[p] = nV1; V2[p] = nV2;
                    const int tA = c1 ? J1[p] : j;
                    J2[p] = c2 ? tA : J2[p];
                    const int tB = c0 ? J0[p] : j;
                    J1[p] = c1 ? tB : J1[p];
                    J0[p] = c0 ? j : J0[p];
                }
            }
        }
        // 4 independent DPP reduce chains in flight
        float wv[QPW];
        #pragma unroll
        for (int p = 0; p < QPW; ++p) wv[p] = wave_max_f32(V0[p]);
        #pragma unroll
        for (int p = 0; p < QPW; ++p) {
            const unsigned long long own = __ballot(V0[p] == wv[p]);
            const int owner = (int)__builtin_ctzll(own);
            const int jwin  = __builtin_amdgcn_readlane(J0[p], owner);
            const int m     = jwin * 64 + owner;
            if (l == k) my_m[p] = m;
            if (l == owner) {                 // owner pops its head
                V0[p] = V1[p]; V1[p] = V2[p]; V2[p] = NEGINF;
                J0[p] = J1[p]; J1[p] = J2[p];
            }
        }
    }

    #pragma unroll
    for (int p = 0; p < QPW; ++p) {
        if (l < KNN) {
            const int n = nbase + p;
            const int m = my_m[p];
            const float d0 = xs[m] - xn0[p], d1 = ys[m] - xn1[p], d2 = zs[m] - xn2[p];
            const float dist = sqrtf(((d0 * d0 + d1 * d1) + d2 * d2) + 1e-12f);
            const size_t base = ((size_t)b * NPTS + n) * KNN + l;
            idx_out[base]  = m;
            dist_out[base] = dist;
        }
    }
}

// ---------------------------------------------------------------------------
// Weight prep: fragment-ordered bf16 B-operands for mfma_f32_16x16x32_bf16.
__global__ void prep_wfrag(const float* __restrict__ w, uint16_t* __restrict__ frag,
                           int C, int NT, int KT) {
    const int i = blockIdx.x * 256 + threadIdx.x;   // one (nt,kt,lane)
    if (i >= NT * KT * 64) return;
    const int lane = i & 63;
    const int kt   = (i >> 6) % KT;
    const int nt   = (i >> 6) / KT;
    const int n    = nt * 16 + (lane & 15);
    const int c0   = kt * 32 + (lane >> 4) * 8;
    uint16_t o[8];
    #pragma unroll
    for (int j = 0; j < 8; ++j) {
        const int c = c0 + j;
        o[j] = (c < C) ? f2bf(w[(size_t)n * C + c]) : (uint16_t)0;
    }
    uint16_t* dst = frag + (size_t)i * 8;
    #pragma unroll
    for (int j = 0; j < 8; ++j) dst[j] = o[j];
}

// w5 (512,512) fp32 -> bf16 row-major
__global__ __launch_bounds__(256) void prep_w5bf(const float* __restrict__ w5,
                                                 uint16_t* __restrict__ w5b) {
    const int i = blockIdx.x * 256 + threadIdx.x;
    if (i < 512 * 512) w5b[i] = f2bf(w5[i]);
}

// ---------------------------------------------------------------------------
// One MFMA conv layer: in (LDS bf16, [80][IN_STRIDE]) x wf -> out (LDS bf16,
// [80][OUT_STRIDE], relu'd). bfrag preloaded for all ni; af hoisted out of
// the ni loop. Epilogue converts via packed v_cvt_pk_bf16_f32 (RNE == f2bf).
template <int NT_TOT, int KT, int IN_STRIDE, int OUT_STRIDE>
__device__ __forceinline__ void mfma_layer(const uint16_t* __restrict__ in,
                                           uint16_t* __restrict__ out,
                                           const uint16_t* __restrict__ wf,
                                           int wave, int lane) {
    constexpr int NT_W = NT_TOT / 4;
    const int col = lane & 15, quad = lane >> 4;
    short8 bfrag[NT_W][KT];
    #pragma unroll
    for (int ni = 0; ni < NT_W; ++ni)
        #pragma unroll
        for (int k = 0; k < KT; ++k)
            bfrag[ni][k] = *(const short8*)(wf +
                ((size_t)((wave * NT_W + ni) * KT + k) * 64 + lane) * 8);
    #pragma unroll
    for (int mt = 0; mt < 5; ++mt) {
        short8 af[KT];
        #pragma unroll
        for (int k = 0; k < KT; ++k)
            af[k] = *(const short8*)(in + (mt * 16 + col) * IN_STRIDE + k * 32 + quad * 8);
        #pragma unroll
        for (int ni = 0; ni < NT_W; ++ni) {
            floatx4 acc = {0.f, 0.f, 0.f, 0.f};
            #pragma unroll
            for (int k = 0; k < KT; ++k)
                acc = __builtin_amdgcn_mfma_f32_16x16x32_bf16(af[k], bfrag[ni][k], acc, 0, 0, 0);
            const int nt = wave * NT_W + ni;
            const int rowb = mt * 16 + quad * 4;
            const uint32_t pk01 = cvtpk_bf16(fmaxf(acc[0], 0.f), fmaxf(acc[1], 0.f));
            const uint32_t pk23 = cvtpk_bf16(fmaxf(acc[2], 0.f), fmaxf(acc[3], 0.f));
            out[(rowb + 0) * OUT_STRIDE + nt * 16 + col] = (uint16_t)pk01;
            out[(rowb + 1) * OUT_STRIDE + nt * 16 + col] = (uint16_t)(pk01 >> 16);
            out[(rowb + 2) * OUT_STRIDE + nt * 16 + col] = (uint16_t)pk23;
            out[(rowb + 3) * OUT_STRIDE + nt * 16 + col] = (uint16_t)(pk23 >> 16);
        }
    }
}

// max over the 20 k-rows of each point -> bf16 into cat (non-negative values)
template <int O, int STRIDE>
__device__ __forceinline__ void maxk(const uint16_t* __restrict__ h,
                                     uint16_t* __restrict__ cat_ws, int catoff,
                                     int t, int b, int n0) {
    constexpr int G = O / 8;
    if (t < P * G) {
        const int p = t / G, g = t % G;
        uint16_t mx[8];
        #pragma unroll
        for (int j = 0; j < 8; ++j) mx[j] = 0;
        for (int k = 0; k < KNN; ++k) {
            const uint16_t* row = h + (p * KNN + k) * STRIDE + g * 8;
            #pragma unroll
            for (int j = 0; j < 8; ++j) mx[j] = row[j] > mx[j] ? row[j] : mx[j];
        }
        uint16_t* dst = cat_ws + ((size_t)b * NPTS + n0 + p) * 512 + catoff + g * 8;
        *(short8*)dst = *(const short8*)mx;
    }
}

// ---------------------------------------------------------------------------
// Fused MLP, MFMA edition. Block = 4 points, 256 threads (4 waves).
__global__ __launch_bounds__(256) void fused_mlp_mfma(
    const float* __restrict__ x,
    const int*   __restrict__ idx_ws,
    const float* __restrict__ dist_ws,
    const uint16_t* __restrict__ wf1,
    const uint16_t* __restrict__ wf2,
    const uint16_t* __restrict__ wf3,
    const uint16_t* __restrict__ wf4,
    uint16_t* __restrict__ cat_ws)      // (B*N, 512) bf16
{
    const int n0 = blockIdx.x * P, b = blockIdx.y, t = threadIdx.x;
    const int wave = t >> 6, lane = t & 63;

    __shared__ __align__(16) uint16_t bufA[12800];  // feat(3200) / h2(5760) / slabs(12800)
    __shared__ __align__(16) uint16_t bufB[10880];  // h1(5760) / h3(10880)

    // ---- stage feat: [80][40] bf16, cols 0-2 xc, 3-5 nbr, 6-25 dist, 26+ zero
    for (int i = t; i < 1600; i += 256) ((uint32_t*)bufA)[i] = 0;
    __syncthreads();
    {
        const float* xb = x + (size_t)b * 3 * NPTS;
        if (t < P * KNN) {
            const int p = t / KNN, k = t % KNN;
            const int n = n0 + p;
            const size_t base = ((size_t)b * NPTS + n) * KNN + k;
            const int   m = idx_ws[base];
            const float d = dist_ws[base];
            uint16_t* fr = bufA + t * 40;
            fr[0] = f2bf(xb[n]);        fr[1] = f2bf(xb[NPTS + n]);
            fr[2] = f2bf(xb[2 * NPTS + n]);
            fr[3] = f2bf(xb[m]);        fr[4] = f2bf(xb[NPTS + m]);
            fr[5] = f2bf(xb[2 * NPTS + m]);
            const uint16_t db = f2bf(d);
            #pragma unroll
            for (int j = 0; j < KNN; ++j) bufA[(p * KNN + j) * 40 + 6 + k] = db;
        }
    }
    __syncthreads();

    // ---- L1: feat(A) -> h1(B)
    mfma_layer<4, 1, 40, 72>(bufA, bufB, wf1, wave, lane);
    __syncthreads();

    // ---- L2: h1(B) -> h2(A); x1 = maxk(h1)
    maxk<64, 72>(bufB, cat_ws, 0, t, b, n0);
    mfma_layer<4, 2, 72, 72>(bufB, bufA, wf2, wave, lane);
    __syncthreads();

    // ---- L3: h2(A) -> h3(B); x2 = maxk(h2)
    maxk<64, 72>(bufA, cat_ws, 64, t, b, n0);
    mfma_layer<8, 2, 72, 136>(bufA, bufB, wf3, wave, lane);
    __syncthreads();

    // ---- L4: h3(B) -> per-wave slab (A) -> relu+max -> cat; x3 = maxk(h3)
    maxk<128, 136>(bufB, cat_ws, 128, t, b, n0);
    {
        float* slab = (float*)bufA + wave * 1600;   // [80][20] f32, wave-private
        const int col = lane & 15, quad = lane >> 4;
        #pragma unroll
        for (int ni = 0; ni < 4; ++ni) {
            const int nt = wave * 4 + ni;
            short8 bfrag[4];
            #pragma unroll
            for (int k = 0; k < 4; ++k)
                bfrag[k] = *(const short8*)(wf4 + ((size_t)(nt * 4 + k) * 64 + lane) * 8);
            #pragma unroll
            for (int mt = 0; mt < 5; ++mt) {
                floatx4 acc = {0.f, 0.f, 0.f, 0.f};
                #pragma unroll
                for (int k = 0; k < 4; ++k) {
                    const short8 af = *(const short8*)(bufB + (mt * 16 + col) * 136
                                                           + k * 32 + quad * 8);
                    acc = __builtin_amdgcn_mfma_f32_16x16x32_bf16(af, bfrag[k], acc, 0, 0, 0);
                }
                #pragma unroll
                for (int r = 0; r < 4; ++r)
                    slab[(mt * 16 + quad * 4 + r) * 20 + col] = fmaxf(acc[r], 0.f);
            }
            const int p = lane >> 4, grp = (lane >> 2) & 3, kq = lane & 3;
            floatx4 mx = {0.f, 0.f, 0.f, 0.f};
            #pragma unroll
            for (int i = 0; i < 5; ++i) {
                const floatx4 v = *(const floatx4*)&slab[(p * KNN + kq * 5 + i) * 20 + grp * 4];
                mx[0] = fmaxf(mx[0], v[0]); mx[1] = fmaxf(mx[1], v[1]);
                mx[2] = fmaxf(mx[2], v[2]); mx[3] = fmaxf(mx[3], v[3]);
            }
            #pragma unroll
            for (int r = 0; r < 4; ++r) {
                mx[r] = fmaxf(mx[r], __shfl_xor(mx[r], 1));
                mx[r] = fmaxf(mx[r], __shfl_xor(mx[r], 2));
            }
            if (kq == 0) {
                const uint32_t p01 = cvtpk_bf16(mx[0], mx[1]);
                const uint32_t p23 = cvtpk_bf16(mx[2], mx[3]);
                uint32_t* dst = (uint32_t*)(cat_ws + ((size_t)b * NPTS + n0 + p) * 512
                              + 256 + nt * 16 + grp * 4);
                dst[0] = p01; dst[1] = p23;
            }
        }
    }
}

// ---------------------------------------------------------------------------
// Final GEMM, MFMA: out[b,o,n] = relu( sum_c w5[o,c] * cat[b,n,c] ).
// 64(o) x 128(n) tile, 4 waves (wave = o-subtile, 8 n-subtiles), K-chunks 64.
__global__ __launch_bounds__(256) void final_gemm_mfma(
    const uint16_t* __restrict__ w5b,  // (512,512) bf16 row-major (o,c)
    const uint16_t* __restrict__ cat,  // (B*N,512) bf16
    float* __restrict__ out)           // (B,512,N) f32
{
    const int b  = blockIdx.z;
    const int o0 = blockIdx.y * 64;
    const int n0 = blockIdx.x * 128;
    const int t  = threadIdx.x;
    const int wave = t >> 6, lane = t & 63;
    const int col = lane & 15, quad = lane >> 4;

    __shared__ __align__(16) uint16_t As[64 * 72];   // w5 tile [o][k], +8 pad
    __shared__ __align__(16) uint16_t Bs[128 * 72];  // cat tile [n][k], +8 pad

    floatx4 acc[8];
    #pragma unroll
    for (int i = 0; i < 8; ++i) acc[i] = (floatx4){0.f, 0.f, 0.f, 0.f};

    const size_t arow_base = (size_t)o0 * 512;
    const size_t brow_base = ((size_t)b * NPTS + n0) * 512;

    for (int kc = 0; kc < 512; kc += 64) {
        #pragma unroll
        for (int i = 0; i < 2; ++i) {             // As: 512 short8
            const int idx = t + i * 256;          // 0..511
            const int row = idx >> 3;             // 0..63
            const int k8  = (idx & 7) * 8;        // 0..56
            *(short8*)&As[row * 72 + k8] =
                *(const short8*)&w5b[arow_base + (size_t)row * 512 + kc + k8];
        }
        #pragma unroll
        for (int i = 0; i < 4; ++i) {             // Bs: 1024 short8
            const int idx = t + i * 256;          // 0..1023
            const int row = idx >> 3;             // 0..127
            const int k8  = (idx & 7) * 8;
            *(short8*)&Bs[row * 72 + k8] =
                *(const short8*)&cat[brow_base + (size_t)row * 512 + kc + k8];
        }
        __syncthreads();
        #pragma unroll
        for (int kt = 0; kt < 2; ++kt) {
            const short8 af = *(const short8*)&As[(wave * 16 + col) * 72 + kt * 32 + quad * 8];
            #pragma unroll
            for (int ns = 0; ns < 8; ++ns) {
                const short8 bf = *(const short8*)&Bs[(ns * 16 + col) * 72 + kt * 32 + quad * 8];
                acc[ns] = __builtin_amdgcn_mfma_f32_16x16x32_bf16(af, bf, acc[ns], 0, 0, 0);
            }
        }
        __syncthreads();
    }

    #pragma unroll
    for (int ns = 0; ns < 8; ++ns) {
        #pragma unroll
        for (int r = 0; r < 4; ++r) {
            out[((size_t)b * 512 + o0 + wave * 16 + quad * 4 + r) * NPTS
                + n0 + ns * 16 + col] = fmaxf(acc[ns][r], 0.f);
        }
    }
}

// ---------------------------------------------------------------------------
extern "C" void kernel_launch(void* const* d_in, const int* in_sizes, int n_in,
                              void* d_out, int out_size, void* d_ws, size_t ws_size,
                              hipStream_t stream) {
    const float* x  = (const float*)d_in[0];  // (8,3,4096)
    const float* w1 = (const float*)d_in[1];  // (64,26)
    const float* w2 = (const float*)d_in[2];  // (64,64)
    const float* w3 = (const float*)d_in[3];  // (128,64)
    const float* w4 = (const float*)d_in[4];  // (256,128)
    const float* w5 = (const float*)d_in[5];  // (512,512)
    float* out = (float*)d_out;               // (8,512,4096) fp32

    // workspace layout (bytes):
    //   [0)         idx_ws   B*N*K int     = 2,621,440
    //   [2621440)   dist_ws  B*N*K f32     = 2,621,440
    //   [5242880)   cat_ws   B*N*512 bf16  = 33,554,432
    //   [38797312)  w5b bf16 (512x512)     = 524,288
    //   [72351744)  wf1 4 KB; wf2 8 KB; wf3 16 KB; wf4 64 KB
    char* ws = (char*)d_ws;
    int*      idx_ws  = (int*)ws;
    float*    dist_ws = (float*)(ws + 2621440);
    uint16_t* cat_ws  = (uint16_t*)(ws + 5242880);
    uint16_t* w5b     = (uint16_t*)(ws + 38797312);
    uint16_t* wf1     = (uint16_t*)(ws + 72351744);
    uint16_t* wf2     = (uint16_t*)(ws + 72351744 + 4096);
    uint16_t* wf3     = (uint16_t*)(ws + 72351744 + 4096 + 8192);
    uint16_t* wf4     = (uint16_t*)(ws + 72351744 + 4096 + 8192 + 16384);

    prep_wfrag<<<dim3(1), 256, 0, stream>>>(w1, wf1, 26,  4, 1);
    prep_wfrag<<<dim3(2), 256, 0, stream>>>(w2, wf2, 64,  4, 2);
    prep_wfrag<<<dim3(4), 256, 0, stream>>>(w3, wf3, 64,  8, 2);
    prep_wfrag<<<dim3(16), 256, 0, stream>>>(w4, wf4, 128, 16, 4);
    prep_w5bf<<<dim3(1024), 256, 0, stream>>>(w5, w5b);

    topk_kernel<<<dim3(NPTS / (WPB * QPW), NB), WPB * 64, 0, stream>>>(x, idx_ws, dist_ws);
    fused_mlp_mfma<<<dim3(NPTS / P, NB), 256, 0, stream>>>(
        x, idx_ws, dist_ws, wf1, wf2, wf3, wf4, cat_ws);
    final_gemm_mfma<<<dim3(NPTS / 128, 512 / 64, NB), 256, 0, stream>>>(w5b, cat_ws, out);
}

// Round 8
// 359.678 us; speedup vs baseline: 1.0423x; 1.0212x over previous
//
#include <hip/hip_runtime.h>
#include <cstdint>
#include <cstddef>

#define NB   8
#define NPTS 4096
#define KNN  20
#define P    4   // points per fused-MLP block (M = P*KNN = 80 rows = 5 m-tiles)
#define QPW  4   // query points per wave in topk
#define WPB  8   // waves per topk block (512 threads)

typedef __attribute__((ext_vector_type(8))) short    short8;
typedef __attribute__((ext_vector_type(4))) float    floatx4;

__device__ __forceinline__ uint16_t f2bf(float f) {
    uint32_t u = __float_as_uint(f);
    uint32_t r = (u + 0x7FFFu + ((u >> 16) & 1u)) >> 16;   // RNE
    return (uint16_t)r;
}

// packed f32->bf16 RNE (same rounding as f2bf), 1 instr for 2 values
__device__ __forceinline__ uint32_t cvtpk_bf16(float lo, float hi) {
    uint32_t r;
    asm("v_cvt_pk_bf16_f32 %0, %1, %2" : "=v"(r) : "v"(lo), "v"(hi));
    return r;
}

#define NEGINF __int_as_float((int)0xFF800000)

// pin a wave-uniform float to an SGPR (value identical; frees VGPRs)
__device__ __forceinline__ float rfl_f32(float v) {
    return __uint_as_float((uint32_t)__builtin_amdgcn_readfirstlane(__float_as_uint(v)));
}

// DPP f32 max step: invalid source lanes fall back to own value (idempotent)
template <int CTRL>
__device__ __forceinline__ float dpp_maxf(float v) {
    int o = __builtin_amdgcn_update_dpp(__float_as_int(v), __float_as_int(v),
                                        CTRL, 0xF, 0xF, false);
    return fmaxf(v, __int_as_float(o));
}
// wave64 f32 max-reduce, result broadcast via readlane 63
__device__ __forceinline__ float wave_max_f32(float v) {
    v = dpp_maxf<0x111>(v);   // row_shr:1
    v = dpp_maxf<0x112>(v);   // row_shr:2
    v = dpp_maxf<0x114>(v);   // row_shr:4
    v = dpp_maxf<0x118>(v);   // row_shr:8
    v = dpp_maxf<0x142>(v);   // row_bcast:15
    v = dpp_maxf<0x143>(v);   // row_bcast:31 -> lane 63 has max
    return __int_as_float(__builtin_amdgcn_readlane(__float_as_int(v), 63));
}

// ---------------------------------------------------------------------------
// Top-20. 512-thread blocks (8 waves); point cloud staged planar in LDS.
// One wave per QPW=4 points, lane l owns columns m%64==l (m = j*64+l).
// s = fma(2,dot,-sqn) - sqm is bitwise == ((2*dot)-sqn)-sqm (2*dot exact),
// so pair values match all prior passing rounds. Lane-local sorted top-3
// (med3 insert) + index regs; k-outer/p-inner selection; rare refill.
__global__ __launch_bounds__(512, 6) void topk_kernel(
    const float* __restrict__ x,      // (B,3,N)
    int*   __restrict__ idx_out,      // (B,N,K)
    float* __restrict__ dist_out)     // (B,N,K)
{
    const int t = threadIdx.x;
    const int wave = t >> 6, l = t & 63;
    const int b = blockIdx.y;

    __shared__ float xs[NPTS], ys[NPTS], zs[NPTS];   // 48 KB planar
    {
        const float* xb = x + (size_t)b * 3 * NPTS;
        for (int i = t; i < NPTS; i += WPB * 64) {
            xs[i] = xb[i];
            ys[i] = xb[NPTS + i];
            zs[i] = xb[2 * NPTS + i];
        }
    }
    __syncthreads();

    const int nbase = (blockIdx.x * WPB + wave) * QPW;

    float xn0[QPW], xn1[QPW], xn2[QPW], sqn[QPW];
    float V0[QPW], V1[QPW], V2[QPW];
    int   J0[QPW], J1[QPW], J2[QPW];
    int   my_m[QPW];

    #pragma unroll
    for (int p = 0; p < QPW; ++p) {
        const int n = nbase + p;
        const float qx = xs[n], qy = ys[n], qz = zs[n];
        xn0[p] = rfl_f32(qx); xn1[p] = rfl_f32(qy); xn2[p] = rfl_f32(qz);
        sqn[p] = rfl_f32(fmaf(qz, qz, fmaf(qy, qy, qx * qx)));
        V0[p] = NEGINF; V1[p] = NEGINF; V2[p] = NEGINF;
        J0[p] = 0; J1[p] = 0; J2[p] = 0;
        my_m[p] = 0;
    }

    #pragma unroll 2
    for (int j = 0; j < 64; ++j) {
        const float px = xs[j * 64 + l], py = ys[j * 64 + l], pz = zs[j * 64 + l];
        const float sqm = fmaf(pz, pz, fmaf(py, py, px * px));   // == old prep .w
        #pragma unroll
        for (int p = 0; p < QPW; ++p) {
            const float dot = fmaf(xn2[p], pz, fmaf(xn1[p], py, xn0[p] * px));
            const float s = fmaf(2.0f, dot, -sqn[p]) - sqm;  // bitwise == prior
            const bool c0 = s > V0[p], c1 = s > V1[p], c2 = s > V2[p];
            const float nV2 = __builtin_amdgcn_fmed3f(V1[p], V2[p], s);
            const float nV1 = __builtin_amdgcn_fmed3f(V0[p], V1[p], s);
            V0[p] = fmaxf(V0[p], s);
            V1[p] = nV1; V2[p] = nV2;
            const int tA = c1 ? J1[p] : j;
            J2[p] = c2 ? tA : J2[p];
            const int tB = c0 ? J0[p] : j;
            J1[p] = c1 ? tB : J1[p];
            J0[p] = c0 ? j : J0[p];
        }
    }

    for (int k = 0; k < KNN; ++k) {
        // rare refill: rebuild top-3 of unconsumed cols (consumed set derived
        // from the k prior winners, which live in my_m[p] of lanes 0..k-1)
        #pragma unroll
        for (int p = 0; p < QPW; ++p) {
            if (V0[p] == NEGINF) {
                unsigned long long cons = 0ull;
                for (int i = 0; i < k; ++i) {
                    const int mw = __builtin_amdgcn_readlane(my_m[p], i);
                    if ((mw & 63) == l) cons |= 1ull << (mw >> 6);
                }
                V1[p] = NEGINF; V2[p] = NEGINF;
                for (int j = 0; j < 64; ++j) {
                    const float px = xs[j * 64 + l], py = ys[j * 64 + l], pz = zs[j * 64 + l];
                    const float sqm = fmaf(pz, pz, fmaf(py, py, px * px));
                    const float dot = fmaf(xn2[p], pz, fmaf(xn1[p], py, xn0[p] * px));
                    float s = fmaf(2.0f, dot, -sqn[p]) - sqm;
                    if ((cons >> j) & 1ull) s = NEGINF;
                    const bool c0 = s > V0[p], c1 = s > V1[p], c2 = s > V2[p];
                    const float nV2 = __builtin_amdgcn_fmed3f(V1[p], V2[p], s);
                    const float nV1 = __builtin_amdgcn_fmed3f(V0[p], V1[p], s);
                    V0[p] = fmaxf(V0[p], s);
                    V1[p] = nV1; V2[p] = nV2;
                    const int tA = c1 ? J1[p] : j;
                    J2[p] = c2 ? tA : J2[p];
                    const int tB = c0 ? J0[p] : j;
                    J1[p] = c1 ? tB : J1[p];
                    J0[p] = c0 ? j : J0[p];
                }
            }
        }
        // 4 independent DPP reduce chains in flight
        float wv[QPW];
        #pragma unroll
        for (int p = 0; p < QPW; ++p) wv[p] = wave_max_f32(V0[p]);
        #pragma unroll
        for (int p = 0; p < QPW; ++p) {
            const unsigned long long own = __ballot(V0[p] == wv[p]);
            const int owner = (int)__builtin_ctzll(own);
            const int jwin  = __builtin_amdgcn_readlane(J0[p], owner);
            const int m     = jwin * 64 + owner;
            if (l == k) my_m[p] = m;
            if (l == owner) {                 // owner pops its head
                V0[p] = V1[p]; V1[p] = V2[p]; V2[p] = NEGINF;
                J0[p] = J1[p]; J1[p] = J2[p];
            }
        }
    }

    #pragma unroll
    for (int p = 0; p < QPW; ++p) {
        if (l < KNN) {
            const int n = nbase + p;
            const int m = my_m[p];
            const float d0 = xs[m] - xn0[p], d1 = ys[m] - xn1[p], d2 = zs[m] - xn2[p];
            const float dist = sqrtf(((d0 * d0 + d1 * d1) + d2 * d2) + 1e-12f);
            const size_t base = ((size_t)b * NPTS + n) * KNN + l;
            idx_out[base]  = m;
            dist_out[base] = dist;
        }
    }
}

// ---------------------------------------------------------------------------
// Merged weight prep (one dispatch): w5 bf16 cast + fragment-ordered bf16
// B-operands for all four conv layers. i = (nt*KT + kt)*64 + lane, identical
// mapping to the per-layer kernels of passing rounds.
__global__ __launch_bounds__(256) void prep_all(
    const float* __restrict__ w1, const float* __restrict__ w2,
    const float* __restrict__ w3, const float* __restrict__ w4,
    const float* __restrict__ w5,
    uint16_t* __restrict__ wf1, uint16_t* __restrict__ wf2,
    uint16_t* __restrict__ wf3, uint16_t* __restrict__ wf4,
    uint16_t* __restrict__ w5b)
{
    int blk = blockIdx.x;
    const int t = threadIdx.x;
    if (blk < 1024) {                       // w5 (512x512) -> bf16
        const int i = blk * 256 + t;
        w5b[i] = f2bf(w5[i]);
        return;
    }
    blk -= 1024;
    const float* w; uint16_t* frag; int C, NT, KT, base;
    if (blk < 1)       { w = w1; frag = wf1; C = 26;  NT = 4;  KT = 1; base = blk; }
    else if (blk < 3)  { w = w2; frag = wf2; C = 64;  NT = 4;  KT = 2; base = blk - 1; }
    else if (blk < 7)  { w = w3; frag = wf3; C = 64;  NT = 8;  KT = 2; base = blk - 3; }
    else               { w = w4; frag = wf4; C = 128; NT = 16; KT = 4; base = blk - 7; }
    const int i = base * 256 + t;           // one (nt,kt,lane)
    if (i >= NT * KT * 64) return;
    const int lane = i & 63;
    const int kt   = (i >> 6) % KT;
    const int nt   = (i >> 6) / KT;
    const int n    = nt * 16 + (lane & 15);
    const int c0   = kt * 32 + (lane >> 4) * 8;
    uint16_t o[8];
    #pragma unroll
    for (int j = 0; j < 8; ++j) {
        const int c = c0 + j;
        o[j] = (c < C) ? f2bf(w[(size_t)n * C + c]) : (uint16_t)0;
    }
    uint16_t* dst = frag + (size_t)i * 8;
    #pragma unroll
    for (int j = 0; j < 8; ++j) dst[j] = o[j];
}

// ---------------------------------------------------------------------------
// One MFMA conv layer: in (LDS bf16, [80][IN_STRIDE]) x wf -> out (LDS bf16,
// [80][OUT_STRIDE], relu'd). bfrag preloaded for all ni; af hoisted out of
// the ni loop. Epilogue converts via packed v_cvt_pk_bf16_f32 (RNE == f2bf).
template <int NT_TOT, int KT, int IN_STRIDE, int OUT_STRIDE>
__device__ __forceinline__ void mfma_layer(const uint16_t* __restrict__ in,
                                           uint16_t* __restrict__ out,
                                           const uint16_t* __restrict__ wf,
                                           int wave, int lane) {
    constexpr int NT_W = NT_TOT / 4;
    const int col = lane & 15, quad = lane >> 4;
    short8 bfrag[NT_W][KT];
    #pragma unroll
    for (int ni = 0; ni < NT_W; ++ni)
        #pragma unroll
        for (int k = 0; k < KT; ++k)
            bfrag[ni][k] = *(const short8*)(wf +
                ((size_t)((wave * NT_W + ni) * KT + k) * 64 + lane) * 8);
    #pragma unroll
    for (int mt = 0; mt < 5; ++mt) {
        short8 af[KT];
        #pragma unroll
        for (int k = 0; k < KT; ++k)
            af[k] = *(const short8*)(in + (mt * 16 + col) * IN_STRIDE + k * 32 + quad * 8);
        #pragma unroll
        for (int ni = 0; ni < NT_W; ++ni) {
            floatx4 acc = {0.f, 0.f, 0.f, 0.f};
            #pragma unroll
            for (int k = 0; k < KT; ++k)
                acc = __builtin_amdgcn_mfma_f32_16x16x32_bf16(af[k], bfrag[ni][k], acc, 0, 0, 0);
            const int nt = wave * NT_W + ni;
            const int rowb = mt * 16 + quad * 4;
            const uint32_t pk01 = cvtpk_bf16(fmaxf(acc[0], 0.f), fmaxf(acc[1], 0.f));
            const uint32_t pk23 = cvtpk_bf16(fmaxf(acc[2], 0.f), fmaxf(acc[3], 0.f));
            out[(rowb + 0) * OUT_STRIDE + nt * 16 + col] = (uint16_t)pk01;
            out[(rowb + 1) * OUT_STRIDE + nt * 16 + col] = (uint16_t)(pk01 >> 16);
            out[(rowb + 2) * OUT_STRIDE + nt * 16 + col] = (uint16_t)pk23;
            out[(rowb + 3) * OUT_STRIDE + nt * 16 + col] = (uint16_t)(pk23 >> 16);
        }
    }
}

// max over the 20 k-rows of each point -> bf16 into cat (non-negative values)
template <int O, int STRIDE>
__device__ __forceinline__ void maxk(const uint16_t* __restrict__ h,
                                     uint16_t* __restrict__ cat_ws, int catoff,
                                     int t, int b, int n0) {
    constexpr int G = O / 8;
    if (t < P * G) {
        const int p = t / G, g = t % G;
        uint16_t mx[8];
        #pragma unroll
        for (int j = 0; j < 8; ++j) mx[j] = 0;
        for (int k = 0; k < KNN; ++k) {
            const uint16_t* row = h + (p * KNN + k) * STRIDE + g * 8;
            #pragma unroll
            for (int j = 0; j < 8; ++j) mx[j] = row[j] > mx[j] ? row[j] : mx[j];
        }
        uint16_t* dst = cat_ws + ((size_t)b * NPTS + n0 + p) * 512 + catoff + g * 8;
        *(short8*)dst = *(const short8*)mx;
    }
}

// ---------------------------------------------------------------------------
// Fused MLP, MFMA edition. Block = 4 points, 256 threads (4 waves).
// (Exact R4-passing body.)
__global__ __launch_bounds__(256) void fused_mlp_mfma(
    const float* __restrict__ x,
    const int*   __restrict__ idx_ws,
    const float* __restrict__ dist_ws,
    const uint16_t* __restrict__ wf1,
    const uint16_t* __restrict__ wf2,
    const uint16_t* __restrict__ wf3,
    const uint16_t* __restrict__ wf4,
    uint16_t* __restrict__ cat_ws)      // (B*N, 512) bf16
{
    const int n0 = blockIdx.x * P, b = blockIdx.y, t = threadIdx.x;
    const int wave = t >> 6, lane = t & 63;

    __shared__ __align__(16) uint16_t bufA[12800];  // feat(3200) / h2(5760) / slabs(12800)
    __shared__ __align__(16) uint16_t bufB[10880];  // h1(5760) / h3(10880)

    // ---- stage feat: [80][40] bf16, cols 0-2 xc, 3-5 nbr, 6-25 dist, 26+ zero
    for (int i = t; i < 1600; i += 256) ((uint32_t*)bufA)[i] = 0;
    __syncthreads();
    {
        const float* xb = x + (size_t)b * 3 * NPTS;
        if (t < P * KNN) {
            const int p = t / KNN, k = t % KNN;
            const int n = n0 + p;
            const size_t base = ((size_t)b * NPTS + n) * KNN + k;
            const int   m = idx_ws[base];
            const float d = dist_ws[base];
            uint16_t* fr = bufA + t * 40;
            fr[0] = f2bf(xb[n]);        fr[1] = f2bf(xb[NPTS + n]);
            fr[2] = f2bf(xb[2 * NPTS + n]);
            fr[3] = f2bf(xb[m]);        fr[4] = f2bf(xb[NPTS + m]);
            fr[5] = f2bf(xb[2 * NPTS + m]);
            const uint16_t db = f2bf(d);
            #pragma unroll
            for (int j = 0; j < KNN; ++j) bufA[(p * KNN + j) * 40 + 6 + k] = db;
        }
    }
    __syncthreads();

    // ---- L1: feat(A) -> h1(B)
    mfma_layer<4, 1, 40, 72>(bufA, bufB, wf1, wave, lane);
    __syncthreads();

    // ---- L2: h1(B) -> h2(A); x1 = maxk(h1)
    maxk<64, 72>(bufB, cat_ws, 0, t, b, n0);
    mfma_layer<4, 2, 72, 72>(bufB, bufA, wf2, wave, lane);
    __syncthreads();

    // ---- L3: h2(A) -> h3(B); x2 = maxk(h2)
    maxk<64, 72>(bufA, cat_ws, 64, t, b, n0);
    mfma_layer<8, 2, 72, 136>(bufA, bufB, wf3, wave, lane);
    __syncthreads();

    // ---- L4: h3(B) -> per-wave slab (A) -> relu+max -> cat; x3 = maxk(h3)
    maxk<128, 136>(bufB, cat_ws, 128, t, b, n0);
    {
        float* slab = (float*)bufA + wave * 1600;   // [80][20] f32, wave-private
        const int col = lane & 15, quad = lane >> 4;
        #pragma unroll
        for (int ni = 0; ni < 4; ++ni) {
            const int nt = wave * 4 + ni;
            short8 bfrag[4];
            #pragma unroll
            for (int k = 0; k < 4; ++k)
                bfrag[k] = *(const short8*)(wf4 + ((size_t)(nt * 4 + k) * 64 + lane) * 8);
            #pragma unroll
            for (int mt = 0; mt < 5; ++mt) {
                floatx4 acc = {0.f, 0.f, 0.f, 0.f};
                #pragma unroll
                for (int k = 0; k < 4; ++k) {
                    const short8 af = *(const short8*)(bufB + (mt * 16 + col) * 136
                                                           + k * 32 + quad * 8);
                    acc = __builtin_amdgcn_mfma_f32_16x16x32_bf16(af, bfrag[k], acc, 0, 0, 0);
                }
                #pragma unroll
                for (int r = 0; r < 4; ++r)
                    slab[(mt * 16 + quad * 4 + r) * 20 + col] = fmaxf(acc[r], 0.f);
            }
            const int p = lane >> 4, grp = (lane >> 2) & 3, kq = lane & 3;
            floatx4 mx = {0.f, 0.f, 0.f, 0.f};
            #pragma unroll
            for (int i = 0; i < 5; ++i) {
                const floatx4 v = *(const floatx4*)&slab[(p * KNN + kq * 5 + i) * 20 + grp * 4];
                mx[0] = fmaxf(mx[0], v[0]); mx[1] = fmaxf(mx[1], v[1]);
                mx[2] = fmaxf(mx[2], v[2]); mx[3] = fmaxf(mx[3], v[3]);
            }
            #pragma unroll
            for (int r = 0; r < 4; ++r) {
                mx[r] = fmaxf(mx[r], __shfl_xor(mx[r], 1));
                mx[r] = fmaxf(mx[r], __shfl_xor(mx[r], 2));
            }
            if (kq == 0) {
                const uint32_t p01 = cvtpk_bf16(mx[0], mx[1]);
                const uint32_t p23 = cvtpk_bf16(mx[2], mx[3]);
                uint32_t* dst = (uint32_t*)(cat_ws + ((size_t)b * NPTS + n0 + p) * 512
                              + 256 + nt * 16 + grp * 4);
                dst[0] = p01; dst[1] = p23;
            }
        }
    }
}

// ---------------------------------------------------------------------------
// Final GEMM, MFMA: out[b,o,n] = relu( sum_c w5[o,c] * cat[b,n,c] ).
// 64(o) x 128(n) tile, 4 waves (wave = o-subtile, 8 n-subtiles), K-chunks 64.
__global__ __launch_bounds__(256) void final_gemm_mfma(
    const uint16_t* __restrict__ w5b,  // (512,512) bf16 row-major (o,c)
    const uint16_t* __restrict__ cat,  // (B*N,512) bf16
    float* __restrict__ out)           // (B,512,N) f32
{
    const int b  = blockIdx.z;
    const int o0 = blockIdx.y * 64;
    const int n0 = blockIdx.x * 128;
    const int t  = threadIdx.x;
    const int wave = t >> 6, lane = t & 63;
    const int col = lane & 15, quad = lane >> 4;

    __shared__ __align__(16) uint16_t As[64 * 72];   // w5 tile [o][k], +8 pad
    __shared__ __align__(16) uint16_t Bs[128 * 72];  // cat tile [n][k], +8 pad

    floatx4 acc[8];
    #pragma unroll
    for (int i = 0; i < 8; ++i) acc[i] = (floatx4){0.f, 0.f, 0.f, 0.f};

    const size_t arow_base = (size_t)o0 * 512;
    const size_t brow_base = ((size_t)b * NPTS + n0) * 512;

    for (int kc = 0; kc < 512; kc += 64) {
        #pragma unroll
        for (int i = 0; i < 2; ++i) {             // As: 512 short8
            const int idx = t + i * 256;          // 0..511
            const int row = idx >> 3;             // 0..63
            const int k8  = (idx & 7) * 8;        // 0..56
            *(short8*)&As[row * 72 + k8] =
                *(const short8*)&w5b[arow_base + (size_t)row * 512 + kc + k8];
        }
        #pragma unroll
        for (int i = 0; i < 4; ++i) {             // Bs: 1024 short8
            const int idx = t + i * 256;          // 0..1023
            const int row = idx >> 3;             // 0..127
            const int k8  = (idx & 7) * 8;
            *(short8*)&Bs[row * 72 + k8] =
                *(const short8*)&cat[brow_base + (size_t)row * 512 + kc + k8];
        }
        __syncthreads();
        #pragma unroll
        for (int kt = 0; kt < 2; ++kt) {
            const short8 af = *(const short8*)&As[(wave * 16 + col) * 72 + kt * 32 + quad * 8];
            #pragma unroll
            for (int ns = 0; ns < 8; ++ns) {
                const short8 bf = *(const short8*)&Bs[(ns * 16 + col) * 72 + kt * 32 + quad * 8];
                acc[ns] = __builtin_amdgcn_mfma_f32_16x16x32_bf16(af, bf, acc[ns], 0, 0, 0);
            }
        }
        __syncthreads();
    }

    #pragma unroll
    for (int ns = 0; ns < 8; ++ns) {
        #pragma unroll
        for (int r = 0; r < 4; ++r) {
            out[((size_t)b * 512 + o0 + wave * 16 + quad * 4 + r) * NPTS
                + n0 + ns * 16 + col] = fmaxf(acc[ns][r], 0.f);
        }
    }
}

// ---------------------------------------------------------------------------
extern "C" void kernel_launch(void* const* d_in, const int* in_sizes, int n_in,
                              void* d_out, int out_size, void* d_ws, size_t ws_size,
                              hipStream_t stream) {
    const float* x  = (const float*)d_in[0];  // (8,3,4096)
    const float* w1 = (const float*)d_in[1];  // (64,26)
    const float* w2 = (const float*)d_in[2];  // (64,64)
    const float* w3 = (const float*)d_in[3];  // (128,64)
    const float* w4 = (const float*)d_in[4];  // (256,128)
    const float* w5 = (const float*)d_in[5];  // (512,512)
    float* out = (float*)d_out;               // (8,512,4096) fp32

    // workspace layout (bytes):
    //   [0)         idx_ws   B*N*K int     = 2,621,440
    //   [2621440)   dist_ws  B*N*K f32     = 2,621,440
    //   [5242880)   cat_ws   B*N*512 bf16  = 33,554,432
    //   [38797312)  w5b bf16 (512x512)     = 524,288
    //   [72351744)  wf1 4 KB; wf2 8 KB; wf3 16 KB; wf4 64 KB
    char* ws = (char*)d_ws;
    int*      idx_ws  = (int*)ws;
    float*    dist_ws = (float*)(ws + 2621440);
    uint16_t* cat_ws  = (uint16_t*)(ws + 5242880);
    uint16_t* w5b     = (uint16_t*)(ws + 38797312);
    uint16_t* wf1     = (uint16_t*)(ws + 72351744);
    uint16_t* wf2     = (uint16_t*)(ws + 72351744 + 4096);
    uint16_t* wf3     = (uint16_t*)(ws + 72351744 + 4096 + 8192);
    uint16_t* wf4     = (uint16_t*)(ws + 72351744 + 4096 + 8192 + 16384);

    prep_all<<<dim3(1024 + 23), 256, 0, stream>>>(w1, w2, w3, w4, w5,
                                                  wf1, wf2, wf3, wf4, w5b);

    topk_kernel<<<dim3(NPTS / (WPB * QPW), NB), WPB * 64, 0, stream>>>(x, idx_ws, dist_ws);
    fused_mlp_mfma<<<dim3(NPTS / P, NB), 256, 0, stream>>>(
        x, idx_ws, dist_ws, wf1, wf2, wf3, wf4, cat_ws);
    final_gemm_mfma<<<dim3(NPTS / 128, 512 / 64, NB), 256, 0, stream>>>(w5b, cat_ws, out);
}

// Round 9
// 353.465 us; speedup vs baseline: 1.0606x; 1.0176x over previous
//
#include <hip/hip_runtime.h>
#include <cstdint>
#include <cstddef>

#define NB   8
#define NPTS 4096
#define KNN  20
#define P    4   // points per fused-MLP block (M = P*KNN = 80 rows = 5 m-tiles)
#define QPW  4   // query points per wave in topk

typedef __attribute__((ext_vector_type(8))) short    short8;
typedef __attribute__((ext_vector_type(4))) float    floatx4;

__device__ __forceinline__ uint16_t f2bf(float f) {
    uint32_t u = __float_as_uint(f);
    uint32_t r = (u + 0x7FFFu + ((u >> 16) & 1u)) >> 16;   // RNE
    return (uint16_t)r;
}

// packed f32->bf16 RNE (same rounding as f2bf), 1 instr for 2 values
__device__ __forceinline__ uint32_t cvtpk_bf16(float lo, float hi) {
    uint32_t r;
    asm("v_cvt_pk_bf16_f32 %0, %1, %2" : "=v"(r) : "v"(lo), "v"(hi));
    return r;
}

#define NEGINF __int_as_float((int)0xFF800000)

// DPP f32 max step: invalid source lanes fall back to own value (idempotent)
template <int CTRL>
__device__ __forceinline__ float dpp_maxf(float v) {
    int o = __builtin_amdgcn_update_dpp(__float_as_int(v), __float_as_int(v),
                                        CTRL, 0xF, 0xF, false);
    return fmaxf(v, __int_as_float(o));
}
// wave64 f32 max-reduce, result broadcast via readlane 63
__device__ __forceinline__ float wave_max_f32(float v) {
    v = dpp_maxf<0x111>(v);   // row_shr:1
    v = dpp_maxf<0x112>(v);   // row_shr:2
    v = dpp_maxf<0x114>(v);   // row_shr:4
    v = dpp_maxf<0x118>(v);   // row_shr:8
    v = dpp_maxf<0x142>(v);   // row_bcast:15
    v = dpp_maxf<0x143>(v);   // row_bcast:31 -> lane 63 has max
    return __int_as_float(__builtin_amdgcn_readlane(__float_as_int(v), 63));
}

// ---------------------------------------------------------------------------
// Top-20: R1's passing structure. One wave per QPW=4 points, lane l owns
// columns m%64==l (m = j*64+l). float4 global loads (L2/L3-served; LDS
// staging measured no faster). s = fma(2,dot,-sqn) - sqm bitwise == prior
// rounds (2*dot exact). Lane-local sorted top-3 (med3 insert) + index regs +
// persistent consumed bitmap; per-round winner via DPP max + ballot; rare
// refill on >3 pops.
__global__ __launch_bounds__(256) void topk_kernel(
    const float4* __restrict__ xyzs,  // (B,N) packed (x,y,z,sq)
    int*   __restrict__ idx_out,      // (B,N,K)
    float* __restrict__ dist_out)     // (B,N,K)
{
    const int t = threadIdx.x;
    const int wave = t >> 6, l = t & 63;
    const int nbase = (blockIdx.x * 4 + wave) * QPW;
    const int b = blockIdx.y;
    const float4* xq = xyzs + (size_t)b * NPTS;

    float xn0[QPW], xn1[QPW], xn2[QPW], sqn[QPW];
    float V0[QPW], V1[QPW], V2[QPW];
    int   J0[QPW], J1[QPW], J2[QPW];
    unsigned long long consumed[QPW];
    int   my_m[QPW];

    #pragma unroll
    for (int p = 0; p < QPW; ++p) {
        const float4 pn = xq[nbase + p];
        xn0[p] = pn.x; xn1[p] = pn.y; xn2[p] = pn.z; sqn[p] = pn.w;
        V0[p] = NEGINF; V1[p] = NEGINF; V2[p] = NEGINF;
        J0[p] = 0; J1[p] = 0; J2[p] = 0;
        consumed[p] = 0ull;
        my_m[p] = 0;
    }

    #pragma unroll 4
    for (int j = 0; j < 64; ++j) {
        const float4 pm = xq[j * 64 + l];
        #pragma unroll
        for (int p = 0; p < QPW; ++p) {
            const float dot = fmaf(xn2[p], pm.z, fmaf(xn1[p], pm.y, xn0[p] * pm.x));
            const float s = fmaf(2.0f, dot, -sqn[p]) - pm.w;  // bitwise == prior
            const bool c0 = s > V0[p], c1 = s > V1[p], c2 = s > V2[p];
            const float nV2 = __builtin_amdgcn_fmed3f(V1[p], V2[p], s);
            const float nV1 = __builtin_amdgcn_fmed3f(V0[p], V1[p], s);
            V0[p] = fmaxf(V0[p], s);
            V1[p] = nV1; V2[p] = nV2;
            const int tA = c1 ? J1[p] : j;
            J2[p] = c2 ? tA : J2[p];
            const int tB = c0 ? J0[p] : j;
            J1[p] = c1 ? tB : J1[p];
            J0[p] = c0 ? j : J0[p];
        }
    }

    #pragma unroll
    for (int p = 0; p < QPW; ++p) {
        for (int k = 0; k < KNN; ++k) {
            if (V0[p] == NEGINF) {   // rare refill: rebuild top-3 of unconsumed
                V1[p] = NEGINF; V2[p] = NEGINF;
                for (int j = 0; j < 64; ++j) {
                    const float4 pm = xq[j * 64 + l];
                    const float dot = fmaf(xn2[p], pm.z, fmaf(xn1[p], pm.y, xn0[p] * pm.x));
                    float s = fmaf(2.0f, dot, -sqn[p]) - pm.w;
                    if ((consumed[p] >> j) & 1ull) s = NEGINF;
                    const bool c0 = s > V0[p], c1 = s > V1[p], c2 = s > V2[p];
                    const float nV2 = __builtin_amdgcn_fmed3f(V1[p], V2[p], s);
                    const float nV1 = __builtin_amdgcn_fmed3f(V0[p], V1[p], s);
                    V0[p] = fmaxf(V0[p], s);
                    V1[p] = nV1; V2[p] = nV2;
                    const int tA = c1 ? J1[p] : j;
                    J2[p] = c2 ? tA : J2[p];
                    const int tB = c0 ? J0[p] : j;
                    J1[p] = c1 ? tB : J1[p];
                    J0[p] = c0 ? j : J0[p];
                }
            }
            const float w = wave_max_f32(V0[p]);
            const unsigned long long own = __ballot(V0[p] == w);
            const int owner = (int)__builtin_ctzll(own);
            const int jwin  = __builtin_amdgcn_readlane(J0[p], owner);
            const int m     = jwin * 64 + owner;
            if (l == k) my_m[p] = m;
            if (l == owner) {                 // owner pops its head
                consumed[p] |= 1ull << J0[p];
                V0[p] = V1[p]; V1[p] = V2[p]; V2[p] = NEGINF;
                J0[p] = J1[p]; J1[p] = J2[p];
            }
        }
    }

    #pragma unroll
    for (int p = 0; p < QPW; ++p) {
        if (l < KNN) {
            const int n = nbase + p;
            const float4 pm = xq[my_m[p]];
            const float d0 = pm.x - xn0[p], d1 = pm.y - xn1[p], d2 = pm.z - xn2[p];
            const float dist = sqrtf(((d0 * d0 + d1 * d1) + d2 * d2) + 1e-12f);
            const size_t base = ((size_t)b * NPTS + n) * KNN + l;
            idx_out[base]  = my_m[p];
            dist_out[base] = dist;
        }
    }
}

// ---------------------------------------------------------------------------
// Merged prep (one dispatch): w5 bf16 cast + fragment-ordered bf16 B-operands
// for all four conv layers + xyzs (x,y,z,||x||^2) pack. All mappings identical
// to the separate passing kernels.
__global__ __launch_bounds__(256) void prep_all(
    const float* __restrict__ x,
    const float* __restrict__ w1, const float* __restrict__ w2,
    const float* __restrict__ w3, const float* __restrict__ w4,
    const float* __restrict__ w5,
    uint16_t* __restrict__ wf1, uint16_t* __restrict__ wf2,
    uint16_t* __restrict__ wf3, uint16_t* __restrict__ wf4,
    uint16_t* __restrict__ w5b,
    float4* __restrict__ xyzs)
{
    int blk = blockIdx.x;
    const int t = threadIdx.x;
    if (blk < 1024) {                       // w5 (512x512) -> bf16
        const int i = blk * 256 + t;
        w5b[i] = f2bf(w5[i]);
        return;
    }
    blk -= 1024;
    if (blk >= 23) {                        // xyzs pack (B*N = 32768 threads)
        const int i = (blk - 23) * 256 + t;
        if (i < NB * NPTS) {
            const int b = i / NPTS, n = i - b * NPTS;
            const float* xb = x + (size_t)b * 3 * NPTS;
            const float x0 = xb[n], x1 = xb[NPTS + n], x2 = xb[2 * NPTS + n];
            float4 v;
            v.x = x0; v.y = x1; v.z = x2;
            v.w = fmaf(x2, x2, fmaf(x1, x1, x0 * x0));
            xyzs[i] = v;
        }
        return;
    }
    const float* w; uint16_t* frag; int C, NT, KT, base;
    if (blk < 1)       { w = w1; frag = wf1; C = 26;  NT = 4;  KT = 1; base = blk; }
    else if (blk < 3)  { w = w2; frag = wf2; C = 64;  NT = 4;  KT = 2; base = blk - 1; }
    else if (blk < 7)  { w = w3; frag = wf3; C = 64;  NT = 8;  KT = 2; base = blk - 3; }
    else               { w = w4; frag = wf4; C = 128; NT = 16; KT = 4; base = blk - 7; }
    const int i = base * 256 + t;           // one (nt,kt,lane)
    if (i >= NT * KT * 64) return;
    const int lane = i & 63;
    const int kt   = (i >> 6) % KT;
    const int nt   = (i >> 6) / KT;
    const int n    = nt * 16 + (lane & 15);
    const int c0   = kt * 32 + (lane >> 4) * 8;
    uint16_t o[8];
    #pragma unroll
    for (int j = 0; j < 8; ++j) {
        const int c = c0 + j;
        o[j] = (c < C) ? f2bf(w[(size_t)n * C + c]) : (uint16_t)0;
    }
    uint16_t* dst = frag + (size_t)i * 8;
    #pragma unroll
    for (int j = 0; j < 8; ++j) dst[j] = o[j];
}

// ---------------------------------------------------------------------------
// One MFMA conv layer: in (LDS bf16, [80][IN_STRIDE]) x wf -> out (LDS bf16,
// [80][OUT_STRIDE], relu'd). bfrag preloaded for all ni; af hoisted out of
// the ni loop. Epilogue converts via packed v_cvt_pk_bf16_f32 (RNE == f2bf).
template <int NT_TOT, int KT, int IN_STRIDE, int OUT_STRIDE>
__device__ __forceinline__ void mfma_layer(const uint16_t* __restrict__ in,
                                           uint16_t* __restrict__ out,
                                           const uint16_t* __restrict__ wf,
                                           int wave, int lane) {
    constexpr int NT_W = NT_TOT / 4;
    const int col = lane & 15, quad = lane >> 4;
    short8 bfrag[NT_W][KT];
    #pragma unroll
    for (int ni = 0; ni < NT_W; ++ni)
        #pragma unroll
        for (int k = 0; k < KT; ++k)
            bfrag[ni][k] = *(const short8*)(wf +
                ((size_t)((wave * NT_W + ni) * KT + k) * 64 + lane) * 8);
    #pragma unroll
    for (int mt = 0; mt < 5; ++mt) {
        short8 af[KT];
        #pragma unroll
        for (int k = 0; k < KT; ++k)
            af[k] = *(const short8*)(in + (mt * 16 + col) * IN_STRIDE + k * 32 + quad * 8);
        #pragma unroll
        for (int ni = 0; ni < NT_W; ++ni) {
            floatx4 acc = {0.f, 0.f, 0.f, 0.f};
            #pragma unroll
            for (int k = 0; k < KT; ++k)
                acc = __builtin_amdgcn_mfma_f32_16x16x32_bf16(af[k], bfrag[ni][k], acc, 0, 0, 0);
            const int nt = wave * NT_W + ni;
            const int rowb = mt * 16 + quad * 4;
            const uint32_t pk01 = cvtpk_bf16(fmaxf(acc[0], 0.f), fmaxf(acc[1], 0.f));
            const uint32_t pk23 = cvtpk_bf16(fmaxf(acc[2], 0.f), fmaxf(acc[3], 0.f));
            out[(rowb + 0) * OUT_STRIDE + nt * 16 + col] = (uint16_t)pk01;
            out[(rowb + 1) * OUT_STRIDE + nt * 16 + col] = (uint16_t)(pk01 >> 16);
            out[(rowb + 2) * OUT_STRIDE + nt * 16 + col] = (uint16_t)pk23;
            out[(rowb + 3) * OUT_STRIDE + nt * 16 + col] = (uint16_t)(pk23 >> 16);
        }
    }
}

// max over the 20 k-rows of each point -> bf16 into cat (non-negative values)
template <int O, int STRIDE>
__device__ __forceinline__ void maxk(const uint16_t* __restrict__ h,
                                     uint16_t* __restrict__ cat_ws, int catoff,
                                     int t, int b, int n0) {
    constexpr int G = O / 8;
    if (t < P * G) {
        const int p = t / G, g = t % G;
        uint16_t mx[8];
        #pragma unroll
        for (int j = 0; j < 8; ++j) mx[j] = 0;
        for (int k = 0; k < KNN; ++k) {
            const uint16_t* row = h + (p * KNN + k) * STRIDE + g * 8;
            #pragma unroll
            for (int j = 0; j < 8; ++j) mx[j] = row[j] > mx[j] ? row[j] : mx[j];
        }
        uint16_t* dst = cat_ws + ((size_t)b * NPTS + n0 + p) * 512 + catoff + g * 8;
        *(short8*)dst = *(const short8*)mx;
    }
}

// ---------------------------------------------------------------------------
// Fused MLP, MFMA edition. Block = 4 points, 256 threads (4 waves).
// (Exact R4/R8-passing body.)
__global__ __launch_bounds__(256) void fused_mlp_mfma(
    const float* __restrict__ x,
    const int*   __restrict__ idx_ws,
    const float* __restrict__ dist_ws,
    const uint16_t* __restrict__ wf1,
    const uint16_t* __restrict__ wf2,
    const uint16_t* __restrict__ wf3,
    const uint16_t* __restrict__ wf4,
    uint16_t* __restrict__ cat_ws)      // (B*N, 512) bf16
{
    const int n0 = blockIdx.x * P, b = blockIdx.y, t = threadIdx.x;
    const int wave = t >> 6, lane = t & 63;

    __shared__ __align__(16) uint16_t bufA[12800];  // feat(3200) / h2(5760) / slabs(12800)
    __shared__ __align__(16) uint16_t bufB[10880];  // h1(5760) / h3(10880)

    // ---- stage feat: [80][40] bf16, cols 0-2 xc, 3-5 nbr, 6-25 dist, 26+ zero
    for (int i = t; i < 1600; i += 256) ((uint32_t*)bufA)[i] = 0;
    __syncthreads();
    {
        const float* xb = x + (size_t)b * 3 * NPTS;
        if (t < P * KNN) {
            const int p = t / KNN, k = t % KNN;
            const int n = n0 + p;
            const size_t base = ((size_t)b * NPTS + n) * KNN + k;
            const int   m = idx_ws[base];
            const float d = dist_ws[base];
            uint16_t* fr = bufA + t * 40;
            fr[0] = f2bf(xb[n]);        fr[1] = f2bf(xb[NPTS + n]);
            fr[2] = f2bf(xb[2 * NPTS + n]);
            fr[3] = f2bf(xb[m]);        fr[4] = f2bf(xb[NPTS + m]);
            fr[5] = f2bf(xb[2 * NPTS + m]);
            const uint16_t db = f2bf(d);
            #pragma unroll
            for (int j = 0; j < KNN; ++j) bufA[(p * KNN + j) * 40 + 6 + k] = db;
        }
    }
    __syncthreads();

    // ---- L1: feat(A) -> h1(B)
    mfma_layer<4, 1, 40, 72>(bufA, bufB, wf1, wave, lane);
    __syncthreads();

    // ---- L2: h1(B) -> h2(A); x1 = maxk(h1)
    maxk<64, 72>(bufB, cat_ws, 0, t, b, n0);
    mfma_layer<4, 2, 72, 72>(bufB, bufA, wf2, wave, lane);
    __syncthreads();

    // ---- L3: h2(A) -> h3(B); x2 = maxk(h2)
    maxk<64, 72>(bufA, cat_ws, 64, t, b, n0);
    mfma_layer<8, 2, 72, 136>(bufA, bufB, wf3, wave, lane);
    __syncthreads();

    // ---- L4: h3(B) -> per-wave slab (A) -> relu+max -> cat; x3 = maxk(h3)
    maxk<128, 136>(bufB, cat_ws, 128, t, b, n0);
    {
        float* slab = (float*)bufA + wave * 1600;   // [80][20] f32, wave-private
        const int col = lane & 15, quad = lane >> 4;
        #pragma unroll
        for (int ni = 0; ni < 4; ++ni) {
            const int nt = wave * 4 + ni;
            short8 bfrag[4];
            #pragma unroll
            for (int k = 0; k < 4; ++k)
                bfrag[k] = *(const short8*)(wf4 + ((size_t)(nt * 4 + k) * 64 + lane) * 8);
            #pragma unroll
            for (int mt = 0; mt < 5; ++mt) {
                floatx4 acc = {0.f, 0.f, 0.f, 0.f};
                #pragma unroll
                for (int k = 0; k < 4; ++k) {
                    const short8 af = *(const short8*)(bufB + (mt * 16 + col) * 136
                                                           + k * 32 + quad * 8);
                    acc = __builtin_amdgcn_mfma_f32_16x16x32_bf16(af, bfrag[k], acc, 0, 0, 0);
                }
                #pragma unroll
                for (int r = 0; r < 4; ++r)
                    slab[(mt * 16 + quad * 4 + r) * 20 + col] = fmaxf(acc[r], 0.f);
            }
            const int p = lane >> 4, grp = (lane >> 2) & 3, kq = lane & 3;
            floatx4 mx = {0.f, 0.f, 0.f, 0.f};
            #pragma unroll
            for (int i = 0; i < 5; ++i) {
                const floatx4 v = *(const floatx4*)&slab[(p * KNN + kq * 5 + i) * 20 + grp * 4];
                mx[0] = fmaxf(mx[0], v[0]); mx[1] = fmaxf(mx[1], v[1]);
                mx[2] = fmaxf(mx[2], v[2]); mx[3] = fmaxf(mx[3], v[3]);
            }
            #pragma unroll
            for (int r = 0; r < 4; ++r) {
                mx[r] = fmaxf(mx[r], __shfl_xor(mx[r], 1));
                mx[r] = fmaxf(mx[r], __shfl_xor(mx[r], 2));
            }
            if (kq == 0) {
                const uint32_t p01 = cvtpk_bf16(mx[0], mx[1]);
                const uint32_t p23 = cvtpk_bf16(mx[2], mx[3]);
                uint32_t* dst = (uint32_t*)(cat_ws + ((size_t)b * NPTS + n0 + p) * 512
                              + 256 + nt * 16 + grp * 4);
                dst[0] = p01; dst[1] = p23;
            }
        }
    }
}

// ---------------------------------------------------------------------------
// Final GEMM, MFMA: out[b,o,n] = relu( sum_c w5[o,c] * cat[b,n,c] ).
// 64(o) x 128(n) tile, 4 waves (wave = o-subtile, 8 n-subtiles), K-chunks 64.
__global__ __launch_bounds__(256) void final_gemm_mfma(
    const uint16_t* __restrict__ w5b,  // (512,512) bf16 row-major (o,c)
    const uint16_t* __restrict__ cat,  // (B*N,512) bf16
    float* __restrict__ out)           // (B,512,N) f32
{
    const int b  = blockIdx.z;
    const int o0 = blockIdx.y * 64;
    const int n0 = blockIdx.x * 128;
    const int t  = threadIdx.x;
    const int wave = t >> 6, lane = t & 63;
    const int col = lane & 15, quad = lane >> 4;

    __shared__ __align__(16) uint16_t As[64 * 72];   // w5 tile [o][k], +8 pad
    __shared__ __align__(16) uint16_t Bs[128 * 72];  // cat tile [n][k], +8 pad

    floatx4 acc[8];
    #pragma unroll
    for (int i = 0; i < 8; ++i) acc[i] = (floatx4){0.f, 0.f, 0.f, 0.f};

    const size_t arow_base = (size_t)o0 * 512;
    const size_t brow_base = ((size_t)b * NPTS + n0) * 512;

    for (int kc = 0; kc < 512; kc += 64) {
        #pragma unroll
        for (int i = 0; i < 2; ++i) {             // As: 512 short8
            const int idx = t + i * 256;          // 0..511
            const int row = idx >> 3;             // 0..63
            const int k8  = (idx & 7) * 8;        // 0..56
            *(short8*)&As[row * 72 + k8] =
                *(const short8*)&w5b[arow_base + (size_t)row * 512 + kc + k8];
        }
        #pragma unroll
        for (int i = 0; i < 4; ++i) {             // Bs: 1024 short8
            const int idx = t + i * 256;          // 0..1023
            const int row = idx >> 3;             // 0..127
            const int k8  = (idx & 7) * 8;
            *(short8*)&Bs[row * 72 + k8] =
                *(const short8*)&cat[brow_base + (size_t)row * 512 + kc + k8];
        }
        __syncthreads();
        #pragma unroll
        for (int kt = 0; kt < 2; ++kt) {
            const short8 af = *(const short8*)&As[(wave * 16 + col) * 72 + kt * 32 + quad * 8];
            #pragma unroll
            for (int ns = 0; ns < 8; ++ns) {
                const short8 bf = *(const short8*)&Bs[(ns * 16 + col) * 72 + kt * 32 + quad * 8];
                acc[ns] = __builtin_amdgcn_mfma_f32_16x16x32_bf16(af, bf, acc[ns], 0, 0, 0);
            }
        }
        __syncthreads();
    }

    #pragma unroll
    for (int ns = 0; ns < 8; ++ns) {
        #pragma unroll
        for (int r = 0; r < 4; ++r) {
            out[((size_t)b * 512 + o0 + wave * 16 + quad * 4 + r) * NPTS
                + n0 + ns * 16 + col] = fmaxf(acc[ns][r], 0.f);
        }
    }
}

// ---------------------------------------------------------------------------
extern "C" void kernel_launch(void* const* d_in, const int* in_sizes, int n_in,
                              void* d_out, int out_size, void* d_ws, size_t ws_size,
                              hipStream_t stream) {
    const float* x  = (const float*)d_in[0];  // (8,3,4096)
    const float* w1 = (const float*)d_in[1];  // (64,26)
    const float* w2 = (const float*)d_in[2];  // (64,64)
    const float* w3 = (const float*)d_in[3];  // (128,64)
    const float* w4 = (const float*)d_in[4];  // (256,128)
    const float* w5 = (const float*)d_in[5];  // (512,512)
    float* out = (float*)d_out;               // (8,512,4096) fp32

    // workspace layout (bytes):
    //   [0)         idx_ws   B*N*K int     = 2,621,440
    //   [2621440)   dist_ws  B*N*K f32     = 2,621,440
    //   [5242880)   cat_ws   B*N*512 bf16  = 33,554,432
    //               (xyzs aliases cat_ws[0:512KB]: consumed by topk BEFORE
    //                fused_mlp writes cat — stream-ordered, safe)
    //   [38797312)  w5b bf16 (512x512)     = 524,288
    //   [72351744)  wf1 4 KB; wf2 8 KB; wf3 16 KB; wf4 64 KB
    char* ws = (char*)d_ws;
    int*      idx_ws  = (int*)ws;
    float*    dist_ws = (float*)(ws + 2621440);
    uint16_t* cat_ws  = (uint16_t*)(ws + 5242880);
    float4*   xyzs    = (float4*)(ws + 5242880);   // alias, 512 KB
    uint16_t* w5b     = (uint16_t*)(ws + 38797312);
    uint16_t* wf1     = (uint16_t*)(ws + 72351744);
    uint16_t* wf2     = (uint16_t*)(ws + 72351744 + 4096);
    uint16_t* wf3     = (uint16_t*)(ws + 72351744 + 4096 + 8192);
    uint16_t* wf4     = (uint16_t*)(ws + 72351744 + 4096 + 8192 + 16384);

    // 1024 (w5b) + 23 (wfrags) + 128 (xyzs) blocks
    prep_all<<<dim3(1024 + 23 + 128), 256, 0, stream>>>(
        x, w1, w2, w3, w4, w5, wf1, wf2, wf3, wf4, w5b, xyzs);

    topk_kernel<<<dim3(NPTS / (4 * QPW), NB), 256, 0, stream>>>(xyzs, idx_ws, dist_ws);
    fused_mlp_mfma<<<dim3(NPTS / P, NB), 256, 0, stream>>>(
        x, idx_ws, dist_ws, wf1, wf2, wf3, wf4, cat_ws);
    final_gemm_mfma<<<dim3(NPTS / 128, 512 / 64, NB), 256, 0, stream>>>(w5b, cat_ws, out);
}

// Round 10
// 326.245 us; speedup vs baseline: 1.1491x; 1.0834x over previous
//
#include <hip/hip_runtime.h>
#include <cstdint>
#include <cstddef>

#define NB   8
#define NPTS 4096
#define KNN  20
#define P    4   // points per fused-MLP block (M = P*KNN = 80 rows = 5 m-tiles)
#define QPW  4   // query points per wave in topk

typedef __attribute__((ext_vector_type(8))) short    short8;
typedef __attribute__((ext_vector_type(4))) float    floatx4;

__device__ __forceinline__ uint16_t f2bf(float f) {
    uint32_t u = __float_as_uint(f);
    uint32_t r = (u + 0x7FFFu + ((u >> 16) & 1u)) >> 16;   // RNE
    return (uint16_t)r;
}

// packed f32->bf16 RNE (same rounding as f2bf), 1 instr for 2 values
__device__ __forceinline__ uint32_t cvtpk_bf16(float lo, float hi) {
    uint32_t r;
    asm("v_cvt_pk_bf16_f32 %0, %1, %2" : "=v"(r) : "v"(lo), "v"(hi));
    return r;
}

__device__ __forceinline__ uint32_t umin32(uint32_t a, uint32_t b) { return a < b ? a : b; }
__device__ __forceinline__ uint32_t umax32(uint32_t a, uint32_t b) { return a > b ? a : b; }

// DPP u32 max step: invalid source lanes fall back to own value (idempotent)
template <int CTRL>
__device__ __forceinline__ uint32_t dpp_maxu(uint32_t v) {
    uint32_t o = (uint32_t)__builtin_amdgcn_update_dpp((int)v, (int)v,
                                                       CTRL, 0xF, 0xF, false);
    return umax32(v, o);
}
// wave64 u32 max-reduce, result broadcast via readlane 63
__device__ __forceinline__ uint32_t wave_max_u32(uint32_t v) {
    v = dpp_maxu<0x111>(v);   // row_shr:1
    v = dpp_maxu<0x112>(v);   // row_shr:2
    v = dpp_maxu<0x114>(v);   // row_shr:4
    v = dpp_maxu<0x118>(v);   // row_shr:8
    v = dpp_maxu<0x142>(v);   // row_bcast:15
    v = dpp_maxu<0x143>(v);   // row_bcast:31 -> lane 63 has max
    return (uint32_t)__builtin_amdgcn_readlane((int)v, 63);
}

// ---------------------------------------------------------------------------
// Top-20, packed-key edition. One wave per QPW=4 points, lane l owns columns
// m%64==l (m = j*64+l). s = fma(2,dot,-sqn) - sqm (bitwise == prior rounds);
// all s <= 0 (self-pair = +0.0), so key = ~bits(s) is u32-monotone in s.
// Low 6 bits replaced by (j^63): one u32 carries value AND index; u32 order
// == (value desc, then j asc, then cross-lane lowest lane) == jax top_k
// order for all pairs differing by >64 ULP (near-ties perturb dists ~1e-6,
// invisible at bf16). Insert = 5 min/max, no cmp/cndmask, no J registers;
// winner j decoded from the wave-max key (no readlane). Sentinel key = 0.
__global__ __launch_bounds__(256) void topk_kernel(
    const float4* __restrict__ xyzs,  // (B,N) packed (x,y,z,sq)
    int*   __restrict__ idx_out,      // (B,N,K)
    float* __restrict__ dist_out)     // (B,N,K)
{
    const int t = threadIdx.x;
    const int wave = t >> 6, l = t & 63;
    const int nbase = (blockIdx.x * 4 + wave) * QPW;
    const int b = blockIdx.y;
    const float4* xq = xyzs + (size_t)b * NPTS;

    float xn0[QPW], xn1[QPW], xn2[QPW], sqn[QPW];
    uint32_t V0[QPW], V1[QPW], V2[QPW];
    unsigned long long consumed[QPW];
    int my_m[QPW];

    #pragma unroll
    for (int p = 0; p < QPW; ++p) {
        const float4 pn = xq[nbase + p];
        xn0[p] = pn.x; xn1[p] = pn.y; xn2[p] = pn.z; sqn[p] = pn.w;
        V0[p] = 0u; V1[p] = 0u; V2[p] = 0u;
        consumed[p] = 0ull;
        my_m[p] = 0;
    }

    #pragma unroll 4
    for (int j = 0; j < 64; ++j) {
        const float4 pm = xq[j * 64 + l];
        const uint32_t jx = (uint32_t)(j ^ 63);
        #pragma unroll
        for (int p = 0; p < QPW; ++p) {
            const float dot = fmaf(xn2[p], pm.z, fmaf(xn1[p], pm.y, xn0[p] * pm.x));
            const float s = fmaf(2.0f, dot, -sqn[p]) - pm.w;  // bitwise == prior
            const uint32_t key = (~__float_as_uint(s) & 0xFFFFFFC0u) | jx;
            const uint32_t t1 = umin32(V0[p], key);   // uses OLD V0
            const uint32_t t2 = umin32(V1[p], key);   // uses OLD V1
            V0[p] = umax32(V0[p], key);
            V1[p] = umax32(V1[p], t1);
            V2[p] = umax32(V2[p], t2);
        }
    }

    #pragma unroll
    for (int p = 0; p < QPW; ++p) {
        for (int k = 0; k < KNN; ++k) {
            if (V0[p] == 0u) {   // rare refill: rebuild top-3 of unconsumed
                V1[p] = 0u; V2[p] = 0u;
                for (int j = 0; j < 64; ++j) {
                    const float4 pm = xq[j * 64 + l];
                    const float dot = fmaf(xn2[p], pm.z, fmaf(xn1[p], pm.y, xn0[p] * pm.x));
                    const float s = fmaf(2.0f, dot, -sqn[p]) - pm.w;
                    uint32_t key = (~__float_as_uint(s) & 0xFFFFFFC0u)
                                 | (uint32_t)(j ^ 63);
                    if ((consumed[p] >> j) & 1ull) key = 0u;
                    const uint32_t t1 = umin32(V0[p], key);
                    const uint32_t t2 = umin32(V1[p], key);
                    V0[p] = umax32(V0[p], key);
                    V1[p] = umax32(V1[p], t1);
                    V2[p] = umax32(V2[p], t2);
                }
            }
            const uint32_t w = wave_max_u32(V0[p]);
            const unsigned long long own = __ballot(V0[p] == w);
            const int owner = (int)__builtin_ctzll(own);
            const int jwin  = 63 - (int)(w & 63u);
            const int m     = jwin * 64 + owner;
            if (l == k) my_m[p] = m;
            if (l == owner) {                 // owner pops its head
                consumed[p] |= 1ull << jwin;
                V0[p] = V1[p]; V1[p] = V2[p]; V2[p] = 0u;
            }
        }
    }

    #pragma unroll
    for (int p = 0; p < QPW; ++p) {
        if (l < KNN) {
            const int n = nbase + p;
            const float4 pm = xq[my_m[p]];
            const float d0 = pm.x - xn0[p], d1 = pm.y - xn1[p], d2 = pm.z - xn2[p];
            const float dist = sqrtf(((d0 * d0 + d1 * d1) + d2 * d2) + 1e-12f);
            const size_t base = ((size_t)b * NPTS + n) * KNN + l;
            idx_out[base]  = my_m[p];
            dist_out[base] = dist;
        }
    }
}

// ---------------------------------------------------------------------------
// Merged prep (one dispatch): w5 bf16 cast + fragment-ordered bf16 B-operands
// for all four conv layers + xyzs (x,y,z,||x||^2) pack. All mappings identical
// to the separate passing kernels.
__global__ __launch_bounds__(256) void prep_all(
    const float* __restrict__ x,
    const float* __restrict__ w1, const float* __restrict__ w2,
    const float* __restrict__ w3, const float* __restrict__ w4,
    const float* __restrict__ w5,
    uint16_t* __restrict__ wf1, uint16_t* __restrict__ wf2,
    uint16_t* __restrict__ wf3, uint16_t* __restrict__ wf4,
    uint16_t* __restrict__ w5b,
    float4* __restrict__ xyzs)
{
    int blk = blockIdx.x;
    const int t = threadIdx.x;
    if (blk < 1024) {                       // w5 (512x512) -> bf16
        const int i = blk * 256 + t;
        w5b[i] = f2bf(w5[i]);
        return;
    }
    blk -= 1024;
    if (blk >= 23) {                        // xyzs pack (B*N = 32768 threads)
        const int i = (blk - 23) * 256 + t;
        if (i < NB * NPTS) {
            const int b = i / NPTS, n = i - b * NPTS;
            const float* xb = x + (size_t)b * 3 * NPTS;
            const float x0 = xb[n], x1 = xb[NPTS + n], x2 = xb[2 * NPTS + n];
            float4 v;
            v.x = x0; v.y = x1; v.z = x2;
            v.w = fmaf(x2, x2, fmaf(x1, x1, x0 * x0));
            xyzs[i] = v;
        }
        return;
    }
    const float* w; uint16_t* frag; int C, NT, KT, base;
    if (blk < 1)       { w = w1; frag = wf1; C = 26;  NT = 4;  KT = 1; base = blk; }
    else if (blk < 3)  { w = w2; frag = wf2; C = 64;  NT = 4;  KT = 2; base = blk - 1; }
    else if (blk < 7)  { w = w3; frag = wf3; C = 64;  NT = 8;  KT = 2; base = blk - 3; }
    else               { w = w4; frag = wf4; C = 128; NT = 16; KT = 4; base = blk - 7; }
    const int i = base * 256 + t;           // one (nt,kt,lane)
    if (i >= NT * KT * 64) return;
    const int lane = i & 63;
    const int kt   = (i >> 6) % KT;
    const int nt   = (i >> 6) / KT;
    const int n    = nt * 16 + (lane & 15);
    const int c0   = kt * 32 + (lane >> 4) * 8;
    uint16_t o[8];
    #pragma unroll
    for (int j = 0; j < 8; ++j) {
        const int c = c0 + j;
        o[j] = (c < C) ? f2bf(w[(size_t)n * C + c]) : (uint16_t)0;
    }
    uint16_t* dst = frag + (size_t)i * 8;
    #pragma unroll
    for (int j = 0; j < 8; ++j) dst[j] = o[j];
}

// ---------------------------------------------------------------------------
// One MFMA conv layer: in (LDS bf16, [80][IN_STRIDE]) x wf -> out (LDS bf16,
// [80][OUT_STRIDE], relu'd). bfrag preloaded for all ni; af hoisted out of
// the ni loop. Epilogue converts via packed v_cvt_pk_bf16_f32 (RNE == f2bf).
template <int NT_TOT, int KT, int IN_STRIDE, int OUT_STRIDE>
__device__ __forceinline__ void mfma_layer(const uint16_t* __restrict__ in,
                                           uint16_t* __restrict__ out,
                                           const uint16_t* __restrict__ wf,
                                           int wave, int lane) {
    constexpr int NT_W = NT_TOT / 4;
    const int col = lane & 15, quad = lane >> 4;
    short8 bfrag[NT_W][KT];
    #pragma unroll
    for (int ni = 0; ni < NT_W; ++ni)
        #pragma unroll
        for (int k = 0; k < KT; ++k)
            bfrag[ni][k] = *(const short8*)(wf +
                ((size_t)((wave * NT_W + ni) * KT + k) * 64 + lane) * 8);
    #pragma unroll
    for (int mt = 0; mt < 5; ++mt) {
        short8 af[KT];
        #pragma unroll
        for (int k = 0; k < KT; ++k)
            af[k] = *(const short8*)(in + (mt * 16 + col) * IN_STRIDE + k * 32 + quad * 8);
        #pragma unroll
        for (int ni = 0; ni < NT_W; ++ni) {
            floatx4 acc = {0.f, 0.f, 0.f, 0.f};
            #pragma unroll
            for (int k = 0; k < KT; ++k)
                acc = __builtin_amdgcn_mfma_f32_16x16x32_bf16(af[k], bfrag[ni][k], acc, 0, 0, 0);
            const int nt = wave * NT_W + ni;
            const int rowb = mt * 16 + quad * 4;
            const uint32_t pk01 = cvtpk_bf16(fmaxf(acc[0], 0.f), fmaxf(acc[1], 0.f));
            const uint32_t pk23 = cvtpk_bf16(fmaxf(acc[2], 0.f), fmaxf(acc[3], 0.f));
            out[(rowb + 0) * OUT_STRIDE + nt * 16 + col] = (uint16_t)pk01;
            out[(rowb + 1) * OUT_STRIDE + nt * 16 + col] = (uint16_t)(pk01 >> 16);
            out[(rowb + 2) * OUT_STRIDE + nt * 16 + col] = (uint16_t)pk23;
            out[(rowb + 3) * OUT_STRIDE + nt * 16 + col] = (uint16_t)(pk23 >> 16);
        }
    }
}

// max over the 20 k-rows of each point -> bf16 into cat (non-negative values)
template <int O, int STRIDE>
__device__ __forceinline__ void maxk(const uint16_t* __restrict__ h,
                                     uint16_t* __restrict__ cat_ws, int catoff,
                                     int t, int b, int n0) {
    constexpr int G = O / 8;
    if (t < P * G) {
        const int p = t / G, g = t % G;
        uint16_t mx[8];
        #pragma unroll
        for (int j = 0; j < 8; ++j) mx[j] = 0;
        for (int k = 0; k < KNN; ++k) {
            const uint16_t* row = h + (p * KNN + k) * STRIDE + g * 8;
            #pragma unroll
            for (int j = 0; j < 8; ++j) mx[j] = row[j] > mx[j] ? row[j] : mx[j];
        }
        uint16_t* dst = cat_ws + ((size_t)b * NPTS + n0 + p) * 512 + catoff + g * 8;
        *(short8*)dst = *(const short8*)mx;
    }
}

// ---------------------------------------------------------------------------
// Fused MLP, MFMA edition. Block = 4 points, 256 threads (4 waves).
// (Exact R4/R8/R9-passing body.)
__global__ __launch_bounds__(256) void fused_mlp_mfma(
    const float* __restrict__ x,
    const int*   __restrict__ idx_ws,
    const float* __restrict__ dist_ws,
    const uint16_t* __restrict__ wf1,
    const uint16_t* __restrict__ wf2,
    const uint16_t* __restrict__ wf3,
    const uint16_t* __restrict__ wf4,
    uint16_t* __restrict__ cat_ws)      // (B*N, 512) bf16
{
    const int n0 = blockIdx.x * P, b = blockIdx.y, t = threadIdx.x;
    const int wave = t >> 6, lane = t & 63;

    __shared__ __align__(16) uint16_t bufA[12800];  // feat(3200) / h2(5760) / slabs(12800)
    __shared__ __align__(16) uint16_t bufB[10880];  // h1(5760) / h3(10880)

    // ---- stage feat: [80][40] bf16, cols 0-2 xc, 3-5 nbr, 6-25 dist, 26+ zero
    for (int i = t; i < 1600; i += 256) ((uint32_t*)bufA)[i] = 0;
    __syncthreads();
    {
        const float* xb = x + (size_t)b * 3 * NPTS;
        if (t < P * KNN) {
            const int p = t / KNN, k = t % KNN;
            const int n = n0 + p;
            const size_t base = ((size_t)b * NPTS + n) * KNN + k;
            const int   m = idx_ws[base];
            const float d = dist_ws[base];
            uint16_t* fr = bufA + t * 40;
            fr[0] = f2bf(xb[n]);        fr[1] = f2bf(xb[NPTS + n]);
            fr[2] = f2bf(xb[2 * NPTS + n]);
            fr[3] = f2bf(xb[m]);        fr[4] = f2bf(xb[NPTS + m]);
            fr[5] = f2bf(xb[2 * NPTS + m]);
            const uint16_t db = f2bf(d);
            #pragma unroll
            for (int j = 0; j < KNN; ++j) bufA[(p * KNN + j) * 40 + 6 + k] = db;
        }
    }
    __syncthreads();

    // ---- L1: feat(A) -> h1(B)
    mfma_layer<4, 1, 40, 72>(bufA, bufB, wf1, wave, lane);
    __syncthreads();

    // ---- L2: h1(B) -> h2(A); x1 = maxk(h1)
    maxk<64, 72>(bufB, cat_ws, 0, t, b, n0);
    mfma_layer<4, 2, 72, 72>(bufB, bufA, wf2, wave, lane);
    __syncthreads();

    // ---- L3: h2(A) -> h3(B); x2 = maxk(h2)
    maxk<64, 72>(bufA, cat_ws, 64, t, b, n0);
    mfma_layer<8, 2, 72, 136>(bufA, bufB, wf3, wave, lane);
    __syncthreads();

    // ---- L4: h3(B) -> per-wave slab (A) -> relu+max -> cat; x3 = maxk(h3)
    maxk<128, 136>(bufB, cat_ws, 128, t, b, n0);
    {
        float* slab = (float*)bufA + wave * 1600;   // [80][20] f32, wave-private
        const int col = lane & 15, quad = lane >> 4;
        #pragma unroll
        for (int ni = 0; ni < 4; ++ni) {
            const int nt = wave * 4 + ni;
            short8 bfrag[4];
            #pragma unroll
            for (int k = 0; k < 4; ++k)
                bfrag[k] = *(const short8*)(wf4 + ((size_t)(nt * 4 + k) * 64 + lane) * 8);
            #pragma unroll
            for (int mt = 0; mt < 5; ++mt) {
                floatx4 acc = {0.f, 0.f, 0.f, 0.f};
                #pragma unroll
                for (int k = 0; k < 4; ++k) {
                    const short8 af = *(const short8*)(bufB + (mt * 16 + col) * 136
                                                           + k * 32 + quad * 8);
                    acc = __builtin_amdgcn_mfma_f32_16x16x32_bf16(af, bfrag[k], acc, 0, 0, 0);
                }
                #pragma unroll
                for (int r = 0; r < 4; ++r)
                    slab[(mt * 16 + quad * 4 + r) * 20 + col] = fmaxf(acc[r], 0.f);
            }
            const int p = lane >> 4, grp = (lane >> 2) & 3, kq = lane & 3;
            floatx4 mx = {0.f, 0.f, 0.f, 0.f};
            #pragma unroll
            for (int i = 0; i < 5; ++i) {
                const floatx4 v = *(const floatx4*)&slab[(p * KNN + kq * 5 + i) * 20 + grp * 4];
                mx[0] = fmaxf(mx[0], v[0]); mx[1] = fmaxf(mx[1], v[1]);
                mx[2] = fmaxf(mx[2], v[2]); mx[3] = fmaxf(mx[3], v[3]);
            }
            #pragma unroll
            for (int r = 0; r < 4; ++r) {
                mx[r] = fmaxf(mx[r], __shfl_xor(mx[r], 1));
                mx[r] = fmaxf(mx[r], __shfl_xor(mx[r], 2));
            }
            if (kq == 0) {
                const uint32_t p01 = cvtpk_bf16(mx[0], mx[1]);
                const uint32_t p23 = cvtpk_bf16(mx[2], mx[3]);
                uint32_t* dst = (uint32_t*)(cat_ws + ((size_t)b * NPTS + n0 + p) * 512
                              + 256 + nt * 16 + grp * 4);
                dst[0] = p01; dst[1] = p23;
            }
        }
    }
}

// ---------------------------------------------------------------------------
// Final GEMM, MFMA: out[b,o,n] = relu( sum_c w5[o,c] * cat[b,n,c] ).
// 64(o) x 128(n) tile, 4 waves (wave = o-subtile, 8 n-subtiles), K-chunks 64.
__global__ __launch_bounds__(256) void final_gemm_mfma(
    const uint16_t* __restrict__ w5b,  // (512,512) bf16 row-major (o,c)
    const uint16_t* __restrict__ cat,  // (B*N,512) bf16
    float* __restrict__ out)           // (B,512,N) f32
{
    const int b  = blockIdx.z;
    const int o0 = blockIdx.y * 64;
    const int n0 = blockIdx.x * 128;
    const int t  = threadIdx.x;
    const int wave = t >> 6, lane = t & 63;
    const int col = lane & 15, quad = lane >> 4;

    __shared__ __align__(16) uint16_t As[64 * 72];   // w5 tile [o][k], +8 pad
    __shared__ __align__(16) uint16_t Bs[128 * 72];  // cat tile [n][k], +8 pad

    floatx4 acc[8];
    #pragma unroll
    for (int i = 0; i < 8; ++i) acc[i] = (floatx4){0.f, 0.f, 0.f, 0.f};

    const size_t arow_base = (size_t)o0 * 512;
    const size_t brow_base = ((size_t)b * NPTS + n0) * 512;

    for (int kc = 0; kc < 512; kc += 64) {
        #pragma unroll
        for (int i = 0; i < 2; ++i) {             // As: 512 short8
            const int idx = t + i * 256;          // 0..511
            const int row = idx >> 3;             // 0..63
            const int k8  = (idx & 7) * 8;        // 0..56
            *(short8*)&As[row * 72 + k8] =
                *(const short8*)&w5b[arow_base + (size_t)row * 512 + kc + k8];
        }
        #pragma unroll
        for (int i = 0; i < 4; ++i) {             // Bs: 1024 short8
            const int idx = t + i * 256;          // 0..1023
            const int row = idx >> 3;             // 0..127
            const int k8  = (idx & 7) * 8;
            *(short8*)&Bs[row * 72 + k8] =
                *(const short8*)&cat[brow_base + (size_t)row * 512 + kc + k8];
        }
        __syncthreads();
        #pragma unroll
        for (int kt = 0; kt < 2; ++kt) {
            const short8 af = *(const short8*)&As[(wave * 16 + col) * 72 + kt * 32 + quad * 8];
            #pragma unroll
            for (int ns = 0; ns < 8; ++ns) {
                const short8 bf = *(const short8*)&Bs[(ns * 16 + col) * 72 + kt * 32 + quad * 8];
                acc[ns] = __builtin_amdgcn_mfma_f32_16x16x32_bf16(af, bf, acc[ns], 0, 0, 0);
            }
        }
        __syncthreads();
    }

    #pragma unroll
    for (int ns = 0; ns < 8; ++ns) {
        #pragma unroll
        for (int r = 0; r < 4; ++r) {
            out[((size_t)b * 512 + o0 + wave * 16 + quad * 4 + r) * NPTS
                + n0 + ns * 16 + col] = fmaxf(acc[ns][r], 0.f);
        }
    }
}

// ---------------------------------------------------------------------------
extern "C" void kernel_launch(void* const* d_in, const int* in_sizes, int n_in,
                              void* d_out, int out_size, void* d_ws, size_t ws_size,
                              hipStream_t stream) {
    const float* x  = (const float*)d_in[0];  // (8,3,4096)
    const float* w1 = (const float*)d_in[1];  // (64,26)
    const float* w2 = (const float*)d_in[2];  // (64,64)
    const float* w3 = (const float*)d_in[3];  // (128,64)
    const float* w4 = (const float*)d_in[4];  // (256,128)
    const float* w5 = (const float*)d_in[5];  // (512,512)
    float* out = (float*)d_out;               // (8,512,4096) fp32

    // workspace layout (bytes):
    //   [0)         idx_ws   B*N*K int     = 2,621,440
    //   [2621440)   dist_ws  B*N*K f32     = 2,621,440
    //   [5242880)   cat_ws   B*N*512 bf16  = 33,554,432
    //               (xyzs aliases cat_ws[0:512KB]: consumed by topk BEFORE
    //                fused_mlp writes cat — stream-ordered, safe)
    //   [38797312)  w5b bf16 (512x512)     = 524,288
    //   [72351744)  wf1 4 KB; wf2 8 KB; wf3 16 KB; wf4 64 KB
    char* ws = (char*)d_ws;
    int*      idx_ws  = (int*)ws;
    float*    dist_ws = (float*)(ws + 2621440);
    uint16_t* cat_ws  = (uint16_t*)(ws + 5242880);
    float4*   xyzs    = (float4*)(ws + 5242880);   // alias, 512 KB
    uint16_t* w5b     = (uint16_t*)(ws + 38797312);
    uint16_t* wf1     = (uint16_t*)(ws + 72351744);
    uint16_t* wf2     = (uint16_t*)(ws + 72351744 + 4096);
    uint16_t* wf3     = (uint16_t*)(ws + 72351744 + 4096 + 8192);
    uint16_t* wf4     = (uint16_t*)(ws + 72351744 + 4096 + 8192 + 16384);

    // 1024 (w5b) + 23 (wfrags) + 128 (xyzs) blocks
    prep_all<<<dim3(1024 + 23 + 128), 256, 0, stream>>>(
        x, w1, w2, w3, w4, w5, wf1, wf2, wf3, wf4, w5b, xyzs);

    topk_kernel<<<dim3(NPTS / (4 * QPW), NB), 256, 0, stream>>>(xyzs, idx_ws, dist_ws);
    fused_mlp_mfma<<<dim3(NPTS / P, NB), 256, 0, stream>>>(
        x, idx_ws, dist_ws, wf1, wf2, wf3, wf4, cat_ws);
    final_gemm_mfma<<<dim3(NPTS / 128, 512 / 64, NB), 256, 0, stream>>>(w5b, cat_ws, out);
}

// Round 11
// 324.995 us; speedup vs baseline: 1.1535x; 1.0038x over previous
//
#include <hip/hip_runtime.h>
#include <cstdint>
#include <cstddef>

#define NB   8
#define NPTS 4096
#define KNN  20
#define P    4   // points per fused-MLP block (M = P*KNN = 80 rows = 5 m-tiles)
#define QPW  4   // query points per wave in topk

typedef __attribute__((ext_vector_type(8))) short    short8;
typedef __attribute__((ext_vector_type(4))) float    floatx4;
typedef __attribute__((ext_vector_type(2))) uint32_t uint2v;

__device__ __forceinline__ uint16_t f2bf(float f) {
    uint32_t u = __float_as_uint(f);
    uint32_t r = (u + 0x7FFFu + ((u >> 16) & 1u)) >> 16;   // RNE
    return (uint16_t)r;
}

// packed f32->bf16 RNE (same rounding as f2bf), 1 instr for 2 values
__device__ __forceinline__ uint32_t cvtpk_bf16(float lo, float hi) {
    uint32_t r;
    asm("v_cvt_pk_bf16_f32 %0, %1, %2" : "=v"(r) : "v"(lo), "v"(hi));
    return r;
}

__device__ __forceinline__ uint32_t umin32(uint32_t a, uint32_t b) { return a < b ? a : b; }
__device__ __forceinline__ uint32_t umax32(uint32_t a, uint32_t b) { return a > b ? a : b; }

// DPP u32 max step: invalid source lanes fall back to own value (idempotent)
template <int CTRL>
__device__ __forceinline__ uint32_t dpp_maxu(uint32_t v) {
    uint32_t o = (uint32_t)__builtin_amdgcn_update_dpp((int)v, (int)v,
                                                       CTRL, 0xF, 0xF, false);
    return umax32(v, o);
}
// wave64 u32 max-reduce, result broadcast via readlane 63
__device__ __forceinline__ uint32_t wave_max_u32(uint32_t v) {
    v = dpp_maxu<0x111>(v);   // row_shr:1
    v = dpp_maxu<0x112>(v);   // row_shr:2
    v = dpp_maxu<0x114>(v);   // row_shr:4
    v = dpp_maxu<0x118>(v);   // row_shr:8
    v = dpp_maxu<0x142>(v);   // row_bcast:15
    v = dpp_maxu<0x143>(v);   // row_bcast:31 -> lane 63 has max
    return (uint32_t)__builtin_amdgcn_readlane((int)v, 63);
}

// ---------------------------------------------------------------------------
// Top-20, packed-key edition (R10-passing body, unchanged).
__global__ __launch_bounds__(256) void topk_kernel(
    const float4* __restrict__ xyzs,  // (B,N) packed (x,y,z,sq)
    int*   __restrict__ idx_out,      // (B,N,K)
    float* __restrict__ dist_out)     // (B,N,K)
{
    const int t = threadIdx.x;
    const int wave = t >> 6, l = t & 63;
    const int nbase = (blockIdx.x * 4 + wave) * QPW;
    const int b = blockIdx.y;
    const float4* xq = xyzs + (size_t)b * NPTS;

    float xn0[QPW], xn1[QPW], xn2[QPW], sqn[QPW];
    uint32_t V0[QPW], V1[QPW], V2[QPW];
    unsigned long long consumed[QPW];
    int my_m[QPW];

    #pragma unroll
    for (int p = 0; p < QPW; ++p) {
        const float4 pn = xq[nbase + p];
        xn0[p] = pn.x; xn1[p] = pn.y; xn2[p] = pn.z; sqn[p] = pn.w;
        V0[p] = 0u; V1[p] = 0u; V2[p] = 0u;
        consumed[p] = 0ull;
        my_m[p] = 0;
    }

    #pragma unroll 4
    for (int j = 0; j < 64; ++j) {
        const float4 pm = xq[j * 64 + l];
        const uint32_t jx = (uint32_t)(j ^ 63);
        #pragma unroll
        for (int p = 0; p < QPW; ++p) {
            const float dot = fmaf(xn2[p], pm.z, fmaf(xn1[p], pm.y, xn0[p] * pm.x));
            const float s = fmaf(2.0f, dot, -sqn[p]) - pm.w;  // bitwise == prior
            const uint32_t key = (~__float_as_uint(s) & 0xFFFFFFC0u) | jx;
            const uint32_t t1 = umin32(V0[p], key);   // uses OLD V0
            const uint32_t t2 = umin32(V1[p], key);   // uses OLD V1
            V0[p] = umax32(V0[p], key);
            V1[p] = umax32(V1[p], t1);
            V2[p] = umax32(V2[p], t2);
        }
    }

    #pragma unroll
    for (int p = 0; p < QPW; ++p) {
        for (int k = 0; k < KNN; ++k) {
            if (V0[p] == 0u) {   // rare refill: rebuild top-3 of unconsumed
                V1[p] = 0u; V2[p] = 0u;
                for (int j = 0; j < 64; ++j) {
                    const float4 pm = xq[j * 64 + l];
                    const float dot = fmaf(xn2[p], pm.z, fmaf(xn1[p], pm.y, xn0[p] * pm.x));
                    const float s = fmaf(2.0f, dot, -sqn[p]) - pm.w;
                    uint32_t key = (~__float_as_uint(s) & 0xFFFFFFC0u)
                                 | (uint32_t)(j ^ 63);
                    if ((consumed[p] >> j) & 1ull) key = 0u;
                    const uint32_t t1 = umin32(V0[p], key);
                    const uint32_t t2 = umin32(V1[p], key);
                    V0[p] = umax32(V0[p], key);
                    V1[p] = umax32(V1[p], t1);
                    V2[p] = umax32(V2[p], t2);
                }
            }
            const uint32_t w = wave_max_u32(V0[p]);
            const unsigned long long own = __ballot(V0[p] == w);
            const int owner = (int)__builtin_ctzll(own);
            const int jwin  = 63 - (int)(w & 63u);
            const int m     = jwin * 64 + owner;
            if (l == k) my_m[p] = m;
            if (l == owner) {                 // owner pops its head
                consumed[p] |= 1ull << jwin;
                V0[p] = V1[p]; V1[p] = V2[p]; V2[p] = 0u;
            }
        }
    }

    #pragma unroll
    for (int p = 0; p < QPW; ++p) {
        if (l < KNN) {
            const int n = nbase + p;
            const float4 pm = xq[my_m[p]];
            const float d0 = pm.x - xn0[p], d1 = pm.y - xn1[p], d2 = pm.z - xn2[p];
            const float dist = sqrtf(((d0 * d0 + d1 * d1) + d2 * d2) + 1e-12f);
            const size_t base = ((size_t)b * NPTS + n) * KNN + l;
            idx_out[base]  = my_m[p];
            dist_out[base] = dist;
        }
    }
}

// ---------------------------------------------------------------------------
// Merged prep (one dispatch): w5 bf16 cast + fragment-ordered bf16 B-operands
// for all four conv layers + xyzs pack. (R9/R10-passing body, unchanged.)
__global__ __launch_bounds__(256) void prep_all(
    const float* __restrict__ x,
    const float* __restrict__ w1, const float* __restrict__ w2,
    const float* __restrict__ w3, const float* __restrict__ w4,
    const float* __restrict__ w5,
    uint16_t* __restrict__ wf1, uint16_t* __restrict__ wf2,
    uint16_t* __restrict__ wf3, uint16_t* __restrict__ wf4,
    uint16_t* __restrict__ w5b,
    float4* __restrict__ xyzs)
{
    int blk = blockIdx.x;
    const int t = threadIdx.x;
    if (blk < 1024) {                       // w5 (512x512) -> bf16
        const int i = blk * 256 + t;
        w5b[i] = f2bf(w5[i]);
        return;
    }
    blk -= 1024;
    if (blk >= 23) {                        // xyzs pack (B*N = 32768 threads)
        const int i = (blk - 23) * 256 + t;
        if (i < NB * NPTS) {
            const int b = i / NPTS, n = i - b * NPTS;
            const float* xb = x + (size_t)b * 3 * NPTS;
            const float x0 = xb[n], x1 = xb[NPTS + n], x2 = xb[2 * NPTS + n];
            float4 v;
            v.x = x0; v.y = x1; v.z = x2;
            v.w = fmaf(x2, x2, fmaf(x1, x1, x0 * x0));
            xyzs[i] = v;
        }
        return;
    }
    const float* w; uint16_t* frag; int C, NT, KT, base;
    if (blk < 1)       { w = w1; frag = wf1; C = 26;  NT = 4;  KT = 1; base = blk; }
    else if (blk < 3)  { w = w2; frag = wf2; C = 64;  NT = 4;  KT = 2; base = blk - 1; }
    else if (blk < 7)  { w = w3; frag = wf3; C = 64;  NT = 8;  KT = 2; base = blk - 3; }
    else               { w = w4; frag = wf4; C = 128; NT = 16; KT = 4; base = blk - 7; }
    const int i = base * 256 + t;           // one (nt,kt,lane)
    if (i >= NT * KT * 64) return;
    const int lane = i & 63;
    const int kt   = (i >> 6) % KT;
    const int nt   = (i >> 6) / KT;
    const int n    = nt * 16 + (lane & 15);
    const int c0   = kt * 32 + (lane >> 4) * 8;
    uint16_t o[8];
    #pragma unroll
    for (int j = 0; j < 8; ++j) {
        const int c = c0 + j;
        o[j] = (c < C) ? f2bf(w[(size_t)n * C + c]) : (uint16_t)0;
    }
    uint16_t* dst = frag + (size_t)i * 8;
    #pragma unroll
    for (int j = 0; j < 8; ++j) dst[j] = o[j];
}

// ---------------------------------------------------------------------------
// One MFMA conv layer, OPERAND-SWAPPED: acc = mfma(W, act) so D-row = channel,
// D-col = point-row. Bitwise-identical accumulators (products commute, k-order
// unchanged); same [m][ch] LDS layout. Each lane now owns 4 CONSECUTIVE
// channels of one row -> epilogue is one aligned ds_write_b64 instead of
// 4 scalar b16 writes (kills the 4-way write bank conflicts).
template <int NT_TOT, int KT, int IN_STRIDE, int OUT_STRIDE>
__device__ __forceinline__ void mfma_layer(const uint16_t* __restrict__ in,
                                           uint16_t* __restrict__ out,
                                           const uint16_t* __restrict__ wf,
                                           int wave, int lane) {
    constexpr int NT_W = NT_TOT / 4;
    const int col = lane & 15, quad = lane >> 4;
    short8 bfrag[NT_W][KT];
    #pragma unroll
    for (int ni = 0; ni < NT_W; ++ni)
        #pragma unroll
        for (int k = 0; k < KT; ++k)
            bfrag[ni][k] = *(const short8*)(wf +
                ((size_t)((wave * NT_W + ni) * KT + k) * 64 + lane) * 8);
    #pragma unroll
    for (int mt = 0; mt < 5; ++mt) {
        short8 af[KT];
        #pragma unroll
        for (int k = 0; k < KT; ++k)
            af[k] = *(const short8*)(in + (mt * 16 + col) * IN_STRIDE + k * 32 + quad * 8);
        #pragma unroll
        for (int ni = 0; ni < NT_W; ++ni) {
            floatx4 acc = {0.f, 0.f, 0.f, 0.f};
            #pragma unroll
            for (int k = 0; k < KT; ++k)
                acc = __builtin_amdgcn_mfma_f32_16x16x32_bf16(bfrag[ni][k], af[k], acc, 0, 0, 0);
            const int nt = wave * NT_W + ni;
            const uint32_t pk01 = cvtpk_bf16(fmaxf(acc[0], 0.f), fmaxf(acc[1], 0.f));
            const uint32_t pk23 = cvtpk_bf16(fmaxf(acc[2], 0.f), fmaxf(acc[3], 0.f));
            uint2v pk; pk.x = pk01; pk.y = pk23;
            *(uint2v*)(out + (mt * 16 + col) * OUT_STRIDE + nt * 16 + quad * 4) = pk;
        }
    }
}

// max over the 20 k-rows of each point -> bf16 into cat (non-negative values)
template <int O, int STRIDE>
__device__ __forceinline__ void maxk(const uint16_t* __restrict__ h,
                                     uint16_t* __restrict__ cat_ws, int catoff,
                                     int t, int b, int n0) {
    constexpr int G = O / 8;
    if (t < P * G) {
        const int p = t / G, g = t % G;
        uint16_t mx[8];
        #pragma unroll
        for (int j = 0; j < 8; ++j) mx[j] = 0;
        for (int k = 0; k < KNN; ++k) {
            const uint16_t* row = h + (p * KNN + k) * STRIDE + g * 8;
            #pragma unroll
            for (int j = 0; j < 8; ++j) mx[j] = row[j] > mx[j] ? row[j] : mx[j];
        }
        uint16_t* dst = cat_ws + ((size_t)b * NPTS + n0 + p) * 512 + catoff + g * 8;
        *(short8*)dst = *(const short8*)mx;
    }
}

// ---------------------------------------------------------------------------
// Fused MLP, MFMA edition. Block = 4 points, 256 threads (4 waves).
// (R4/R8/R9/R10 structure; mfma_layer + L4 operand-swapped for vector writes.)
__global__ __launch_bounds__(256) void fused_mlp_mfma(
    const float* __restrict__ x,
    const int*   __restrict__ idx_ws,
    const float* __restrict__ dist_ws,
    const uint16_t* __restrict__ wf1,
    const uint16_t* __restrict__ wf2,
    const uint16_t* __restrict__ wf3,
    const uint16_t* __restrict__ wf4,
    uint16_t* __restrict__ cat_ws)      // (B*N, 512) bf16
{
    const int n0 = blockIdx.x * P, b = blockIdx.y, t = threadIdx.x;
    const int wave = t >> 6, lane = t & 63;

    __shared__ __align__(16) uint16_t bufA[12800];  // feat(3200) / h2(5760) / slabs(12800)
    __shared__ __align__(16) uint16_t bufB[10880];  // h1(5760) / h3(10880)

    // ---- stage feat: [80][40] bf16, cols 0-2 xc, 3-5 nbr, 6-25 dist, 26+ zero
    for (int i = t; i < 1600; i += 256) ((uint32_t*)bufA)[i] = 0;
    __syncthreads();
    {
        const float* xb = x + (size_t)b * 3 * NPTS;
        if (t < P * KNN) {
            const int p = t / KNN, k = t % KNN;
            const int n = n0 + p;
            const size_t base = ((size_t)b * NPTS + n) * KNN + k;
            const int   m = idx_ws[base];
            const float d = dist_ws[base];
            uint16_t* fr = bufA + t * 40;
            fr[0] = f2bf(xb[n]);        fr[1] = f2bf(xb[NPTS + n]);
            fr[2] = f2bf(xb[2 * NPTS + n]);
            fr[3] = f2bf(xb[m]);        fr[4] = f2bf(xb[NPTS + m]);
            fr[5] = f2bf(xb[2 * NPTS + m]);
            const uint16_t db = f2bf(d);
            #pragma unroll
            for (int j = 0; j < KNN; ++j) bufA[(p * KNN + j) * 40 + 6 + k] = db;
        }
    }
    __syncthreads();

    // ---- L1: feat(A) -> h1(B)
    mfma_layer<4, 1, 40, 72>(bufA, bufB, wf1, wave, lane);
    __syncthreads();

    // ---- L2: h1(B) -> h2(A); x1 = maxk(h1)
    maxk<64, 72>(bufB, cat_ws, 0, t, b, n0);
    mfma_layer<4, 2, 72, 72>(bufB, bufA, wf2, wave, lane);
    __syncthreads();

    // ---- L3: h2(A) -> h3(B); x2 = maxk(h2)
    maxk<64, 72>(bufA, cat_ws, 64, t, b, n0);
    mfma_layer<8, 2, 72, 136>(bufA, bufB, wf3, wave, lane);
    __syncthreads();

    // ---- L4: h3(B) -> per-wave slab (A) -> relu+max -> cat; x3 = maxk(h3)
    maxk<128, 136>(bufB, cat_ws, 128, t, b, n0);
    {
        float* slab = (float*)bufA + wave * 1600;   // [80][20] f32, wave-private
        const int col = lane & 15, quad = lane >> 4;
        #pragma unroll
        for (int ni = 0; ni < 4; ++ni) {
            const int nt = wave * 4 + ni;
            short8 bfrag[4];
            #pragma unroll
            for (int k = 0; k < 4; ++k)
                bfrag[k] = *(const short8*)(wf4 + ((size_t)(nt * 4 + k) * 64 + lane) * 8);
            #pragma unroll
            for (int mt = 0; mt < 5; ++mt) {
                floatx4 acc = {0.f, 0.f, 0.f, 0.f};
                #pragma unroll
                for (int k = 0; k < 4; ++k) {
                    const short8 af = *(const short8*)(bufB + (mt * 16 + col) * 136
                                                           + k * 32 + quad * 8);
                    acc = __builtin_amdgcn_mfma_f32_16x16x32_bf16(bfrag[k], af, acc, 0, 0, 0);
                }
                // swapped: lane owns channels quad*4..+3 of row mt*16+col
                floatx4 v;
                v[0] = fmaxf(acc[0], 0.f); v[1] = fmaxf(acc[1], 0.f);
                v[2] = fmaxf(acc[2], 0.f); v[3] = fmaxf(acc[3], 0.f);
                *(floatx4*)&slab[(mt * 16 + col) * 20 + quad * 4] = v;
            }
            const int p = lane >> 4, grp = (lane >> 2) & 3, kq = lane & 3;
            floatx4 mx = {0.f, 0.f, 0.f, 0.f};
            #pragma unroll
            for (int i = 0; i < 5; ++i) {
                const floatx4 v = *(const floatx4*)&slab[(p * KNN + kq * 5 + i) * 20 + grp * 4];
                mx[0] = fmaxf(mx[0], v[0]); mx[1] = fmaxf(mx[1], v[1]);
                mx[2] = fmaxf(mx[2], v[2]); mx[3] = fmaxf(mx[3], v[3]);
            }
            #pragma unroll
            for (int r = 0; r < 4; ++r) {
                mx[r] = fmaxf(mx[r], __shfl_xor(mx[r], 1));
                mx[r] = fmaxf(mx[r], __shfl_xor(mx[r], 2));
            }
            if (kq == 0) {
                const uint32_t p01 = cvtpk_bf16(mx[0], mx[1]);
                const uint32_t p23 = cvtpk_bf16(mx[2], mx[3]);
                uint32_t* dst = (uint32_t*)(cat_ws + ((size_t)b * NPTS + n0 + p) * 512
                              + 256 + nt * 16 + grp * 4);
                dst[0] = p01; dst[1] = p23;
            }
        }
    }
}

// ---------------------------------------------------------------------------
// Final GEMM, MFMA (R9/R10-passing body, unchanged — global-write coalescing
// prefers the original operand order).
__global__ __launch_bounds__(256) void final_gemm_mfma(
    const uint16_t* __restrict__ w5b,  // (512,512) bf16 row-major (o,c)
    const uint16_t* __restrict__ cat,  // (B*N,512) bf16
    float* __restrict__ out)           // (B,512,N) f32
{
    const int b  = blockIdx.z;
    const int o0 = blockIdx.y * 64;
    const int n0 = blockIdx.x * 128;
    const int t  = threadIdx.x;
    const int wave = t >> 6, lane = t & 63;
    const int col = lane & 15, quad = lane >> 4;

    __shared__ __align__(16) uint16_t As[64 * 72];   // w5 tile [o][k], +8 pad
    __shared__ __align__(16) uint16_t Bs[128 * 72];  // cat tile [n][k], +8 pad

    floatx4 acc[8];
    #pragma unroll
    for (int i = 0; i < 8; ++i) acc[i] = (floatx4){0.f, 0.f, 0.f, 0.f};

    const size_t arow_base = (size_t)o0 * 512;
    const size_t brow_base = ((size_t)b * NPTS + n0) * 512;

    for (int kc = 0; kc < 512; kc += 64) {
        #pragma unroll
        for (int i = 0; i < 2; ++i) {             // As: 512 short8
            const int idx = t + i * 256;          // 0..511
            const int row = idx >> 3;             // 0..63
            const int k8  = (idx & 7) * 8;        // 0..56
            *(short8*)&As[row * 72 + k8] =
                *(const short8*)&w5b[arow_base + (size_t)row * 512 + kc + k8];
        }
        #pragma unroll
        for (int i = 0; i < 4; ++i) {             // Bs: 1024 short8
            const int idx = t + i * 256;          // 0..1023
            const int row = idx >> 3;             // 0..127
            const int k8  = (idx & 7) * 8;
            *(short8*)&Bs[row * 72 + k8] =
                *(const short8*)&cat[brow_base + (size_t)row * 512 + kc + k8];
        }
        __syncthreads();
        #pragma unroll
        for (int kt = 0; kt < 2; ++kt) {
            const short8 af = *(const short8*)&As[(wave * 16 + col) * 72 + kt * 32 + quad * 8];
            #pragma unroll
            for (int ns = 0; ns < 8; ++ns) {
                const short8 bf = *(const short8*)&Bs[(ns * 16 + col) * 72 + kt * 32 + quad * 8];
                acc[ns] = __builtin_amdgcn_mfma_f32_16x16x32_bf16(af, bf, acc[ns], 0, 0, 0);
            }
        }
        __syncthreads();
    }

    #pragma unroll
    for (int ns = 0; ns < 8; ++ns) {
        #pragma unroll
        for (int r = 0; r < 4; ++r) {
            out[((size_t)b * 512 + o0 + wave * 16 + quad * 4 + r) * NPTS
                + n0 + ns * 16 + col] = fmaxf(acc[ns][r], 0.f);
        }
    }
}

// ---------------------------------------------------------------------------
extern "C" void kernel_launch(void* const* d_in, const int* in_sizes, int n_in,
                              void* d_out, int out_size, void* d_ws, size_t ws_size,
                              hipStream_t stream) {
    const float* x  = (const float*)d_in[0];  // (8,3,4096)
    const float* w1 = (const float*)d_in[1];  // (64,26)
    const float* w2 = (const float*)d_in[2];  // (64,64)
    const float* w3 = (const float*)d_in[3];  // (128,64)
    const float* w4 = (const float*)d_in[4];  // (256,128)
    const float* w5 = (const float*)d_in[5];  // (512,512)
    float* out = (float*)d_out;               // (8,512,4096) fp32

    // workspace layout (bytes):
    //   [0)         idx_ws   B*N*K int     = 2,621,440
    //   [2621440)   dist_ws  B*N*K f32     = 2,621,440
    //   [5242880)   cat_ws   B*N*512 bf16  = 33,554,432
    //               (xyzs aliases cat_ws[0:512KB]: consumed by topk BEFORE
    //                fused_mlp writes cat — stream-ordered, safe)
    //   [38797312)  w5b bf16 (512x512)     = 524,288
    //   [72351744)  wf1 4 KB; wf2 8 KB; wf3 16 KB; wf4 64 KB
    char* ws = (char*)d_ws;
    int*      idx_ws  = (int*)ws;
    float*    dist_ws = (float*)(ws + 2621440);
    uint16_t* cat_ws  = (uint16_t*)(ws + 5242880);
    float4*   xyzs    = (float4*)(ws + 5242880);   // alias, 512 KB
    uint16_t* w5b     = (uint16_t*)(ws + 38797312);
    uint16_t* wf1     = (uint16_t*)(ws + 72351744);
    uint16_t* wf2     = (uint16_t*)(ws + 72351744 + 4096);
    uint16_t* wf3     = (uint16_t*)(ws + 72351744 + 4096 + 8192);
    uint16_t* wf4     = (uint16_t*)(ws + 72351744 + 4096 + 8192 + 16384);

    // 1024 (w5b) + 23 (wfrags) + 128 (xyzs) blocks
    prep_all<<<dim3(1024 + 23 + 128), 256, 0, stream>>>(
        x, w1, w2, w3, w4, w5, wf1, wf2, wf3, wf4, w5b, xyzs);

    topk_kernel<<<dim3(NPTS / (4 * QPW), NB), 256, 0, stream>>>(xyzs, idx_ws, dist_ws);
    fused_mlp_mfma<<<dim3(NPTS / P, NB), 256, 0, stream>>>(
        x, idx_ws, dist_ws, wf1, wf2, wf3, wf4, cat_ws);
    final_gemm_mfma<<<dim3(NPTS / 128, 512 / 64, NB), 256, 0, stream>>>(w5b, cat_ws, out);
}

// Round 12
// 306.548 us; speedup vs baseline: 1.2229x; 1.0602x over previous
//
#include <hip/hip_runtime.h>
#include <cstdint>
#include <cstddef>

#define NB   8
#define NPTS 4096
#define KNN  20
#define P    4   // points per fused-MLP block (M = P*KNN = 80 rows = 5 m-tiles)
#define QPW  4   // query points per wave in topk

typedef __attribute__((ext_vector_type(8))) short    short8;
typedef __attribute__((ext_vector_type(4))) float    floatx4;
typedef __attribute__((ext_vector_type(2))) uint32_t uint2v;

__device__ __forceinline__ uint16_t f2bf(float f) {
    uint32_t u = __float_as_uint(f);
    uint32_t r = (u + 0x7FFFu + ((u >> 16) & 1u)) >> 16;   // RNE
    return (uint16_t)r;
}

// packed f32->bf16 RNE (same rounding as f2bf), 1 instr for 2 values
__device__ __forceinline__ uint32_t cvtpk_bf16(float lo, float hi) {
    uint32_t r;
    asm("v_cvt_pk_bf16_f32 %0, %1, %2" : "=v"(r) : "v"(lo), "v"(hi));
    return r;
}

// per-half u16 max of two packed pairs (non-negative bf16 => value order)
__device__ __forceinline__ uint32_t max2u16(uint32_t a, uint32_t b) {
    const uint32_t al = a & 0xFFFFu, ah = a >> 16;
    const uint32_t bl = b & 0xFFFFu, bh = b >> 16;
    const uint32_t l = al > bl ? al : bl;
    const uint32_t h = ah > bh ? ah : bh;
    return l | (h << 16);
}

__device__ __forceinline__ uint32_t umin32(uint32_t a, uint32_t b) { return a < b ? a : b; }
__device__ __forceinline__ uint32_t umax32(uint32_t a, uint32_t b) { return a > b ? a : b; }

// DPP u32 max step: invalid source lanes fall back to own value (idempotent)
template <int CTRL>
__device__ __forceinline__ uint32_t dpp_maxu(uint32_t v) {
    uint32_t o = (uint32_t)__builtin_amdgcn_update_dpp((int)v, (int)v,
                                                       CTRL, 0xF, 0xF, false);
    return umax32(v, o);
}
// wave64 u32 max-reduce, result broadcast via readlane 63
__device__ __forceinline__ uint32_t wave_max_u32(uint32_t v) {
    v = dpp_maxu<0x111>(v);   // row_shr:1
    v = dpp_maxu<0x112>(v);   // row_shr:2
    v = dpp_maxu<0x114>(v);   // row_shr:4
    v = dpp_maxu<0x118>(v);   // row_shr:8
    v = dpp_maxu<0x142>(v);   // row_bcast:15
    v = dpp_maxu<0x143>(v);   // row_bcast:31 -> lane 63 has max
    return (uint32_t)__builtin_amdgcn_readlane((int)v, 63);
}

// ---------------------------------------------------------------------------
// Top-20, packed-key edition (R10/R11-passing body, unchanged).
__global__ __launch_bounds__(256) void topk_kernel(
    const float4* __restrict__ xyzs,  // (B,N) packed (x,y,z,sq)
    int*   __restrict__ idx_out,      // (B,N,K)
    float* __restrict__ dist_out)     // (B,N,K)
{
    const int t = threadIdx.x;
    const int wave = t >> 6, l = t & 63;
    const int nbase = (blockIdx.x * 4 + wave) * QPW;
    const int b = blockIdx.y;
    const float4* xq = xyzs + (size_t)b * NPTS;

    float xn0[QPW], xn1[QPW], xn2[QPW], sqn[QPW];
    uint32_t V0[QPW], V1[QPW], V2[QPW];
    unsigned long long consumed[QPW];
    int my_m[QPW];

    #pragma unroll
    for (int p = 0; p < QPW; ++p) {
        const float4 pn = xq[nbase + p];
        xn0[p] = pn.x; xn1[p] = pn.y; xn2[p] = pn.z; sqn[p] = pn.w;
        V0[p] = 0u; V1[p] = 0u; V2[p] = 0u;
        consumed[p] = 0ull;
        my_m[p] = 0;
    }

    #pragma unroll 4
    for (int j = 0; j < 64; ++j) {
        const float4 pm = xq[j * 64 + l];
        const uint32_t jx = (uint32_t)(j ^ 63);
        #pragma unroll
        for (int p = 0; p < QPW; ++p) {
            const float dot = fmaf(xn2[p], pm.z, fmaf(xn1[p], pm.y, xn0[p] * pm.x));
            const float s = fmaf(2.0f, dot, -sqn[p]) - pm.w;  // bitwise == prior
            const uint32_t key = (~__float_as_uint(s) & 0xFFFFFFC0u) | jx;
            const uint32_t t1 = umin32(V0[p], key);   // uses OLD V0
            const uint32_t t2 = umin32(V1[p], key);   // uses OLD V1
            V0[p] = umax32(V0[p], key);
            V1[p] = umax32(V1[p], t1);
            V2[p] = umax32(V2[p], t2);
        }
    }

    #pragma unroll
    for (int p = 0; p < QPW; ++p) {
        for (int k = 0; k < KNN; ++k) {
            if (V0[p] == 0u) {   // rare refill: rebuild top-3 of unconsumed
                V1[p] = 0u; V2[p] = 0u;
                for (int j = 0; j < 64; ++j) {
                    const float4 pm = xq[j * 64 + l];
                    const float dot = fmaf(xn2[p], pm.z, fmaf(xn1[p], pm.y, xn0[p] * pm.x));
                    const float s = fmaf(2.0f, dot, -sqn[p]) - pm.w;
                    uint32_t key = (~__float_as_uint(s) & 0xFFFFFFC0u)
                                 | (uint32_t)(j ^ 63);
                    if ((consumed[p] >> j) & 1ull) key = 0u;
                    const uint32_t t1 = umin32(V0[p], key);
                    const uint32_t t2 = umin32(V1[p], key);
                    V0[p] = umax32(V0[p], key);
                    V1[p] = umax32(V1[p], t1);
                    V2[p] = umax32(V2[p], t2);
                }
            }
            const uint32_t w = wave_max_u32(V0[p]);
            const unsigned long long own = __ballot(V0[p] == w);
            const int owner = (int)__builtin_ctzll(own);
            const int jwin  = 63 - (int)(w & 63u);
            const int m     = jwin * 64 + owner;
            if (l == k) my_m[p] = m;
            if (l == owner) {                 // owner pops its head
                consumed[p] |= 1ull << jwin;
                V0[p] = V1[p]; V1[p] = V2[p]; V2[p] = 0u;
            }
        }
    }

    #pragma unroll
    for (int p = 0; p < QPW; ++p) {
        if (l < KNN) {
            const int n = nbase + p;
            const float4 pm = xq[my_m[p]];
            const float d0 = pm.x - xn0[p], d1 = pm.y - xn1[p], d2 = pm.z - xn2[p];
            const float dist = sqrtf(((d0 * d0 + d1 * d1) + d2 * d2) + 1e-12f);
            const size_t base = ((size_t)b * NPTS + n) * KNN + l;
            idx_out[base]  = my_m[p];
            dist_out[base] = dist;
        }
    }
}

// ---------------------------------------------------------------------------
// Merged prep (one dispatch): w5 bf16 cast + fragment-ordered bf16 B-operands
// for all four conv layers + xyzs pack. (R9-R11-passing body, unchanged.)
__global__ __launch_bounds__(256) void prep_all(
    const float* __restrict__ x,
    const float* __restrict__ w1, const float* __restrict__ w2,
    const float* __restrict__ w3, const float* __restrict__ w4,
    const float* __restrict__ w5,
    uint16_t* __restrict__ wf1, uint16_t* __restrict__ wf2,
    uint16_t* __restrict__ wf3, uint16_t* __restrict__ wf4,
    uint16_t* __restrict__ w5b,
    float4* __restrict__ xyzs)
{
    int blk = blockIdx.x;
    const int t = threadIdx.x;
    if (blk < 1024) {                       // w5 (512x512) -> bf16
        const int i = blk * 256 + t;
        w5b[i] = f2bf(w5[i]);
        return;
    }
    blk -= 1024;
    if (blk >= 23) {                        // xyzs pack (B*N = 32768 threads)
        const int i = (blk - 23) * 256 + t;
        if (i < NB * NPTS) {
            const int b = i / NPTS, n = i - b * NPTS;
            const float* xb = x + (size_t)b * 3 * NPTS;
            const float x0 = xb[n], x1 = xb[NPTS + n], x2 = xb[2 * NPTS + n];
            float4 v;
            v.x = x0; v.y = x1; v.z = x2;
            v.w = fmaf(x2, x2, fmaf(x1, x1, x0 * x0));
            xyzs[i] = v;
        }
        return;
    }
    const float* w; uint16_t* frag; int C, NT, KT, base;
    if (blk < 1)       { w = w1; frag = wf1; C = 26;  NT = 4;  KT = 1; base = blk; }
    else if (blk < 3)  { w = w2; frag = wf2; C = 64;  NT = 4;  KT = 2; base = blk - 1; }
    else if (blk < 7)  { w = w3; frag = wf3; C = 64;  NT = 8;  KT = 2; base = blk - 3; }
    else               { w = w4; frag = wf4; C = 128; NT = 16; KT = 4; base = blk - 7; }
    const int i = base * 256 + t;           // one (nt,kt,lane)
    if (i >= NT * KT * 64) return;
    const int lane = i & 63;
    const int kt   = (i >> 6) % KT;
    const int nt   = (i >> 6) / KT;
    const int n    = nt * 16 + (lane & 15);
    const int c0   = kt * 32 + (lane >> 4) * 8;
    uint16_t o[8];
    #pragma unroll
    for (int j = 0; j < 8; ++j) {
        const int c = c0 + j;
        o[j] = (c < C) ? f2bf(w[(size_t)n * C + c]) : (uint16_t)0;
    }
    uint16_t* dst = frag + (size_t)i * 8;
    #pragma unroll
    for (int j = 0; j < 8; ++j) dst[j] = o[j];
}

// ---------------------------------------------------------------------------
// One MFMA conv layer, operand-swapped (R11-passing body, unchanged):
// acc = mfma(W, act) so lane owns 4 consecutive channels of one row ->
// epilogue is one aligned ds_write_b64.
template <int NT_TOT, int KT, int IN_STRIDE, int OUT_STRIDE>
__device__ __forceinline__ void mfma_layer(const uint16_t* __restrict__ in,
                                           uint16_t* __restrict__ out,
                                           const uint16_t* __restrict__ wf,
                                           int wave, int lane) {
    constexpr int NT_W = NT_TOT / 4;
    const int col = lane & 15, quad = lane >> 4;
    short8 bfrag[NT_W][KT];
    #pragma unroll
    for (int ni = 0; ni < NT_W; ++ni)
        #pragma unroll
        for (int k = 0; k < KT; ++k)
            bfrag[ni][k] = *(const short8*)(wf +
                ((size_t)((wave * NT_W + ni) * KT + k) * 64 + lane) * 8);
    #pragma unroll
    for (int mt = 0; mt < 5; ++mt) {
        short8 af[KT];
        #pragma unroll
        for (int k = 0; k < KT; ++k)
            af[k] = *(const short8*)(in + (mt * 16 + col) * IN_STRIDE + k * 32 + quad * 8);
        #pragma unroll
        for (int ni = 0; ni < NT_W; ++ni) {
            floatx4 acc = {0.f, 0.f, 0.f, 0.f};
            #pragma unroll
            for (int k = 0; k < KT; ++k)
                acc = __builtin_amdgcn_mfma_f32_16x16x32_bf16(bfrag[ni][k], af[k], acc, 0, 0, 0);
            const int nt = wave * NT_W + ni;
            const uint32_t pk01 = cvtpk_bf16(fmaxf(acc[0], 0.f), fmaxf(acc[1], 0.f));
            const uint32_t pk23 = cvtpk_bf16(fmaxf(acc[2], 0.f), fmaxf(acc[3], 0.f));
            uint2v pk; pk.x = pk01; pk.y = pk23;
            *(uint2v*)(out + (mt * 16 + col) * OUT_STRIDE + nt * 16 + quad * 4) = pk;
        }
    }
}

// max over the 20 k-rows of each point -> bf16 into cat (non-negative values)
template <int O, int STRIDE>
__device__ __forceinline__ void maxk(const uint16_t* __restrict__ h,
                                     uint16_t* __restrict__ cat_ws, int catoff,
                                     int t, int b, int n0) {
    constexpr int G = O / 8;
    if (t < P * G) {
        const int p = t / G, g = t % G;
        uint16_t mx[8];
        #pragma unroll
        for (int j = 0; j < 8; ++j) mx[j] = 0;
        for (int k = 0; k < KNN; ++k) {
            const uint16_t* row = h + (p * KNN + k) * STRIDE + g * 8;
            #pragma unroll
            for (int j = 0; j < 8; ++j) mx[j] = row[j] > mx[j] ? row[j] : mx[j];
        }
        uint16_t* dst = cat_ws + ((size_t)b * NPTS + n0 + p) * 512 + catoff + g * 8;
        *(short8*)dst = *(const short8*)mx;
    }
}

// ---------------------------------------------------------------------------
// Fused MLP, MFMA edition. Block = 4 points, 256 threads (4 waves).
// L4 slab is now bf16 (monotone RNE: max(round(.)) == round(max(.)) for the
// non-negative relu'd values -> x4 bitwise unchanged), written as one
// ds_write_b64 per (mt,ni) using the R11-proven swapped layout. LDS total
// drops 47.4 -> 34.6 KB => 4 blocks/CU (was 3).
__global__ __launch_bounds__(256) void fused_mlp_mfma(
    const float* __restrict__ x,
    const int*   __restrict__ idx_ws,
    const float* __restrict__ dist_ws,
    const uint16_t* __restrict__ wf1,
    const uint16_t* __restrict__ wf2,
    const uint16_t* __restrict__ wf3,
    const uint16_t* __restrict__ wf4,
    uint16_t* __restrict__ cat_ws)      // (B*N, 512) bf16
{
    const int n0 = blockIdx.x * P, b = blockIdx.y, t = threadIdx.x;
    const int wave = t >> 6, lane = t & 63;

    __shared__ __align__(16) uint16_t bufA[6400];   // feat(3200)/h2(5760)/slabs(6400)
    __shared__ __align__(16) uint16_t bufB[10880];  // h1(5760) / h3(10880)

    // ---- stage feat: [80][40] bf16, cols 0-2 xc, 3-5 nbr, 6-25 dist, 26+ zero
    for (int i = t; i < 1600; i += 256) ((uint32_t*)bufA)[i] = 0;
    __syncthreads();
    {
        const float* xb = x + (size_t)b * 3 * NPTS;
        if (t < P * KNN) {
            const int p = t / KNN, k = t % KNN;
            const int n = n0 + p;
            const size_t base = ((size_t)b * NPTS + n) * KNN + k;
            const int   m = idx_ws[base];
            const float d = dist_ws[base];
            uint16_t* fr = bufA + t * 40;
            fr[0] = f2bf(xb[n]);        fr[1] = f2bf(xb[NPTS + n]);
            fr[2] = f2bf(xb[2 * NPTS + n]);
            fr[3] = f2bf(xb[m]);        fr[4] = f2bf(xb[NPTS + m]);
            fr[5] = f2bf(xb[2 * NPTS + m]);
            const uint16_t db = f2bf(d);
            #pragma unroll
            for (int j = 0; j < KNN; ++j) bufA[(p * KNN + j) * 40 + 6 + k] = db;
        }
    }
    __syncthreads();

    // ---- L1: feat(A) -> h1(B)
    mfma_layer<4, 1, 40, 72>(bufA, bufB, wf1, wave, lane);
    __syncthreads();

    // ---- L2: h1(B) -> h2(A); x1 = maxk(h1)
    maxk<64, 72>(bufB, cat_ws, 0, t, b, n0);
    mfma_layer<4, 2, 72, 72>(bufB, bufA, wf2, wave, lane);
    __syncthreads();

    // ---- L3: h2(A) -> h3(B); x2 = maxk(h2)
    maxk<64, 72>(bufA, cat_ws, 64, t, b, n0);
    mfma_layer<8, 2, 72, 136>(bufA, bufB, wf3, wave, lane);
    __syncthreads();

    // ---- L4: h3(B) -> per-wave bf16 slab (A) -> u16 max -> cat; x3 = maxk(h3)
    maxk<128, 136>(bufB, cat_ws, 128, t, b, n0);
    {
        uint16_t* slab = bufA + wave * 1600;   // [80][20] bf16, wave-private
        const int col = lane & 15, quad = lane >> 4;
        #pragma unroll
        for (int ni = 0; ni < 4; ++ni) {
            const int nt = wave * 4 + ni;
            short8 bfrag[4];
            #pragma unroll
            for (int k = 0; k < 4; ++k)
                bfrag[k] = *(const short8*)(wf4 + ((size_t)(nt * 4 + k) * 64 + lane) * 8);
            #pragma unroll
            for (int mt = 0; mt < 5; ++mt) {
                floatx4 acc = {0.f, 0.f, 0.f, 0.f};
                #pragma unroll
                for (int k = 0; k < 4; ++k) {
                    const short8 af = *(const short8*)(bufB + (mt * 16 + col) * 136
                                                           + k * 32 + quad * 8);
                    acc = __builtin_amdgcn_mfma_f32_16x16x32_bf16(bfrag[k], af, acc, 0, 0, 0);
                }
                // swapped layout: lane owns channels quad*4..+3 of row mt*16+col
                uint2v pk;
                pk.x = cvtpk_bf16(fmaxf(acc[0], 0.f), fmaxf(acc[1], 0.f));
                pk.y = cvtpk_bf16(fmaxf(acc[2], 0.f), fmaxf(acc[3], 0.f));
                *(uint2v*)&slab[(mt * 16 + col) * 20 + quad * 4] = pk;
            }
            // reduce 20 k-rows: lane (p,grp,kq) covers 5 rows x 4 channels,
            // then combine across kq via shfl_xor (packed u16 max)
            const int p = lane >> 4, grp = (lane >> 2) & 3, kq = lane & 3;
            uint32_t m01 = 0u, m23 = 0u;
            #pragma unroll
            for (int i = 0; i < 5; ++i) {
                const uint2v v = *(const uint2v*)&slab[(p * KNN + kq * 5 + i) * 20 + grp * 4];
                m01 = max2u16(m01, v.x);
                m23 = max2u16(m23, v.y);
            }
            m01 = max2u16(m01, (uint32_t)__shfl_xor((int)m01, 1));
            m23 = max2u16(m23, (uint32_t)__shfl_xor((int)m23, 1));
            m01 = max2u16(m01, (uint32_t)__shfl_xor((int)m01, 2));
            m23 = max2u16(m23, (uint32_t)__shfl_xor((int)m23, 2));
            if (kq == 0) {
                uint32_t* dst = (uint32_t*)(cat_ws + ((size_t)b * NPTS + n0 + p) * 512
                              + 256 + nt * 16 + grp * 4);
                dst[0] = m01; dst[1] = m23;
            }
        }
    }
}

// ---------------------------------------------------------------------------
// Final GEMM, MFMA (R9-R11-passing body, unchanged).
__global__ __launch_bounds__(256) void final_gemm_mfma(
    const uint16_t* __restrict__ w5b,  // (512,512) bf16 row-major (o,c)
    const uint16_t* __restrict__ cat,  // (B*N,512) bf16
    float* __restrict__ out)           // (B,512,N) f32
{
    const int b  = blockIdx.z;
    const int o0 = blockIdx.y * 64;
    const int n0 = blockIdx.x * 128;
    const int t  = threadIdx.x;
    const int wave = t >> 6, lane = t & 63;
    const int col = lane & 15, quad = lane >> 4;

    __shared__ __align__(16) uint16_t As[64 * 72];   // w5 tile [o][k], +8 pad
    __shared__ __align__(16) uint16_t Bs[128 * 72];  // cat tile [n][k], +8 pad

    floatx4 acc[8];
    #pragma unroll
    for (int i = 0; i < 8; ++i) acc[i] = (floatx4){0.f, 0.f, 0.f, 0.f};

    const size_t arow_base = (size_t)o0 * 512;
    const size_t brow_base = ((size_t)b * NPTS + n0) * 512;

    for (int kc = 0; kc < 512; kc += 64) {
        #pragma unroll
        for (int i = 0; i < 2; ++i) {             // As: 512 short8
            const int idx = t + i * 256;          // 0..511
            const int row = idx >> 3;             // 0..63
            const int k8  = (idx & 7) * 8;        // 0..56
            *(short8*)&As[row * 72 + k8] =
                *(const short8*)&w5b[arow_base + (size_t)row * 512 + kc + k8];
        }
        #pragma unroll
        for (int i = 0; i < 4; ++i) {             // Bs: 1024 short8
            const int idx = t + i * 256;          // 0..1023
            const int row = idx >> 3;             // 0..127
            const int k8  = (idx & 7) * 8;
            *(short8*)&Bs[row * 72 + k8] =
                *(const short8*)&cat[brow_base + (size_t)row * 512 + kc + k8];
        }
        __syncthreads();
        #pragma unroll
        for (int kt = 0; kt < 2; ++kt) {
            const short8 af = *(const short8*)&As[(wave * 16 + col) * 72 + kt * 32 + quad * 8];
            #pragma unroll
            for (int ns = 0; ns < 8; ++ns) {
                const short8 bf = *(const short8*)&Bs[(ns * 16 + col) * 72 + kt * 32 + quad * 8];
                acc[ns] = __builtin_amdgcn_mfma_f32_16x16x32_bf16(af, bf, acc[ns], 0, 0, 0);
            }
        }
        __syncthreads();
    }

    #pragma unroll
    for (int ns = 0; ns < 8; ++ns) {
        #pragma unroll
        for (int r = 0; r < 4; ++r) {
            out[((size_t)b * 512 + o0 + wave * 16 + quad * 4 + r) * NPTS
                + n0 + ns * 16 + col] = fmaxf(acc[ns][r], 0.f);
        }
    }
}

// ---------------------------------------------------------------------------
extern "C" void kernel_launch(void* const* d_in, const int* in_sizes, int n_in,
                              void* d_out, int out_size, void* d_ws, size_t ws_size,
                              hipStream_t stream) {
    const float* x  = (const float*)d_in[0];  // (8,3,4096)
    const float* w1 = (const float*)d_in[1];  // (64,26)
    const float* w2 = (const float*)d_in[2];  // (64,64)
    const float* w3 = (const float*)d_in[3];  // (128,64)
    const float* w4 = (const float*)d_in[4];  // (256,128)
    const float* w5 = (const float*)d_in[5];  // (512,512)
    float* out = (float*)d_out;               // (8,512,4096) fp32

    // workspace layout (bytes):
    //   [0)         idx_ws   B*N*K int     = 2,621,440
    //   [2621440)   dist_ws  B*N*K f32     = 2,621,440
    //   [5242880)   cat_ws   B*N*512 bf16  = 33,554,432
    //               (xyzs aliases cat_ws[0:512KB]: consumed by topk BEFORE
    //                fused_mlp writes cat — stream-ordered, safe)
    //   [38797312)  w5b bf16 (512x512)     = 524,288
    //   [72351744)  wf1 4 KB; wf2 8 KB; wf3 16 KB; wf4 64 KB
    char* ws = (char*)d_ws;
    int*      idx_ws  = (int*)ws;
    float*    dist_ws = (float*)(ws + 2621440);
    uint16_t* cat_ws  = (uint16_t*)(ws + 5242880);
    float4*   xyzs    = (float4*)(ws + 5242880);   // alias, 512 KB
    uint16_t* w5b     = (uint16_t*)(ws + 38797312);
    uint16_t* wf1     = (uint16_t*)(ws + 72351744);
    uint16_t* wf2     = (uint16_t*)(ws + 72351744 + 4096);
    uint16_t* wf3     = (uint16_t*)(ws + 72351744 + 4096 + 8192);
    uint16_t* wf4     = (uint16_t*)(ws + 72351744 + 4096 + 8192 + 16384);

    // 1024 (w5b) + 23 (wfrags) + 128 (xyzs) blocks
    prep_all<<<dim3(1024 + 23 + 128), 256, 0, stream>>>(
        x, w1, w2, w3, w4, w5, wf1, wf2, wf3, wf4, w5b, xyzs);

    topk_kernel<<<dim3(NPTS / (4 * QPW), NB), 256, 0, stream>>>(xyzs, idx_ws, dist_ws);
    fused_mlp_mfma<<<dim3(NPTS / P, NB), 256, 0, stream>>>(
        x, idx_ws, dist_ws, wf1, wf2, wf3, wf4, cat_ws);
    final_gemm_mfma<<<dim3(NPTS / 128, 512 / 64, NB), 256, 0, stream>>>(w5b, cat_ws, out);
}

// Round 14
// 302.938 us; speedup vs baseline: 1.2375x; 1.0119x over previous
//
#include <hip/hip_runtime.h>
#include <cstdint>
#include <cstddef>

#define NB   8
#define NPTS 4096
#define KNN  20
#define P    4   // points per fused-MLP block (M = P*KNN = 80 rows = 5 m-tiles)
#define QPW  4   // query points per wave in topk

typedef __attribute__((ext_vector_type(8))) short    short8;
typedef __attribute__((ext_vector_type(4))) float    floatx4;
typedef __attribute__((ext_vector_type(2))) uint32_t uint2v;

__device__ __forceinline__ uint16_t f2bf(float f) {
    uint32_t u = __float_as_uint(f);
    uint32_t r = (u + 0x7FFFu + ((u >> 16) & 1u)) >> 16;   // RNE
    return (uint16_t)r;
}

// packed f32->bf16 RNE (same rounding as f2bf), 1 instr for 2 values
__device__ __forceinline__ uint32_t cvtpk_bf16(float lo, float hi) {
    uint32_t r;
    asm("v_cvt_pk_bf16_f32 %0, %1, %2" : "=v"(r) : "v"(lo), "v"(hi));
    return r;
}

// per-half u16 max of two packed pairs (non-negative bf16 => value order)
__device__ __forceinline__ uint32_t max2u16(uint32_t a, uint32_t b) {
    const uint32_t al = a & 0xFFFFu, ah = a >> 16;
    const uint32_t bl = b & 0xFFFFu, bh = b >> 16;
    const uint32_t l = al > bl ? al : bl;
    const uint32_t h = ah > bh ? ah : bh;
    return l | (h << 16);
}

__device__ __forceinline__ uint32_t umin32(uint32_t a, uint32_t b) { return a < b ? a : b; }
__device__ __forceinline__ uint32_t umax32(uint32_t a, uint32_t b) { return a > b ? a : b; }

// DPP u32 max step: invalid source lanes fall back to own value (idempotent)
template <int CTRL>
__device__ __forceinline__ uint32_t dpp_maxu(uint32_t v) {
    uint32_t o = (uint32_t)__builtin_amdgcn_update_dpp((int)v, (int)v,
                                                       CTRL, 0xF, 0xF, false);
    return umax32(v, o);
}
// wave64 u32 max-reduce, result broadcast via readlane 63
__device__ __forceinline__ uint32_t wave_max_u32(uint32_t v) {
    v = dpp_maxu<0x111>(v);   // row_shr:1
    v = dpp_maxu<0x112>(v);   // row_shr:2
    v = dpp_maxu<0x114>(v);   // row_shr:4
    v = dpp_maxu<0x118>(v);   // row_shr:8
    v = dpp_maxu<0x142>(v);   // row_bcast:15
    v = dpp_maxu<0x143>(v);   // row_bcast:31 -> lane 63 has max
    return (uint32_t)__builtin_amdgcn_readlane((int)v, 63);
}

// ---------------------------------------------------------------------------
// Top-20, packed-key edition (R10-R12-passing body, unchanged).
__global__ __launch_bounds__(256) void topk_kernel(
    const float4* __restrict__ xyzs,  // (B,N) packed (x,y,z,sq)
    int*   __restrict__ idx_out,      // (B,N,K)
    float* __restrict__ dist_out)     // (B,N,K)
{
    const int t = threadIdx.x;
    const int wave = t >> 6, l = t & 63;
    const int nbase = (blockIdx.x * 4 + wave) * QPW;
    const int b = blockIdx.y;
    const float4* xq = xyzs + (size_t)b * NPTS;

    float xn0[QPW], xn1[QPW], xn2[QPW], sqn[QPW];
    uint32_t V0[QPW], V1[QPW], V2[QPW];
    unsigned long long consumed[QPW];
    int my_m[QPW];

    #pragma unroll
    for (int p = 0; p < QPW; ++p) {
        const float4 pn = xq[nbase + p];
        xn0[p] = pn.x; xn1[p] = pn.y; xn2[p] = pn.z; sqn[p] = pn.w;
        V0[p] = 0u; V1[p] = 0u; V2[p] = 0u;
        consumed[p] = 0ull;
        my_m[p] = 0;
    }

    #pragma unroll 4
    for (int j = 0; j < 64; ++j) {
        const float4 pm = xq[j * 64 + l];
        const uint32_t jx = (uint32_t)(j ^ 63);
        #pragma unroll
        for (int p = 0; p < QPW; ++p) {
            const float dot = fmaf(xn2[p], pm.z, fmaf(xn1[p], pm.y, xn0[p] * pm.x));
            const float s = fmaf(2.0f, dot, -sqn[p]) - pm.w;  // bitwise == prior
            const uint32_t key = (~__float_as_uint(s) & 0xFFFFFFC0u) | jx;
            const uint32_t t1 = umin32(V0[p], key);   // uses OLD V0
            const uint32_t t2 = umin32(V1[p], key);   // uses OLD V1
            V0[p] = umax32(V0[p], key);
            V1[p] = umax32(V1[p], t1);
            V2[p] = umax32(V2[p], t2);
        }
    }

    #pragma unroll
    for (int p = 0; p < QPW; ++p) {
        for (int k = 0; k < KNN; ++k) {
            if (V0[p] == 0u) {   // rare refill: rebuild top-3 of unconsumed
                V1[p] = 0u; V2[p] = 0u;
                for (int j = 0; j < 64; ++j) {
                    const float4 pm = xq[j * 64 + l];
                    const float dot = fmaf(xn2[p], pm.z, fmaf(xn1[p], pm.y, xn0[p] * pm.x));
                    const float s = fmaf(2.0f, dot, -sqn[p]) - pm.w;
                    uint32_t key = (~__float_as_uint(s) & 0xFFFFFFC0u)
                                 | (uint32_t)(j ^ 63);
                    if ((consumed[p] >> j) & 1ull) key = 0u;
                    const uint32_t t1 = umin32(V0[p], key);
                    const uint32_t t2 = umin32(V1[p], key);
                    V0[p] = umax32(V0[p], key);
                    V1[p] = umax32(V1[p], t1);
                    V2[p] = umax32(V2[p], t2);
                }
            }
            const uint32_t w = wave_max_u32(V0[p]);
            const unsigned long long own = __ballot(V0[p] == w);
            const int owner = (int)__builtin_ctzll(own);
            const int jwin  = 63 - (int)(w & 63u);
            const int m     = jwin * 64 + owner;
            if (l == k) my_m[p] = m;
            if (l == owner) {                 // owner pops its head
                consumed[p] |= 1ull << jwin;
                V0[p] = V1[p]; V1[p] = V2[p]; V2[p] = 0u;
            }
        }
    }

    #pragma unroll
    for (int p = 0; p < QPW; ++p) {
        if (l < KNN) {
            const int n = nbase + p;
            const float4 pm = xq[my_m[p]];
            const float d0 = pm.x - xn0[p], d1 = pm.y - xn1[p], d2 = pm.z - xn2[p];
            const float dist = sqrtf(((d0 * d0 + d1 * d1) + d2 * d2) + 1e-12f);
            const size_t base = ((size_t)b * NPTS + n) * KNN + l;
            idx_out[base]  = my_m[p];
            dist_out[base] = dist;
        }
    }
}

// ---------------------------------------------------------------------------
// Merged prep (one dispatch): w5 bf16 cast + fragment-ordered bf16 B-operands
// for all four conv layers + xyzs pack. (R9-R12-passing body, unchanged.)
__global__ __launch_bounds__(256) void prep_all(
    const float* __restrict__ x,
    const float* __restrict__ w1, const float* __restrict__ w2,
    const float* __restrict__ w3, const float* __restrict__ w4,
    const float* __restrict__ w5,
    uint16_t* __restrict__ wf1, uint16_t* __restrict__ wf2,
    uint16_t* __restrict__ wf3, uint16_t* __restrict__ wf4,
    uint16_t* __restrict__ w5b,
    float4* __restrict__ xyzs)
{
    int blk = blockIdx.x;
    const int t = threadIdx.x;
    if (blk < 1024) {                       // w5 (512x512) -> bf16
        const int i = blk * 256 + t;
        w5b[i] = f2bf(w5[i]);
        return;
    }
    blk -= 1024;
    if (blk >= 23) {                        // xyzs pack (B*N = 32768 threads)
        const int i = (blk - 23) * 256 + t;
        if (i < NB * NPTS) {
            const int b = i / NPTS, n = i - b * NPTS;
            const float* xb = x + (size_t)b * 3 * NPTS;
            const float x0 = xb[n], x1 = xb[NPTS + n], x2 = xb[2 * NPTS + n];
            float4 v;
            v.x = x0; v.y = x1; v.z = x2;
            v.w = fmaf(x2, x2, fmaf(x1, x1, x0 * x0));
            xyzs[i] = v;
        }
        return;
    }
    const float* w; uint16_t* frag; int C, NT, KT, base;
    if (blk < 1)       { w = w1; frag = wf1; C = 26;  NT = 4;  KT = 1; base = blk; }
    else if (blk < 3)  { w = w2; frag = wf2; C = 64;  NT = 4;  KT = 2; base = blk - 1; }
    else if (blk < 7)  { w = w3; frag = wf3; C = 64;  NT = 8;  KT = 2; base = blk - 3; }
    else               { w = w4; frag = wf4; C = 128; NT = 16; KT = 4; base = blk - 7; }
    const int i = base * 256 + t;           // one (nt,kt,lane)
    if (i >= NT * KT * 64) return;
    const int lane = i & 63;
    const int kt   = (i >> 6) % KT;
    const int nt   = (i >> 6) / KT;
    const int n    = nt * 16 + (lane & 15);
    const int c0   = kt * 32 + (lane >> 4) * 8;
    uint16_t o[8];
    #pragma unroll
    for (int j = 0; j < 8; ++j) {
        const int c = c0 + j;
        o[j] = (c < C) ? f2bf(w[(size_t)n * C + c]) : (uint16_t)0;
    }
    uint16_t* dst = frag + (size_t)i * 8;
    #pragma unroll
    for (int j = 0; j < 8; ++j) dst[j] = o[j];
}

// ---------------------------------------------------------------------------
// One MFMA conv layer, operand-swapped (R11/R12-proven): acc = mfma(W, act),
// lane owns 4 consecutive channels of one row -> one aligned 8B write.
// SWZO: XOR-swizzle the output column (phys = logical ^ ((row&7)<<3)) —
// lets h3 use stride 128 without the stride-256B bank problem. The XOR only
// touches bits 3-5 of the element offset, and all writes are 4-elem runs at
// 4-aligned bases with fixed bits >=2, so runs stay contiguous & 8B-aligned.
template <int NT_TOT, int KT, int IN_STRIDE, int OUT_STRIDE, int SWZO>
__device__ __forceinline__ void mfma_layer(const uint16_t* __restrict__ in,
                                           uint16_t* __restrict__ out,
                                           const uint16_t* __restrict__ wf,
                                           int wave, int lane) {
    constexpr int NT_W = NT_TOT / 4;
    const int col = lane & 15, quad = lane >> 4;
    short8 bfrag[NT_W][KT];
    #pragma unroll
    for (int ni = 0; ni < NT_W; ++ni)
        #pragma unroll
        for (int k = 0; k < KT; ++k)
            bfrag[ni][k] = *(const short8*)(wf +
                ((size_t)((wave * NT_W + ni) * KT + k) * 64 + lane) * 8);
    #pragma unroll
    for (int mt = 0; mt < 5; ++mt) {
        short8 af[KT];
        #pragma unroll
        for (int k = 0; k < KT; ++k)
            af[k] = *(const short8*)(in + (mt * 16 + col) * IN_STRIDE + k * 32 + quad * 8);
        #pragma unroll
        for (int ni = 0; ni < NT_W; ++ni) {
            floatx4 acc = {0.f, 0.f, 0.f, 0.f};
            #pragma unroll
            for (int k = 0; k < KT; ++k)
                acc = __builtin_amdgcn_mfma_f32_16x16x32_bf16(bfrag[ni][k], af[k], acc, 0, 0, 0);
            const int nt = wave * NT_W + ni;
            const uint32_t pk01 = cvtpk_bf16(fmaxf(acc[0], 0.f), fmaxf(acc[1], 0.f));
            const uint32_t pk23 = cvtpk_bf16(fmaxf(acc[2], 0.f), fmaxf(acc[3], 0.f));
            uint2v pk; pk.x = pk01; pk.y = pk23;
            int oc = nt * 16 + quad * 4;
            if (SWZO) oc ^= (col & 7) << 3;   // row&7 == col&7 (row = mt*16+col)
            *(uint2v*)(out + (mt * 16 + col) * OUT_STRIDE + oc) = pk;
        }
    }
}

// max over the 20 k-rows of each point -> bf16 into cat (non-negative values)
// SWZ: input buffer is XOR-swizzled (h3); logical col g*8 lives at
// (g*8)^((row&7)<<3) — 8-aligned, so the 8-run stays contiguous.
template <int O, int STRIDE, int SWZ>
__device__ __forceinline__ void maxk(const uint16_t* __restrict__ h,
                                     uint16_t* __restrict__ cat_ws, int catoff,
                                     int t, int b, int n0) {
    constexpr int G = O / 8;
    if (t < P * G) {
        const int p = t / G, g = t % G;
        uint16_t mx[8];
        #pragma unroll
        for (int j = 0; j < 8; ++j) mx[j] = 0;
        for (int k = 0; k < KNN; ++k) {
            const int row = p * KNN + k;
            const int c = SWZ ? ((g * 8) ^ ((row & 7) << 3)) : g * 8;
            const uint16_t* rp = h + row * STRIDE + c;
            #pragma unroll
            for (int j = 0; j < 8; ++j) mx[j] = rp[j] > mx[j] ? rp[j] : mx[j];
        }
        uint16_t* dst = cat_ws + ((size_t)b * NPTS + n0 + p) * 512 + catoff + g * 8;
        *(short8*)dst = *(const short8*)mx;
    }
}

// ---------------------------------------------------------------------------
// Fused MLP, MFMA edition. Block = 4 points, 256 threads (4 waves).
// LDS squeezed under 32 KB for 5 blocks/CU (was 4):
//   bufA: feat [80][40] (3200) / h2 [80][72] (5760) / slabs 4x[80][18] (5760)
//   bufB: h1 [80][72] (5760) / h3 [80][128] XOR-swizzled (10240)
//   total = 11520 + 20480 = 32000 B
// h3 stride 136->128 is safe only with the swizzle (else 16-way read
// conflicts); slab stride 20->18 gives an odd dword stride (9) = all 32
// banks, written as two 4B stores (8B alignment not guaranteed at 36B rows).
__global__ __launch_bounds__(256) void fused_mlp_mfma(
    const float* __restrict__ x,
    const int*   __restrict__ idx_ws,
    const float* __restrict__ dist_ws,
    const uint16_t* __restrict__ wf1,
    const uint16_t* __restrict__ wf2,
    const uint16_t* __restrict__ wf3,
    const uint16_t* __restrict__ wf4,
    uint16_t* __restrict__ cat_ws)      // (B*N, 512) bf16
{
    const int n0 = blockIdx.x * P, b = blockIdx.y, t = threadIdx.x;
    const int wave = t >> 6, lane = t & 63;

    __shared__ __align__(16) uint16_t bufA[5760];   // feat(3200)/h2(5760)/slabs(5760)
    __shared__ __align__(16) uint16_t bufB[10240];  // h1(5760) / h3-swz(10240)

    // ---- stage feat: [80][40] bf16, cols 0-2 xc, 3-5 nbr, 6-25 dist, 26+ zero
    for (int i = t; i < 1600; i += 256) ((uint32_t*)bufA)[i] = 0;
    __syncthreads();
    {
        const float* xb = x + (size_t)b * 3 * NPTS;
        if (t < P * KNN) {
            const int p = t / KNN, k = t % KNN;
            const int n = n0 + p;
            const size_t base = ((size_t)b * NPTS + n) * KNN + k;
            const int   m = idx_ws[base];
            const float d = dist_ws[base];
            uint16_t* fr = bufA + t * 40;
            fr[0] = f2bf(xb[n]);        fr[1] = f2bf(xb[NPTS + n]);
            fr[2] = f2bf(xb[2 * NPTS + n]);
            fr[3] = f2bf(xb[m]);        fr[4] = f2bf(xb[NPTS + m]);
            fr[5] = f2bf(xb[2 * NPTS + m]);
            const uint16_t db = f2bf(d);
            #pragma unroll
            for (int j = 0; j < KNN; ++j) bufA[(p * KNN + j) * 40 + 6 + k] = db;
        }
    }
    __syncthreads();

    // ---- L1: feat(A) -> h1(B)
    mfma_layer<4, 1, 40, 72, 0>(bufA, bufB, wf1, wave, lane);
    __syncthreads();

    // ---- L2: h1(B) -> h2(A); x1 = maxk(h1)
    maxk<64, 72, 0>(bufB, cat_ws, 0, t, b, n0);
    mfma_layer<4, 2, 72, 72, 0>(bufB, bufA, wf2, wave, lane);
    __syncthreads();

    // ---- L3: h2(A) -> h3(B, swizzled stride 128); x2 = maxk(h2)
    maxk<64, 72, 0>(bufA, cat_ws, 64, t, b, n0);
    mfma_layer<8, 2, 72, 128, 1>(bufA, bufB, wf3, wave, lane);
    __syncthreads();

    // ---- L4: h3(B,swz) -> per-wave bf16 slab (A, stride 18) -> u16 max -> cat
    maxk<128, 128, 1>(bufB, cat_ws, 128, t, b, n0);
    {
        uint16_t* slab = bufA + wave * 1440;   // [80][18] bf16, wave-private
        const int col = lane & 15, quad = lane >> 4;
        #pragma unroll
        for (int ni = 0; ni < 4; ++ni) {
            const int nt = wave * 4 + ni;
            short8 bfrag[4];
            #pragma unroll
            for (int k = 0; k < 4; ++k)
                bfrag[k] = *(const short8*)(wf4 + ((size_t)(nt * 4 + k) * 64 + lane) * 8);
            #pragma unroll
            for (int mt = 0; mt < 5; ++mt) {
                const int row = mt * 16 + col;
                floatx4 acc = {0.f, 0.f, 0.f, 0.f};
                #pragma unroll
                for (int k = 0; k < 4; ++k) {
                    const short8 af = *(const short8*)(bufB + row * 128
                                        + ((k * 32 + quad * 8) ^ ((col & 7) << 3)));
                    acc = __builtin_amdgcn_mfma_f32_16x16x32_bf16(bfrag[k], af, acc, 0, 0, 0);
                }
                // swapped layout: lane owns channels quad*4..+3 of row
                uint32_t* sp = (uint32_t*)&slab[row * 18 + quad * 4];  // 4B-aligned
                sp[0] = cvtpk_bf16(fmaxf(acc[0], 0.f), fmaxf(acc[1], 0.f));
                sp[1] = cvtpk_bf16(fmaxf(acc[2], 0.f), fmaxf(acc[3], 0.f));
            }
            // reduce 20 k-rows: lane (p,grp,kq) covers 5 rows x 4 channels,
            // then combine across kq via shfl_xor (packed u16 max)
            const int p = lane >> 4, grp = (lane >> 2) & 3, kq = lane & 3;
            uint32_t m01 = 0u, m23 = 0u;
            #pragma unroll
            for (int i = 0; i < 5; ++i) {
                const uint32_t* rp = (const uint32_t*)
                    &slab[(p * KNN + kq * 5 + i) * 18 + grp * 4];
                m01 = max2u16(m01, rp[0]);
                m23 = max2u16(m23, rp[1]);
            }
            m01 = max2u16(m01, (uint32_t)__shfl_xor((int)m01, 1));
            m23 = max2u16(m23, (uint32_t)__shfl_xor((int)m23, 1));
            m01 = max2u16(m01, (uint32_t)__shfl_xor((int)m01, 2));
            m23 = max2u16(m23, (uint32_t)__shfl_xor((int)m23, 2));
            if (kq == 0) {
                uint32_t* dst = (uint32_t*)(cat_ws + ((size_t)b * NPTS + n0 + p) * 512
                              + 256 + nt * 16 + grp * 4);
                dst[0] = m01; dst[1] = m23;
            }
        }
    }
}

// ---------------------------------------------------------------------------
// Final GEMM, MFMA: out[b,o,n] = relu( sum_c w5[o,c] * cat[b,n,c] ).
// 128(o) x 128(n) tile, 4 waves (wave = 32-row o-slice: 2 o-sub x 8 n-sub),
// K-chunks of 64. Halves cat L2 re-reads vs the 64x128 tile (4 o-blocks
// per (b,n0) instead of 8) and block count 2048 -> 1024.
__global__ __launch_bounds__(256) void final_gemm_mfma(
    const uint16_t* __restrict__ w5b,  // (512,512) bf16 row-major (o,c)
    const uint16_t* __restrict__ cat,  // (B*N,512) bf16
    float* __restrict__ out)           // (B,512,N) f32
{
    const int b  = blockIdx.z;
    const int o0 = blockIdx.y * 128;
    const int n0 = blockIdx.x * 128;
    const int t  = threadIdx.x;
    const int wave = t >> 6, lane = t & 63;
    const int col = lane & 15, quad = lane >> 4;

    __shared__ __align__(16) uint16_t As[128 * 72];  // w5 tile [o][k], +8 pad
    __shared__ __align__(16) uint16_t Bs[128 * 72];  // cat tile [n][k], +8 pad

    floatx4 acc[2][8];
    #pragma unroll
    for (int i = 0; i < 2; ++i)
        #pragma unroll
        for (int j = 0; j < 8; ++j) acc[i][j] = (floatx4){0.f, 0.f, 0.f, 0.f};

    const size_t arow_base = (size_t)o0 * 512;
    const size_t brow_base = ((size_t)b * NPTS + n0) * 512;

    for (int kc = 0; kc < 512; kc += 64) {
        #pragma unroll
        for (int i = 0; i < 4; ++i) {             // As: 1024 short8
            const int idx = t + i * 256;          // 0..1023
            const int row = idx >> 3;             // 0..127
            const int k8  = (idx & 7) * 8;        // 0..56
            *(short8*)&As[row * 72 + k8] =
                *(const short8*)&w5b[arow_base + (size_t)row * 512 + kc + k8];
        }
        #pragma unroll
        for (int i = 0; i < 4; ++i) {             // Bs: 1024 short8
            const int idx = t + i * 256;
            const int row = idx >> 3;
            const int k8  = (idx & 7) * 8;
            *(short8*)&Bs[row * 72 + k8] =
                *(const short8*)&cat[brow_base + (size_t)row * 512 + kc + k8];
        }
        __syncthreads();
        #pragma unroll
        for (int kt = 0; kt < 2; ++kt) {
            short8 af[2];
            #pragma unroll
            for (int os = 0; os < 2; ++os)
                af[os] = *(const short8*)&As[(wave * 32 + os * 16 + col) * 72
                                             + kt * 32 + quad * 8];
            #pragma unroll
            for (int ns = 0; ns < 8; ++ns) {
                const short8 bf = *(const short8*)&Bs[(ns * 16 + col) * 72
                                                      + kt * 32 + quad * 8];
                #pragma unroll
                for (int os = 0; os < 2; ++os)
                    acc[os][ns] = __builtin_amdgcn_mfma_f32_16x16x32_bf16(
                        af[os], bf, acc[os][ns], 0, 0, 0);
            }
        }
        __syncthreads();
    }

    #pragma unroll
    for (int os = 0; os < 2; ++os) {
        #pragma unroll
        for (int ns = 0; ns < 8; ++ns) {
            #pragma unroll
            for (int r = 0; r < 4; ++r) {
                out[((size_t)b * 512 + o0 + wave * 32 + os * 16 + quad * 4 + r) * NPTS
                    + n0 + ns * 16 + col] = fmaxf(acc[os][ns][r], 0.f);
            }
        }
    }
}

// ---------------------------------------------------------------------------
extern "C" void kernel_launch(void* const* d_in, const int* in_sizes, int n_in,
                              void* d_out, int out_size, void* d_ws, size_t ws_size,
                              hipStream_t stream) {
    const float* x  = (const float*)d_in[0];  // (8,3,4096)
    const float* w1 = (const float*)d_in[1];  // (64,26)
    const float* w2 = (const float*)d_in[2];  // (64,64)
    const float* w3 = (const float*)d_in[3];  // (128,64)
    const float* w4 = (const float*)d_in[4];  // (256,128)
    const float* w5 = (const float*)d_in[5];  // (512,512)
    float* out = (float*)d_out;               // (8,512,4096) fp32

    // workspace layout (bytes):
    //   [0)         idx_ws   B*N*K int     = 2,621,440
    //   [2621440)   dist_ws  B*N*K f32     = 2,621,440
    //   [5242880)   cat_ws   B*N*512 bf16  = 33,554,432
    //               (xyzs aliases cat_ws[0:512KB]: consumed by topk BEFORE
    //                fused_mlp writes cat — stream-ordered, safe)
    //   [38797312)  w5b bf16 (512x512)     = 524,288
    //   [72351744)  wf1 4 KB; wf2 8 KB; wf3 16 KB; wf4 64 KB
    char* ws = (char*)d_ws;
    int*      idx_ws  = (int*)ws;
    float*    dist_ws = (float*)(ws + 2621440);
    uint16_t* cat_ws  = (uint16_t*)(ws + 5242880);
    float4*   xyzs    = (float4*)(ws + 5242880);   // alias, 512 KB
    uint16_t* w5b     = (uint16_t*)(ws + 38797312);
    uint16_t* wf1     = (uint16_t*)(ws + 72351744);
    uint16_t* wf2     = (uint16_t*)(ws + 72351744 + 4096);
    uint16_t* wf3     = (uint16_t*)(ws + 72351744 + 4096 + 8192);
    uint16_t* wf4     = (uint16_t*)(ws + 72351744 + 4096 + 8192 + 16384);

    // 1024 (w5b) + 23 (wfrags) + 128 (xyzs) blocks
    prep_all<<<dim3(1024 + 23 + 128), 256, 0, stream>>>(
        x, w1, w2, w3, w4, w5, wf1, wf2, wf3, wf4, w5b, xyzs);

    topk_kernel<<<dim3(NPTS / (4 * QPW), NB), 256, 0, stream>>>(xyzs, idx_ws, dist_ws);
    fused_mlp_mfma<<<dim3(NPTS / P, NB), 256, 0, stream>>>(
        x, idx_ws, dist_ws, wf1, wf2, wf3, wf4, cat_ws);
    final_gemm_mfma<<<dim3(NPTS / 128, 512 / 128, NB), 256, 0, stream>>>(w5b, cat_ws, out);
}

// Round 15
// 298.448 us; speedup vs baseline: 1.2561x; 1.0150x over previous
//
#include <hip/hip_runtime.h>
#include <cstdint>
#include <cstddef>

#define NB   8
#define NPTS 4096
#define KNN  20
#define P    4   // points per fused-MLP block (M = P*KNN = 80 rows = 5 m-tiles)
#define QPW  4   // query points per wave in topk

typedef __attribute__((ext_vector_type(8))) short    short8;
typedef __attribute__((ext_vector_type(4))) float    floatx4;
typedef __attribute__((ext_vector_type(2))) uint32_t uint2v;

__device__ __forceinline__ uint16_t f2bf(float f) {
    uint32_t u = __float_as_uint(f);
    uint32_t r = (u + 0x7FFFu + ((u >> 16) & 1u)) >> 16;   // RNE
    return (uint16_t)r;
}

// packed f32->bf16 RNE (same rounding as f2bf), 1 instr for 2 values
__device__ __forceinline__ uint32_t cvtpk_bf16(float lo, float hi) {
    uint32_t r;
    asm("v_cvt_pk_bf16_f32 %0, %1, %2" : "=v"(r) : "v"(lo), "v"(hi));
    return r;
}

// packed 2xu16 max, single VOP3P instr (== old max2u16 bitwise)
__device__ __forceinline__ uint32_t pkmax_u16(uint32_t a, uint32_t b) {
    uint32_t r;
    asm("v_pk_max_u16 %0, %1, %2" : "=v"(r) : "v"(a), "v"(b));
    return r;
}

__device__ __forceinline__ uint32_t umin32(uint32_t a, uint32_t b) { return a < b ? a : b; }
__device__ __forceinline__ uint32_t umax32(uint32_t a, uint32_t b) { return a > b ? a : b; }

// DPP u32 max step: invalid source lanes fall back to own value (idempotent)
template <int CTRL>
__device__ __forceinline__ uint32_t dpp_maxu(uint32_t v) {
    uint32_t o = (uint32_t)__builtin_amdgcn_update_dpp((int)v, (int)v,
                                                       CTRL, 0xF, 0xF, false);
    return umax32(v, o);
}
// wave64 u32 max-reduce, result broadcast via readlane 63
__device__ __forceinline__ uint32_t wave_max_u32(uint32_t v) {
    v = dpp_maxu<0x111>(v);   // row_shr:1
    v = dpp_maxu<0x112>(v);   // row_shr:2
    v = dpp_maxu<0x114>(v);   // row_shr:4
    v = dpp_maxu<0x118>(v);   // row_shr:8
    v = dpp_maxu<0x142>(v);   // row_bcast:15
    v = dpp_maxu<0x143>(v);   // row_bcast:31 -> lane 63 has max
    return (uint32_t)__builtin_amdgcn_readlane((int)v, 63);
}

// ---------------------------------------------------------------------------
// Top-20, packed-key edition (R10-R14-passing body, unchanged).
__global__ __launch_bounds__(256) void topk_kernel(
    const float4* __restrict__ xyzs,  // (B,N) packed (x,y,z,sq)
    int*   __restrict__ idx_out,      // (B,N,K)
    float* __restrict__ dist_out)     // (B,N,K)
{
    const int t = threadIdx.x;
    const int wave = t >> 6, l = t & 63;
    const int nbase = (blockIdx.x * 4 + wave) * QPW;
    const int b = blockIdx.y;
    const float4* xq = xyzs + (size_t)b * NPTS;

    float xn0[QPW], xn1[QPW], xn2[QPW], sqn[QPW];
    uint32_t V0[QPW], V1[QPW], V2[QPW];
    unsigned long long consumed[QPW];
    int my_m[QPW];

    #pragma unroll
    for (int p = 0; p < QPW; ++p) {
        const float4 pn = xq[nbase + p];
        xn0[p] = pn.x; xn1[p] = pn.y; xn2[p] = pn.z; sqn[p] = pn.w;
        V0[p] = 0u; V1[p] = 0u; V2[p] = 0u;
        consumed[p] = 0ull;
        my_m[p] = 0;
    }

    #pragma unroll 4
    for (int j = 0; j < 64; ++j) {
        const float4 pm = xq[j * 64 + l];
        const uint32_t jx = (uint32_t)(j ^ 63);
        #pragma unroll
        for (int p = 0; p < QPW; ++p) {
            const float dot = fmaf(xn2[p], pm.z, fmaf(xn1[p], pm.y, xn0[p] * pm.x));
            const float s = fmaf(2.0f, dot, -sqn[p]) - pm.w;  // bitwise == prior
            const uint32_t key = (~__float_as_uint(s) & 0xFFFFFFC0u) | jx;
            const uint32_t t1 = umin32(V0[p], key);   // uses OLD V0
            const uint32_t t2 = umin32(V1[p], key);   // uses OLD V1
            V0[p] = umax32(V0[p], key);
            V1[p] = umax32(V1[p], t1);
            V2[p] = umax32(V2[p], t2);
        }
    }

    #pragma unroll
    for (int p = 0; p < QPW; ++p) {
        for (int k = 0; k < KNN; ++k) {
            if (V0[p] == 0u) {   // rare refill: rebuild top-3 of unconsumed
                V1[p] = 0u; V2[p] = 0u;
                for (int j = 0; j < 64; ++j) {
                    const float4 pm = xq[j * 64 + l];
                    const float dot = fmaf(xn2[p], pm.z, fmaf(xn1[p], pm.y, xn0[p] * pm.x));
                    const float s = fmaf(2.0f, dot, -sqn[p]) - pm.w;
                    uint32_t key = (~__float_as_uint(s) & 0xFFFFFFC0u)
                                 | (uint32_t)(j ^ 63);
                    if ((consumed[p] >> j) & 1ull) key = 0u;
                    const uint32_t t1 = umin32(V0[p], key);
                    const uint32_t t2 = umin32(V1[p], key);
                    V0[p] = umax32(V0[p], key);
                    V1[p] = umax32(V1[p], t1);
                    V2[p] = umax32(V2[p], t2);
                }
            }
            const uint32_t w = wave_max_u32(V0[p]);
            const unsigned long long own = __ballot(V0[p] == w);
            const int owner = (int)__builtin_ctzll(own);
            const int jwin  = 63 - (int)(w & 63u);
            const int m     = jwin * 64 + owner;
            if (l == k) my_m[p] = m;
            if (l == owner) {                 // owner pops its head
                consumed[p] |= 1ull << jwin;
                V0[p] = V1[p]; V1[p] = V2[p]; V2[p] = 0u;
            }
        }
    }

    #pragma unroll
    for (int p = 0; p < QPW; ++p) {
        if (l < KNN) {
            const int n = nbase + p;
            const float4 pm = xq[my_m[p]];
            const float d0 = pm.x - xn0[p], d1 = pm.y - xn1[p], d2 = pm.z - xn2[p];
            const float dist = sqrtf(((d0 * d0 + d1 * d1) + d2 * d2) + 1e-12f);
            const size_t base = ((size_t)b * NPTS + n) * KNN + l;
            idx_out[base]  = my_m[p];
            dist_out[base] = dist;
        }
    }
}

// ---------------------------------------------------------------------------
// Merged prep (one dispatch): w5 bf16 cast + fragment-ordered bf16 B-operands
// for all four conv layers + xyzs pack. (R9-R14-passing body, unchanged.)
__global__ __launch_bounds__(256) void prep_all(
    const float* __restrict__ x,
    const float* __restrict__ w1, const float* __restrict__ w2,
    const float* __restrict__ w3, const float* __restrict__ w4,
    const float* __restrict__ w5,
    uint16_t* __restrict__ wf1, uint16_t* __restrict__ wf2,
    uint16_t* __restrict__ wf3, uint16_t* __restrict__ wf4,
    uint16_t* __restrict__ w5b,
    float4* __restrict__ xyzs)
{
    int blk = blockIdx.x;
    const int t = threadIdx.x;
    if (blk < 1024) {                       // w5 (512x512) -> bf16
        const int i = blk * 256 + t;
        w5b[i] = f2bf(w5[i]);
        return;
    }
    blk -= 1024;
    if (blk >= 23) {                        // xyzs pack (B*N = 32768 threads)
        const int i = (blk - 23) * 256 + t;
        if (i < NB * NPTS) {
            const int b = i / NPTS, n = i - b * NPTS;
            const float* xb = x + (size_t)b * 3 * NPTS;
            const float x0 = xb[n], x1 = xb[NPTS + n], x2 = xb[2 * NPTS + n];
            float4 v;
            v.x = x0; v.y = x1; v.z = x2;
            v.w = fmaf(x2, x2, fmaf(x1, x1, x0 * x0));
            xyzs[i] = v;
        }
        return;
    }
    const float* w; uint16_t* frag; int C, NT, KT, base;
    if (blk < 1)       { w = w1; frag = wf1; C = 26;  NT = 4;  KT = 1; base = blk; }
    else if (blk < 3)  { w = w2; frag = wf2; C = 64;  NT = 4;  KT = 2; base = blk - 1; }
    else if (blk < 7)  { w = w3; frag = wf3; C = 64;  NT = 8;  KT = 2; base = blk - 3; }
    else               { w = w4; frag = wf4; C = 128; NT = 16; KT = 4; base = blk - 7; }
    const int i = base * 256 + t;           // one (nt,kt,lane)
    if (i >= NT * KT * 64) return;
    const int lane = i & 63;
    const int kt   = (i >> 6) % KT;
    const int nt   = (i >> 6) / KT;
    const int n    = nt * 16 + (lane & 15);
    const int c0   = kt * 32 + (lane >> 4) * 8;
    uint16_t o[8];
    #pragma unroll
    for (int j = 0; j < 8; ++j) {
        const int c = c0 + j;
        o[j] = (c < C) ? f2bf(w[(size_t)n * C + c]) : (uint16_t)0;
    }
    uint16_t* dst = frag + (size_t)i * 8;
    #pragma unroll
    for (int j = 0; j < 8; ++j) dst[j] = o[j];
}

// ---------------------------------------------------------------------------
// One MFMA conv layer, operand-swapped (R11-R14-proven): acc = mfma(W, act),
// lane owns 4 consecutive channels of one row -> one aligned 8B write.
// SWZO: XOR-swizzle the output column (phys = logical ^ ((row&7)<<3)).
template <int NT_TOT, int KT, int IN_STRIDE, int OUT_STRIDE, int SWZO>
__device__ __forceinline__ void mfma_layer(const uint16_t* __restrict__ in,
                                           uint16_t* __restrict__ out,
                                           const uint16_t* __restrict__ wf,
                                           int wave, int lane) {
    constexpr int NT_W = NT_TOT / 4;
    const int col = lane & 15, quad = lane >> 4;
    short8 bfrag[NT_W][KT];
    #pragma unroll
    for (int ni = 0; ni < NT_W; ++ni)
        #pragma unroll
        for (int k = 0; k < KT; ++k)
            bfrag[ni][k] = *(const short8*)(wf +
                ((size_t)((wave * NT_W + ni) * KT + k) * 64 + lane) * 8);
    #pragma unroll
    for (int mt = 0; mt < 5; ++mt) {
        short8 af[KT];
        #pragma unroll
        for (int k = 0; k < KT; ++k)
            af[k] = *(const short8*)(in + (mt * 16 + col) * IN_STRIDE + k * 32 + quad * 8);
        #pragma unroll
        for (int ni = 0; ni < NT_W; ++ni) {
            floatx4 acc = {0.f, 0.f, 0.f, 0.f};
            #pragma unroll
            for (int k = 0; k < KT; ++k)
                acc = __builtin_amdgcn_mfma_f32_16x16x32_bf16(bfrag[ni][k], af[k], acc, 0, 0, 0);
            const int nt = wave * NT_W + ni;
            const uint32_t pk01 = cvtpk_bf16(fmaxf(acc[0], 0.f), fmaxf(acc[1], 0.f));
            const uint32_t pk23 = cvtpk_bf16(fmaxf(acc[2], 0.f), fmaxf(acc[3], 0.f));
            uint2v pk; pk.x = pk01; pk.y = pk23;
            int oc = nt * 16 + quad * 4;
            if (SWZO) oc ^= (col & 7) << 3;   // row&7 == col&7 (row = mt*16+col)
            *(uint2v*)(out + (mt * 16 + col) * OUT_STRIDE + oc) = pk;
        }
    }
}

// max over the 20 k-rows of each point -> bf16 into cat (non-negative values).
// 4 channels/thread (2x parallelism vs 8) + v_pk_max_u16 (1 instr per 2 ch).
// 8B uint2v loads: rows at even strides, cols 4-aligned => 8B-aligned; SWZ XOR
// touches element bits 3-5 only and a 4-aligned 4-run never crosses an
// 8-boundary => runs stay contiguous.
template <int O, int STRIDE, int SWZ>
__device__ __forceinline__ void maxk(const uint16_t* __restrict__ h,
                                     uint16_t* __restrict__ cat_ws, int catoff,
                                     int t, int b, int n0) {
    constexpr int G = O / 4;
    if (t < P * G) {
        const int p = t / G, g = t % G;
        uint32_t m0 = 0u, m1 = 0u;
        for (int k = 0; k < KNN; ++k) {
            const int row = p * KNN + k;
            const int c = SWZ ? ((g * 4) ^ ((row & 7) << 3)) : g * 4;
            const uint2v v = *(const uint2v*)(h + row * STRIDE + c);
            m0 = pkmax_u16(m0, v.x);
            m1 = pkmax_u16(m1, v.y);
        }
        uint2v o; o.x = m0; o.y = m1;
        *(uint2v*)(cat_ws + ((size_t)b * NPTS + n0 + p) * 512 + catoff + g * 4) = o;
    }
}

// ---------------------------------------------------------------------------
// Fused MLP, MFMA edition. Block = 4 points, 256 threads (4 waves).
// LDS layout (R14-proven, 32000 B => 5 blocks/CU):
//   bufA: feat [80][40] (3200) / h2 [80][72] (5760) / slabs 4x[80][18] (5760)
//   bufB: h1 [80][72] (5760) / h3 [80][128] XOR-swizzled (10240)
__global__ __launch_bounds__(256) void fused_mlp_mfma(
    const float* __restrict__ x,
    const int*   __restrict__ idx_ws,
    const float* __restrict__ dist_ws,
    const uint16_t* __restrict__ wf1,
    const uint16_t* __restrict__ wf2,
    const uint16_t* __restrict__ wf3,
    const uint16_t* __restrict__ wf4,
    uint16_t* __restrict__ cat_ws)      // (B*N, 512) bf16
{
    const int n0 = blockIdx.x * P, b = blockIdx.y, t = threadIdx.x;
    const int wave = t >> 6, lane = t & 63;

    __shared__ __align__(16) uint16_t bufA[5760];   // feat(3200)/h2(5760)/slabs(5760)
    __shared__ __align__(16) uint16_t bufB[10240];  // h1(5760) / h3-swz(10240)

    // ---- stage feat: [80][40] bf16, cols 0-2 xc, 3-5 nbr, 6-25 dist, 26+ zero
    for (int i = t; i < 1600; i += 256) ((uint32_t*)bufA)[i] = 0;
    __syncthreads();
    {
        const float* xb = x + (size_t)b * 3 * NPTS;
        if (t < P * KNN) {
            const int p = t / KNN, k = t % KNN;
            const int n = n0 + p;
            const size_t base = ((size_t)b * NPTS + n) * KNN + k;
            const int   m = idx_ws[base];
            const float d = dist_ws[base];
            uint16_t* fr = bufA + t * 40;
            fr[0] = f2bf(xb[n]);        fr[1] = f2bf(xb[NPTS + n]);
            fr[2] = f2bf(xb[2 * NPTS + n]);
            fr[3] = f2bf(xb[m]);        fr[4] = f2bf(xb[NPTS + m]);
            fr[5] = f2bf(xb[2 * NPTS + m]);
            const uint16_t db = f2bf(d);
            #pragma unroll
            for (int j = 0; j < KNN; ++j) bufA[(p * KNN + j) * 40 + 6 + k] = db;
        }
    }
    __syncthreads();

    // ---- L1: feat(A) -> h1(B)
    mfma_layer<4, 1, 40, 72, 0>(bufA, bufB, wf1, wave, lane);
    __syncthreads();

    // ---- L2: h1(B) -> h2(A); x1 = maxk(h1)
    maxk<64, 72, 0>(bufB, cat_ws, 0, t, b, n0);
    mfma_layer<4, 2, 72, 72, 0>(bufB, bufA, wf2, wave, lane);
    __syncthreads();

    // ---- L3: h2(A) -> h3(B, swizzled stride 128); x2 = maxk(h2)
    maxk<64, 72, 0>(bufA, cat_ws, 64, t, b, n0);
    mfma_layer<8, 2, 72, 128, 1>(bufA, bufB, wf3, wave, lane);
    __syncthreads();

    // ---- L4: h3(B,swz) -> per-wave bf16 slab (A, stride 18) -> pk max -> cat
    maxk<128, 128, 1>(bufB, cat_ws, 128, t, b, n0);
    {
        uint16_t* slab = bufA + wave * 1440;   // [80][18] bf16, wave-private
        const int col = lane & 15, quad = lane >> 4;
        #pragma unroll
        for (int ni = 0; ni < 4; ++ni) {
            const int nt = wave * 4 + ni;
            short8 bfrag[4];
            #pragma unroll
            for (int k = 0; k < 4; ++k)
                bfrag[k] = *(const short8*)(wf4 + ((size_t)(nt * 4 + k) * 64 + lane) * 8);
            #pragma unroll
            for (int mt = 0; mt < 5; ++mt) {
                const int row = mt * 16 + col;
                floatx4 acc = {0.f, 0.f, 0.f, 0.f};
                #pragma unroll
                for (int k = 0; k < 4; ++k) {
                    const short8 af = *(const short8*)(bufB + row * 128
                                        + ((k * 32 + quad * 8) ^ ((col & 7) << 3)));
                    acc = __builtin_amdgcn_mfma_f32_16x16x32_bf16(bfrag[k], af, acc, 0, 0, 0);
                }
                // swapped layout: lane owns channels quad*4..+3 of row
                uint32_t* sp = (uint32_t*)&slab[row * 18 + quad * 4];  // 4B-aligned
                sp[0] = cvtpk_bf16(fmaxf(acc[0], 0.f), fmaxf(acc[1], 0.f));
                sp[1] = cvtpk_bf16(fmaxf(acc[2], 0.f), fmaxf(acc[3], 0.f));
            }
            // reduce 20 k-rows: lane (p,grp,kq) covers 5 rows x 4 channels,
            // then combine across kq via shfl_xor (v_pk_max_u16 throughout)
            const int p = lane >> 4, grp = (lane >> 2) & 3, kq = lane & 3;
            uint32_t m01 = 0u, m23 = 0u;
            #pragma unroll
            for (int i = 0; i < 5; ++i) {
                const uint32_t* rp = (const uint32_t*)
                    &slab[(p * KNN + kq * 5 + i) * 18 + grp * 4];
                m01 = pkmax_u16(m01, rp[0]);
                m23 = pkmax_u16(m23, rp[1]);
            }
            m01 = pkmax_u16(m01, (uint32_t)__shfl_xor((int)m01, 1));
            m23 = pkmax_u16(m23, (uint32_t)__shfl_xor((int)m23, 1));
            m01 = pkmax_u16(m01, (uint32_t)__shfl_xor((int)m01, 2));
            m23 = pkmax_u16(m23, (uint32_t)__shfl_xor((int)m23, 2));
            if (kq == 0) {
                uint32_t* dst = (uint32_t*)(cat_ws + ((size_t)b * NPTS + n0 + p) * 512
                              + 256 + nt * 16 + grp * 4);
                dst[0] = m01; dst[1] = m23;
            }
        }
    }
}

// ---------------------------------------------------------------------------
// Final GEMM, MFMA (R14-passing 128x128-tile body, unchanged).
__global__ __launch_bounds__(256) void final_gemm_mfma(
    const uint16_t* __restrict__ w5b,  // (512,512) bf16 row-major (o,c)
    const uint16_t* __restrict__ cat,  // (B*N,512) bf16
    float* __restrict__ out)           // (B,512,N) f32
{
    const int b  = blockIdx.z;
    const int o0 = blockIdx.y * 128;
    const int n0 = blockIdx.x * 128;
    const int t  = threadIdx.x;
    const int wave = t >> 6, lane = t & 63;
    const int col = lane & 15, quad = lane >> 4;

    __shared__ __align__(16) uint16_t As[128 * 72];  // w5 tile [o][k], +8 pad
    __shared__ __align__(16) uint16_t Bs[128 * 72];  // cat tile [n][k], +8 pad

    floatx4 acc[2][8];
    #pragma unroll
    for (int i = 0; i < 2; ++i)
        #pragma unroll
        for (int j = 0; j < 8; ++j) acc[i][j] = (floatx4){0.f, 0.f, 0.f, 0.f};

    const size_t arow_base = (size_t)o0 * 512;
    const size_t brow_base = ((size_t)b * NPTS + n0) * 512;

    for (int kc = 0; kc < 512; kc += 64) {
        #pragma unroll
        for (int i = 0; i < 4; ++i) {             // As: 1024 short8
            const int idx = t + i * 256;          // 0..1023
            const int row = idx >> 3;             // 0..127
            const int k8  = (idx & 7) * 8;        // 0..56
            *(short8*)&As[row * 72 + k8] =
                *(const short8*)&w5b[arow_base + (size_t)row * 512 + kc + k8];
        }
        #pragma unroll
        for (int i = 0; i < 4; ++i) {             // Bs: 1024 short8
            const int idx = t + i * 256;
            const int row = idx >> 3;
            const int k8  = (idx & 7) * 8;
            *(short8*)&Bs[row * 72 + k8] =
                *(const short8*)&cat[brow_base + (size_t)row * 512 + kc + k8];
        }
        __syncthreads();
        #pragma unroll
        for (int kt = 0; kt < 2; ++kt) {
            short8 af[2];
            #pragma unroll
            for (int os = 0; os < 2; ++os)
                af[os] = *(const short8*)&As[(wave * 32 + os * 16 + col) * 72
                                             + kt * 32 + quad * 8];
            #pragma unroll
            for (int ns = 0; ns < 8; ++ns) {
                const short8 bf = *(const short8*)&Bs[(ns * 16 + col) * 72
                                                      + kt * 32 + quad * 8];
                #pragma unroll
                for (int os = 0; os < 2; ++os)
                    acc[os][ns] = __builtin_amdgcn_mfma_f32_16x16x32_bf16(
                        af[os], bf, acc[os][ns], 0, 0, 0);
            }
        }
        __syncthreads();
    }

    #pragma unroll
    for (int os = 0; os < 2; ++os) {
        #pragma unroll
        for (int ns = 0; ns < 8; ++ns) {
            #pragma unroll
            for (int r = 0; r < 4; ++r) {
                out[((size_t)b * 512 + o0 + wave * 32 + os * 16 + quad * 4 + r) * NPTS
                    + n0 + ns * 16 + col] = fmaxf(acc[os][ns][r], 0.f);
            }
        }
    }
}

// ---------------------------------------------------------------------------
extern "C" void kernel_launch(void* const* d_in, const int* in_sizes, int n_in,
                              void* d_out, int out_size, void* d_ws, size_t ws_size,
                              hipStream_t stream) {
    const float* x  = (const float*)d_in[0];  // (8,3,4096)
    const float* w1 = (const float*)d_in[1];  // (64,26)
    const float* w2 = (const float*)d_in[2];  // (64,64)
    const float* w3 = (const float*)d_in[3];  // (128,64)
    const float* w4 = (const float*)d_in[4];  // (256,128)
    const float* w5 = (const float*)d_in[5];  // (512,512)
    float* out = (float*)d_out;               // (8,512,4096) fp32

    // workspace layout (bytes):
    //   [0)         idx_ws   B*N*K int     = 2,621,440
    //   [2621440)   dist_ws  B*N*K f32     = 2,621,440
    //   [5242880)   cat_ws   B*N*512 bf16  = 33,554,432
    //               (xyzs aliases cat_ws[0:512KB]: consumed by topk BEFORE
    //                fused_mlp writes cat — stream-ordered, safe)
    //   [38797312)  w5b bf16 (512x512)     = 524,288
    //   [72351744)  wf1 4 KB; wf2 8 KB; wf3 16 KB; wf4 64 KB
    char* ws = (char*)d_ws;
    int*      idx_ws  = (int*)ws;
    float*    dist_ws = (float*)(ws + 2621440);
    uint16_t* cat_ws  = (uint16_t*)(ws + 5242880);
    float4*   xyzs    = (float4*)(ws + 5242880);   // alias, 512 KB
    uint16_t* w5b     = (uint16_t*)(ws + 38797312);
    uint16_t* wf1     = (uint16_t*)(ws + 72351744);
    uint16_t* wf2     = (uint16_t*)(ws + 72351744 + 4096);
    uint16_t* wf3     = (uint16_t*)(ws + 72351744 + 4096 + 8192);
    uint16_t* wf4     = (uint16_t*)(ws + 72351744 + 4096 + 8192 + 16384);

    // 1024 (w5b) + 23 (wfrags) + 128 (xyzs) blocks
    prep_all<<<dim3(1024 + 23 + 128), 256, 0, stream>>>(
        x, w1, w2, w3, w4, w5, wf1, wf2, wf3, wf4, w5b, xyzs);

    topk_kernel<<<dim3(NPTS / (4 * QPW), NB), 256, 0, stream>>>(xyzs, idx_ws, dist_ws);
    fused_mlp_mfma<<<dim3(NPTS / P, NB), 256, 0, stream>>>(
        x, idx_ws, dist_ws, wf1, wf2, wf3, wf4, cat_ws);
    final_gemm_mfma<<<dim3(NPTS / 128, 512 / 128, NB), 256, 0, stream>>>(w5b, cat_ws, out);
}